// Round 10
// baseline (1260.536 us; speedup 1.0000x reference)
//
#include <hip/hip_runtime.h>
#include <math.h>

#define S   30
#define FD  200
#define TT  1024
#define BB  1024
#define NC  7

// ---- workspace layout (float offsets), overlaid by live range ----
// C1 occupies [0, 31457280) and is LIVE until k_f2d completes.
// AF/GV/GH/RWS/WclsT overlay the C1 region and may only be written AFTER k_f2d.
#define OFS_C1   0ull
#define OFS_F2   31457280ull
#define OFS_AF   0ull
#define OFS_GV   921600ull
#define OFS_GH   10137600ull
#define OFS_R    19691520ull     // 3*1024*30*100 floats
#define OFS_WT   28907520ull     // WclsT: 7*18000 = 126,000 floats

// ================= K1: conv1 + relu -> C1 =================
__global__ __launch_bounds__(256) void k_conv1(
    const float* __restrict__ x,
    const float* __restrict__ Wc1, const float* __restrict__ bc1,
    float* __restrict__ C1) {
    const int c = blockIdx.x, b = blockIdx.y;
    const int t = threadIdx.x;
    const int t0 = c * 256;
    __shared__ float xb[S * 258];
    __shared__ float w1l[90 * 32];
    for (int idx = t; idx < 2700; idx += 256) {
        int so = idx / 90, r = idx % 90;
        w1l[r * 32 + so] = Wc1[idx];
    }
    for (int idx = t; idx < 180; idx += 256) {
        int r = idx >> 1, z = idx & 1;
        w1l[r * 32 + 30 + z] = 0.f;
    }
    for (int idx = t; idx < S * 64; idx += 256) {
        int s = idx >> 6, u = idx & 63;
        float4 v = *(const float4*)(x + (size_t)(b * S + s) * TT + t0 + 4 * u);
        float* d = xb + s * 258 + 1 + 4 * u;
        d[0] = v.x; d[1] = v.y; d[2] = v.z; d[3] = v.w;
    }
    if (t < 60) {
        int s = t % S;
        if (t < S) {
            int gt = t0 - 1;
            xb[s * 258] = (gt >= 0) ? x[(size_t)(b * S + s) * TT + gt] : 0.f;
        } else {
            int gt = t0 + 256;
            xb[s * 258 + 257] = (gt < TT) ? x[(size_t)(b * S + s) * TT + gt] : 0.f;
        }
    }
    __syncthreads();
    float acc[32];
#pragma unroll
    for (int so = 0; so < 32; so++) acc[so] = (so < S) ? bc1[so] : 0.f;
    for (int si = 0; si < S; si++) {
        float v0 = xb[si * 258 + t];
        float v1 = xb[si * 258 + t + 1];
        float v2 = xb[si * 258 + t + 2];
        const float* wr = w1l + si * 96;
#pragma unroll
        for (int u = 0; u < 8; u++) {
            float4 w0 = *(const float4*)(wr + 4 * u);
            float4 w1 = *(const float4*)(wr + 32 + 4 * u);
            float4 w2 = *(const float4*)(wr + 64 + 4 * u);
            acc[4 * u + 0] = fmaf(w0.x, v0, fmaf(w1.x, v1, fmaf(w2.x, v2, acc[4 * u + 0])));
            acc[4 * u + 1] = fmaf(w0.y, v0, fmaf(w1.y, v1, fmaf(w2.y, v2, acc[4 * u + 1])));
            acc[4 * u + 2] = fmaf(w0.z, v0, fmaf(w1.z, v1, fmaf(w2.z, v2, acc[4 * u + 2])));
            acc[4 * u + 3] = fmaf(w0.w, v0, fmaf(w1.w, v1, fmaf(w2.w, v2, acc[4 * u + 3])));
        }
    }
#pragma unroll
    for (int so = 0; so < 32; so++) {
        if (so < S)
            C1[(size_t)(b * S + so) * TT + t0 + t] = fmaxf(acc[so], 0.f);
    }
}

// ---------- FMA tile helpers ----------
#define FMA4(av, wv, accm)                           \
    {                                                \
        accm[0] = fmaf(av, (wv).x, accm[0]);         \
        accm[1] = fmaf(av, (wv).y, accm[1]);         \
        accm[2] = fmaf(av, (wv).z, accm[2]);         \
        accm[3] = fmaf(av, (wv).w, accm[3]);         \
    }

__device__ inline void fma_tile8(const float4 a0, const float4 a1,
                                 const float4 w[8], float accm[4]) {
    FMA4(a0.x, w[0], accm); FMA4(a0.y, w[1], accm);
    FMA4(a0.z, w[2], accm); FMA4(a0.w, w[3], accm);
    FMA4(a1.x, w[4], accm); FMA4(a1.y, w[5], accm);
    FMA4(a1.z, w[6], accm); FMA4(a1.w, w[7], accm);
}

template<int RPT>
__device__ inline void zacc(float acc[][4]) {
#pragma unroll
    for (int m = 0; m < RPT; m++)
#pragma unroll
        for (int q = 0; q < 4; q++) acc[m][q] = 0.f;
}

// ---------- gemm_w4_pf: X(LDS) @ W(global), depth-8 register pipeline ----------
template<int RPT, int N, int K>
__device__ inline void gemm_w4_pf(const float* Xl, int xstr, const float* __restrict__ W,
                                  int ct, int rt, float acc[][4]) {
    const float* wp = W + 4 * ct;
    float4 wreg[8];
#pragma unroll
    for (int u = 0; u < 8; u++) wreg[u] = *(const float4*)(wp + u * N);
#pragma unroll 1
    for (int kt = 0; kt < K / 8 - 1; kt++) {
        float4 wnxt[8];
#pragma unroll
        for (int u = 0; u < 8; u++) wnxt[u] = *(const float4*)(wp + (kt * 8 + 8 + u) * N);
#pragma unroll
        for (int m = 0; m < RPT; m++) {
            const float* xr = Xl + (rt * RPT + m) * xstr + kt * 8;
            float4 a0 = *(const float4*)(xr);
            float4 a1 = *(const float4*)(xr + 4);
            fma_tile8(a0, a1, wreg, acc[m]);
        }
#pragma unroll
        for (int u = 0; u < 8; u++) wreg[u] = wnxt[u];
    }
    {
        const int kb = K - 8;
#pragma unroll
        for (int m = 0; m < RPT; m++) {
            const float* xr = Xl + (rt * RPT + m) * xstr + kb;
            float4 a0 = *(const float4*)(xr);
            float4 a1 = *(const float4*)(xr + 4);
            fma_tile8(a0, a1, wreg, acc[m]);
        }
    }
}

// ---------- gemm_w4_pf_dual: shared W stream, two X buffers / acc sets ----------
template<int RPT, int N, int K>
__device__ inline void gemm_w4_pf_dual(const float* X0, const float* X1, int xstr,
                                       const float* __restrict__ W,
                                       int ct, int rt,
                                       float acc0[][4], float acc1[][4]) {
    const float* wp = W + 4 * ct;
    float4 wreg[8];
#pragma unroll
    for (int u = 0; u < 8; u++) wreg[u] = *(const float4*)(wp + u * N);
#pragma unroll 1
    for (int kt = 0; kt < K / 8 - 1; kt++) {
        float4 wnxt[8];
#pragma unroll
        for (int u = 0; u < 8; u++) wnxt[u] = *(const float4*)(wp + (kt * 8 + 8 + u) * N);
#pragma unroll
        for (int m = 0; m < RPT; m++) {
            const float* xr = X0 + (rt * RPT + m) * xstr + kt * 8;
            float4 a0 = *(const float4*)(xr);
            float4 a1 = *(const float4*)(xr + 4);
            fma_tile8(a0, a1, wreg, acc0[m]);
        }
#pragma unroll
        for (int m = 0; m < RPT; m++) {
            const float* xr = X1 + (rt * RPT + m) * xstr + kt * 8;
            float4 a0 = *(const float4*)(xr);
            float4 a1 = *(const float4*)(xr + 4);
            fma_tile8(a0, a1, wreg, acc1[m]);
        }
#pragma unroll
        for (int u = 0; u < 8; u++) wreg[u] = wnxt[u];
    }
    {
        const int kb = K - 8;
#pragma unroll
        for (int m = 0; m < RPT; m++) {
            const float* xr = X0 + (rt * RPT + m) * xstr + kb;
            float4 a0 = *(const float4*)(xr);
            float4 a1 = *(const float4*)(xr + 4);
            fma_tile8(a0, a1, wreg, acc0[m]);
        }
#pragma unroll
        for (int m = 0; m < RPT; m++) {
            const float* xr = X1 + (rt * RPT + m) * xstr + kb;
            float4 a0 = *(const float4*)(xr);
            float4 a1 = *(const float4*)(xr + 4);
            fma_tile8(a0, a1, wreg, acc1[m]);
        }
    }
}

// ---------- gemm_w4_pf_quad: shared W stream, four X buffers / acc sets ----------
// Samples processed sequentially inside each kt step to cap register transients.
template<int RPT, int N, int K>
__device__ inline void gemm_w4_pf_quad(const float* X0, const float* X1,
                                       const float* X2, const float* X3, int xstr,
                                       const float* __restrict__ W,
                                       int ct, int rt,
                                       float acc0[][4], float acc1[][4],
                                       float acc2[][4], float acc3[][4]) {
    const float* wp = W + 4 * ct;
    float4 wreg[8];
#pragma unroll
    for (int u = 0; u < 8; u++) wreg[u] = *(const float4*)(wp + u * N);
#pragma unroll 1
    for (int kt = 0; kt < K / 8 - 1; kt++) {
        float4 wnxt[8];
#pragma unroll
        for (int u = 0; u < 8; u++) wnxt[u] = *(const float4*)(wp + (kt * 8 + 8 + u) * N);
#pragma unroll
        for (int m = 0; m < RPT; m++) {
            const float* xr = X0 + (rt * RPT + m) * xstr + kt * 8;
            fma_tile8(*(const float4*)(xr), *(const float4*)(xr + 4), wreg, acc0[m]);
        }
#pragma unroll
        for (int m = 0; m < RPT; m++) {
            const float* xr = X1 + (rt * RPT + m) * xstr + kt * 8;
            fma_tile8(*(const float4*)(xr), *(const float4*)(xr + 4), wreg, acc1[m]);
        }
#pragma unroll
        for (int m = 0; m < RPT; m++) {
            const float* xr = X2 + (rt * RPT + m) * xstr + kt * 8;
            fma_tile8(*(const float4*)(xr), *(const float4*)(xr + 4), wreg, acc2[m]);
        }
#pragma unroll
        for (int m = 0; m < RPT; m++) {
            const float* xr = X3 + (rt * RPT + m) * xstr + kt * 8;
            fma_tile8(*(const float4*)(xr), *(const float4*)(xr + 4), wreg, acc3[m]);
        }
#pragma unroll
        for (int u = 0; u < 8; u++) wreg[u] = wnxt[u];
    }
    {
        const int kb = K - 8;
#pragma unroll
        for (int m = 0; m < RPT; m++) {
            const float* xr = X0 + (rt * RPT + m) * xstr + kb;
            fma_tile8(*(const float4*)(xr), *(const float4*)(xr + 4), wreg, acc0[m]);
        }
#pragma unroll
        for (int m = 0; m < RPT; m++) {
            const float* xr = X1 + (rt * RPT + m) * xstr + kb;
            fma_tile8(*(const float4*)(xr), *(const float4*)(xr + 4), wreg, acc1[m]);
        }
#pragma unroll
        for (int m = 0; m < RPT; m++) {
            const float* xr = X2 + (rt * RPT + m) * xstr + kb;
            fma_tile8(*(const float4*)(xr), *(const float4*)(xr + 4), wreg, acc2[m]);
        }
#pragma unroll
        for (int m = 0; m < RPT; m++) {
            const float* xr = X3 + (rt * RPT + m) * xstr + kb;
            fma_tile8(*(const float4*)(xr), *(const float4*)(xr + 4), wreg, acc3[m]);
        }
    }
}

// ---------- gemm_a32: Al(LDS, stride 32) @ Xl(LDS) ----------
template<int RPT>
__device__ inline void gemm_a32(const float* Al, const float* Xl, int xstr,
                                int ct, int rt, float acc[][4]) {
#pragma unroll
    for (int k4 = 0; k4 < 8; k4++) {
        float4 xv0 = *(const float4*)(Xl + (4 * k4 + 0) * xstr + 4 * ct);
        float4 xv1 = *(const float4*)(Xl + (4 * k4 + 1) * xstr + 4 * ct);
        float4 xv2 = *(const float4*)(Xl + (4 * k4 + 2) * xstr + 4 * ct);
        float4 xv3 = *(const float4*)(Xl + (4 * k4 + 3) * xstr + 4 * ct);
#pragma unroll
        for (int m = 0; m < RPT; m++) {
            float4 av = *(const float4*)(Al + (rt * RPT + m) * 32 + 4 * k4);
            FMA4(av.x, xv0, acc[m]);
            FMA4(av.y, xv1, acc[m]);
            FMA4(av.z, xv2, acc[m]);
            FMA4(av.w, xv3, acc[m]);
        }
    }
}

// ---------- gemm_a32_dual ----------
template<int RPT>
__device__ inline void gemm_a32_dual(const float* Al0, const float* X0,
                                     const float* Al1, const float* X1,
                                     int xstr, int ct, int rt,
                                     float acc0[][4], float acc1[][4]) {
#pragma unroll
    for (int k4 = 0; k4 < 8; k4++) {
        float4 x00 = *(const float4*)(X0 + (4 * k4 + 0) * xstr + 4 * ct);
        float4 x01 = *(const float4*)(X0 + (4 * k4 + 1) * xstr + 4 * ct);
        float4 x02 = *(const float4*)(X0 + (4 * k4 + 2) * xstr + 4 * ct);
        float4 x03 = *(const float4*)(X0 + (4 * k4 + 3) * xstr + 4 * ct);
        float4 x10 = *(const float4*)(X1 + (4 * k4 + 0) * xstr + 4 * ct);
        float4 x11 = *(const float4*)(X1 + (4 * k4 + 1) * xstr + 4 * ct);
        float4 x12 = *(const float4*)(X1 + (4 * k4 + 2) * xstr + 4 * ct);
        float4 x13 = *(const float4*)(X1 + (4 * k4 + 3) * xstr + 4 * ct);
#pragma unroll
        for (int m = 0; m < RPT; m++) {
            float4 av0 = *(const float4*)(Al0 + (rt * RPT + m) * 32 + 4 * k4);
            FMA4(av0.x, x00, acc0[m]);
            FMA4(av0.y, x01, acc0[m]);
            FMA4(av0.z, x02, acc0[m]);
            FMA4(av0.w, x03, acc0[m]);
            float4 av1 = *(const float4*)(Al1 + (rt * RPT + m) * 32 + 4 * k4);
            FMA4(av1.x, x10, acc1[m]);
            FMA4(av1.y, x11, acc1[m]);
            FMA4(av1.z, x12, acc1[m]);
            FMA4(av1.w, x13, acc1[m]);
        }
    }
}

// ---------- gemm_a32_quad: samples sequential within each k4 step ----------
template<int RPT>
__device__ inline void gemm_a32_quad(const float* Al0, const float* X0,
                                     const float* Al1, const float* X1,
                                     const float* Al2, const float* X2,
                                     const float* Al3, const float* X3,
                                     int xstr, int ct, int rt,
                                     float acc0[][4], float acc1[][4],
                                     float acc2[][4], float acc3[][4]) {
#pragma unroll
    for (int k4 = 0; k4 < 8; k4++) {
        {
            float4 x0 = *(const float4*)(X0 + (4 * k4 + 0) * xstr + 4 * ct);
            float4 x1 = *(const float4*)(X0 + (4 * k4 + 1) * xstr + 4 * ct);
            float4 x2 = *(const float4*)(X0 + (4 * k4 + 2) * xstr + 4 * ct);
            float4 x3 = *(const float4*)(X0 + (4 * k4 + 3) * xstr + 4 * ct);
#pragma unroll
            for (int m = 0; m < RPT; m++) {
                float4 av = *(const float4*)(Al0 + (rt * RPT + m) * 32 + 4 * k4);
                FMA4(av.x, x0, acc0[m]);
                FMA4(av.y, x1, acc0[m]);
                FMA4(av.z, x2, acc0[m]);
                FMA4(av.w, x3, acc0[m]);
            }
        }
        {
            float4 x0 = *(const float4*)(X1 + (4 * k4 + 0) * xstr + 4 * ct);
            float4 x1 = *(const float4*)(X1 + (4 * k4 + 1) * xstr + 4 * ct);
            float4 x2 = *(const float4*)(X1 + (4 * k4 + 2) * xstr + 4 * ct);
            float4 x3 = *(const float4*)(X1 + (4 * k4 + 3) * xstr + 4 * ct);
#pragma unroll
            for (int m = 0; m < RPT; m++) {
                float4 av = *(const float4*)(Al1 + (rt * RPT + m) * 32 + 4 * k4);
                FMA4(av.x, x0, acc1[m]);
                FMA4(av.y, x1, acc1[m]);
                FMA4(av.z, x2, acc1[m]);
                FMA4(av.w, x3, acc1[m]);
            }
        }
        {
            float4 x0 = *(const float4*)(X2 + (4 * k4 + 0) * xstr + 4 * ct);
            float4 x1 = *(const float4*)(X2 + (4 * k4 + 1) * xstr + 4 * ct);
            float4 x2 = *(const float4*)(X2 + (4 * k4 + 2) * xstr + 4 * ct);
            float4 x3 = *(const float4*)(X2 + (4 * k4 + 3) * xstr + 4 * ct);
#pragma unroll
            for (int m = 0; m < RPT; m++) {
                float4 av = *(const float4*)(Al2 + (rt * RPT + m) * 32 + 4 * k4);
                FMA4(av.x, x0, acc2[m]);
                FMA4(av.y, x1, acc2[m]);
                FMA4(av.z, x2, acc2[m]);
                FMA4(av.w, x3, acc2[m]);
            }
        }
        {
            float4 x0 = *(const float4*)(X3 + (4 * k4 + 0) * xstr + 4 * ct);
            float4 x1 = *(const float4*)(X3 + (4 * k4 + 1) * xstr + 4 * ct);
            float4 x2 = *(const float4*)(X3 + (4 * k4 + 2) * xstr + 4 * ct);
            float4 x3 = *(const float4*)(X3 + (4 * k4 + 3) * xstr + 4 * ct);
#pragma unroll
            for (int m = 0; m < RPT; m++) {
                float4 av = *(const float4*)(Al3 + (rt * RPT + m) * 32 + 4 * k4);
                FMA4(av.x, x0, acc3[m]);
                FMA4(av.y, x1, acc3[m]);
                FMA4(av.z, x2, acc3[m]);
                FMA4(av.w, x3, acc3[m]);
            }
        }
    }
}

// ---------- gemm_w150_pf: N=150, float2-pair columns ----------
__device__ inline void gemm_w150_pf(const float* Xl, const float* __restrict__ W,
                                    int ct2, int rt2, float acc[5][4], int off23) {
    const float* wp = W + 4 * ct2;
    float2 wa[8], wb[8];
#pragma unroll
    for (int u = 0; u < 8; u++) {
        wa[u] = *(const float2*)(wp + u * 150);
        wb[u] = *(const float2*)(wp + u * 150 + off23);
    }
#pragma unroll 1
    for (int kt = 0; kt < 24; kt++) {
        float2 na[8], nb[8];
#pragma unroll
        for (int u = 0; u < 8; u++) {
            int k = kt * 8 + 8 + u;
            na[u] = *(const float2*)(wp + k * 150);
            nb[u] = *(const float2*)(wp + k * 150 + off23);
        }
#pragma unroll
        for (int m = 0; m < 5; m++) {
            const float* xr = Xl + (rt2 * 5 + m) * FD + kt * 8;
            float4 a0 = *(const float4*)(xr);
            float4 a1 = *(const float4*)(xr + 4);
            float av[8] = {a0.x, a0.y, a0.z, a0.w, a1.x, a1.y, a1.z, a1.w};
#pragma unroll
            for (int u = 0; u < 8; u++) {
                acc[m][0] = fmaf(av[u], wa[u].x, acc[m][0]);
                acc[m][1] = fmaf(av[u], wa[u].y, acc[m][1]);
                acc[m][2] = fmaf(av[u], wb[u].x, acc[m][2]);
                acc[m][3] = fmaf(av[u], wb[u].y, acc[m][3]);
            }
        }
#pragma unroll
        for (int u = 0; u < 8; u++) { wa[u] = na[u]; wb[u] = nb[u]; }
    }
#pragma unroll
    for (int m = 0; m < 5; m++) {
        const float* xr = Xl + (rt2 * 5 + m) * FD + 192;
        float4 a0 = *(const float4*)(xr);
        float4 a1 = *(const float4*)(xr + 4);
        float av[8] = {a0.x, a0.y, a0.z, a0.w, a1.x, a1.y, a1.z, a1.w};
#pragma unroll
        for (int u = 0; u < 8; u++) {
            acc[m][0] = fmaf(av[u], wa[u].x, acc[m][0]);
            acc[m][1] = fmaf(av[u], wa[u].y, acc[m][1]);
            acc[m][2] = fmaf(av[u], wb[u].x, acc[m][2]);
            acc[m][3] = fmaf(av[u], wb[u].y, acc[m][3]);
        }
    }
}

// ---------- gemm_w150_pf_dual: shared W stream, two X buffers / acc sets ----------
__device__ inline void gemm_w150_pf_dual(const float* X0, const float* X1,
                                         const float* __restrict__ W,
                                         int ct2, int rt2,
                                         float acc0[5][4], float acc1[5][4], int off23) {
    const float* wp = W + 4 * ct2;
    float2 wa[8], wb[8];
#pragma unroll
    for (int u = 0; u < 8; u++) {
        wa[u] = *(const float2*)(wp + u * 150);
        wb[u] = *(const float2*)(wp + u * 150 + off23);
    }
#pragma unroll 1
    for (int kt = 0; kt < 24; kt++) {
        float2 na[8], nb[8];
#pragma unroll
        for (int u = 0; u < 8; u++) {
            int k = kt * 8 + 8 + u;
            na[u] = *(const float2*)(wp + k * 150);
            nb[u] = *(const float2*)(wp + k * 150 + off23);
        }
#pragma unroll
        for (int m = 0; m < 5; m++) {
            const float* xr = X0 + (rt2 * 5 + m) * FD + kt * 8;
            float4 a0 = *(const float4*)(xr);
            float4 a1 = *(const float4*)(xr + 4);
            float av[8] = {a0.x, a0.y, a0.z, a0.w, a1.x, a1.y, a1.z, a1.w};
#pragma unroll
            for (int u = 0; u < 8; u++) {
                acc0[m][0] = fmaf(av[u], wa[u].x, acc0[m][0]);
                acc0[m][1] = fmaf(av[u], wa[u].y, acc0[m][1]);
                acc0[m][2] = fmaf(av[u], wb[u].x, acc0[m][2]);
                acc0[m][3] = fmaf(av[u], wb[u].y, acc0[m][3]);
            }
        }
#pragma unroll
        for (int m = 0; m < 5; m++) {
            const float* xr = X1 + (rt2 * 5 + m) * FD + kt * 8;
            float4 a0 = *(const float4*)(xr);
            float4 a1 = *(const float4*)(xr + 4);
            float av[8] = {a0.x, a0.y, a0.z, a0.w, a1.x, a1.y, a1.z, a1.w};
#pragma unroll
            for (int u = 0; u < 8; u++) {
                acc1[m][0] = fmaf(av[u], wa[u].x, acc1[m][0]);
                acc1[m][1] = fmaf(av[u], wa[u].y, acc1[m][1]);
                acc1[m][2] = fmaf(av[u], wb[u].x, acc1[m][2]);
                acc1[m][3] = fmaf(av[u], wb[u].y, acc1[m][3]);
            }
        }
#pragma unroll
        for (int u = 0; u < 8; u++) { wa[u] = na[u]; wb[u] = nb[u]; }
    }
#pragma unroll
    for (int m = 0; m < 5; m++) {
        const float* xr = X0 + (rt2 * 5 + m) * FD + 192;
        float4 a0 = *(const float4*)(xr);
        float4 a1 = *(const float4*)(xr + 4);
        float av[8] = {a0.x, a0.y, a0.z, a0.w, a1.x, a1.y, a1.z, a1.w};
#pragma unroll
        for (int u = 0; u < 8; u++) {
            acc0[m][0] = fmaf(av[u], wa[u].x, acc0[m][0]);
            acc0[m][1] = fmaf(av[u], wa[u].y, acc0[m][1]);
            acc0[m][2] = fmaf(av[u], wb[u].x, acc0[m][2]);
            acc0[m][3] = fmaf(av[u], wb[u].y, acc0[m][3]);
        }
    }
#pragma unroll
    for (int m = 0; m < 5; m++) {
        const float* xr = X1 + (rt2 * 5 + m) * FD + 192;
        float4 a0 = *(const float4*)(xr);
        float4 a1 = *(const float4*)(xr + 4);
        float av[8] = {a0.x, a0.y, a0.z, a0.w, a1.x, a1.y, a1.z, a1.w};
#pragma unroll
        for (int u = 0; u < 8; u++) {
            acc1[m][0] = fmaf(av[u], wa[u].x, acc1[m][0]);
            acc1[m][1] = fmaf(av[u], wa[u].y, acc1[m][1]);
            acc1[m][2] = fmaf(av[u], wb[u].x, acc1[m][2]);
            acc1[m][3] = fmaf(av[u], wb[u].y, acc1[m][3]);
        }
    }
}

// ================= K2: k_f2d — dual-sample conv2 + F2 GEMM, shared Wt stream =================
__global__ __launch_bounds__(256, 2) void k_f2d(
    const float* __restrict__ C1,
    const float* __restrict__ Wc2, const float* __restrict__ bc2,
    const float* __restrict__ Wt, const float* __restrict__ bt,
    float* __restrict__ F2) {
    const int b0 = blockIdx.x * 2, b1 = b0 + 1;
    const int t = threadIdx.x;
    __shared__ float buf0[S * 130], buf1[S * 130];  // staged C1 chunk; then xsl [ch][128]
    __shared__ float w2l[90 * 32];
    const int ct = t % 50, rt = t / 50;
    const int c3p = t & 63, sg = t >> 6;
    const int p0 = 2 * c3p;

    for (int idx = t; idx < 2700; idx += 256) {
        int ch = idx / 90, r = idx % 90;
        w2l[r * 32 + ch] = Wc2[idx];
    }
    for (int idx = t; idx < 180; idx += 256) {
        int r = idx >> 1, z = idx & 1;
        w2l[r * 32 + 30 + z] = 0.f;
    }
    float bias[8];
#pragma unroll
    for (int m = 0; m < 8; m++) {
        int ch = sg * 8 + m;
        bias[m] = bc2[ch < S ? ch : 0];
    }
    float acc0[6][4], acc1[6][4];
    zacc<6>(acc0); zacc<6>(acc1);

    for (int ks = 0; ks < 8; ks++) {
        for (int idx = t; idx < 1920; idx += 256) {
            int h = idx >= 960 ? 1 : 0;
            int r = idx - h * 960;
            int s = r >> 5, u = r & 31;
            float4 v = *(const float4*)(C1 + (size_t)((h ? b1 : b0) * S + s) * TT + ks * 128 + 4 * u);
            float* d = (h ? buf1 : buf0) + s * 130 + 1 + 4 * u;
            d[0] = v.x; d[1] = v.y; d[2] = v.z; d[3] = v.w;
        }
        if (t < 120) {
            int h = t / 60, r = t % 60;
            int s = r % S;
            const float* C1b = C1 + (size_t)((h ? b1 : b0) * S + s) * TT;
            float* bufh = h ? buf1 : buf0;
            if (r < S) {
                int gt = ks * 128 - 1;
                bufh[s * 130] = (gt >= 0) ? C1b[gt] : 0.f;
            } else {
                int gt = ks * 128 + 128;
                bufh[s * 130 + 129] = (gt < TT) ? C1b[gt] : 0.f;
            }
        }
        __syncthreads();
        float a00[8], a01[8], a10[8], a11[8];
#pragma unroll
        for (int m = 0; m < 8; m++) {
            a00[m] = bias[m]; a01[m] = bias[m];
            a10[m] = bias[m]; a11[m] = bias[m];
        }
        for (int si = 0; si < S; si++) {
            float2 va0 = *(const float2*)(buf0 + si * 130 + p0);
            float2 vb0 = *(const float2*)(buf0 + si * 130 + p0 + 2);
            float2 va1 = *(const float2*)(buf1 + si * 130 + p0);
            float2 vb1 = *(const float2*)(buf1 + si * 130 + p0 + 2);
            const float* wr = w2l + si * 96 + sg * 8;
            float4 w0a = *(const float4*)(wr);
            float4 w0b = *(const float4*)(wr + 4);
            float4 w1a = *(const float4*)(wr + 32);
            float4 w1b = *(const float4*)(wr + 36);
            float4 w2a = *(const float4*)(wr + 64);
            float4 w2b = *(const float4*)(wr + 68);
            float w0[8] = {w0a.x, w0a.y, w0a.z, w0a.w, w0b.x, w0b.y, w0b.z, w0b.w};
            float w1[8] = {w1a.x, w1a.y, w1a.z, w1a.w, w1b.x, w1b.y, w1b.z, w1b.w};
            float w2[8] = {w2a.x, w2a.y, w2a.z, w2a.w, w2b.x, w2b.y, w2b.z, w2b.w};
#pragma unroll
            for (int m = 0; m < 8; m++) {
                a00[m] = fmaf(w0[m], va0.x, fmaf(w1[m], va0.y, fmaf(w2[m], vb0.x, a00[m])));
                a01[m] = fmaf(w0[m], va0.y, fmaf(w1[m], vb0.x, fmaf(w2[m], vb0.y, a01[m])));
                a10[m] = fmaf(w0[m], va1.x, fmaf(w1[m], va1.y, fmaf(w2[m], vb1.x, a10[m])));
                a11[m] = fmaf(w0[m], va1.y, fmaf(w1[m], vb1.x, fmaf(w2[m], vb1.y, a11[m])));
            }
        }
        __syncthreads();
#pragma unroll
        for (int m = 0; m < 8; m++) {
            int ch = sg * 8 + m;
            if (ch < S) {
                float2 o0 = {fmaxf(a00[m], 0.f), fmaxf(a01[m], 0.f)};
                float2 o1 = {fmaxf(a10[m], 0.f), fmaxf(a11[m], 0.f)};
                *(float2*)(buf0 + ch * 128 + p0) = o0;
                *(float2*)(buf1 + ch * 128 + p0) = o1;
            }
        }
        __syncthreads();
        if (t < 250)
            gemm_w4_pf_dual<6, FD, 128>(buf0, buf1, 128, Wt + (size_t)ks * 128 * FD,
                                        ct, rt, acc0, acc1);
        __syncthreads();
    }
    if (t < 250) {
#pragma unroll
        for (int m = 0; m < 6; m++) {
            int row = rt * 6 + m;
            float4 o0, o1;
            o0.x = fmaxf(acc0[m][0] + bt[4 * ct + 0], 0.f);
            o0.y = fmaxf(acc0[m][1] + bt[4 * ct + 1], 0.f);
            o0.z = fmaxf(acc0[m][2] + bt[4 * ct + 2], 0.f);
            o0.w = fmaxf(acc0[m][3] + bt[4 * ct + 3], 0.f);
            o1.x = fmaxf(acc1[m][0] + bt[4 * ct + 0], 0.f);
            o1.y = fmaxf(acc1[m][1] + bt[4 * ct + 1], 0.f);
            o1.z = fmaxf(acc1[m][2] + bt[4 * ct + 2], 0.f);
            o1.w = fmaxf(acc1[m][3] + bt[4 * ct + 3], 0.f);
            *(float4*)(F2 + (size_t)(b0 * S + row) * FD + 4 * ct) = o0;
            *(float4*)(F2 + (size_t)(b1 * S + row) * FD + 4 * ct) = o1;
        }
    }
}

// ================= K3: k_att2 — dual-sample, shared W register streams =================
__global__ __launch_bounds__(256) void k_att2(
    const float* __restrict__ F2, const float* __restrict__ Wa,
    const float* __restrict__ adj, const float* __restrict__ Wl,
    const float* __restrict__ Wgl,
    float* __restrict__ AF, float* __restrict__ Gv) {
    const int b0 = blockIdx.x * 2, b1 = b0 + 1;
    const int t = threadIdx.x;
    __shared__ float A0[32 * FD], A1[32 * FD];    // F2 per sample, rows 30/31 zero
    __shared__ float Bu0[32 * FD], Bu1[32 * FD];  // P / T staging per sample
    __shared__ float scl0[1024], scl1[1024];      // scores -> A_F (stride 32)
    __shared__ float adjl[1024];
    for (int idx = t; idx < 1500; idx += 256) {
        *(float4*)(A0 + 4 * idx) = *(const float4*)(F2 + (size_t)b0 * S * FD + 4 * idx);
        *(float4*)(A1 + 4 * idx) = *(const float4*)(F2 + (size_t)b1 * S * FD + 4 * idx);
    }
    for (int idx = t; idx < 400; idx += 256) {
        A0[6000 + idx] = 0.f; A1[6000 + idx] = 0.f;
        Bu0[6000 + idx] = 0.f; Bu1[6000 + idx] = 0.f;
    }
    for (int idx = t; idx < 1024; idx += 256) {
        int r = idx >> 5, cc = idx & 31;
        adjl[idx] = (r < S && cc < S) ? adj[r * S + cc] : 0.f;
        scl0[idx] = 0.f; scl1[idx] = 0.f;
    }
    __syncthreads();
    const int ct = t % 50, rt = t / 50;
    float acc0[6][4], acc1[6][4];
    // P = F2 @ Wa (dual, shared W stream) -> Bu
    zacc<6>(acc0); zacc<6>(acc1);
    if (t < 250) {
        gemm_w4_pf_dual<6, FD, FD>(A0, A1, FD, Wa, ct, rt, acc0, acc1);
#pragma unroll
        for (int m = 0; m < 6; m++) {
            float4 o0 = {acc0[m][0], acc0[m][1], acc0[m][2], acc0[m][3]};
            float4 o1 = {acc1[m][0], acc1[m][1], acc1[m][2], acc1[m][3]};
            *(float4*)(Bu0 + (rt * 6 + m) * FD + 4 * ct) = o0;
            *(float4*)(Bu1 + (rt * 6 + m) * FD + 4 * ct) = o1;
        }
    }
    __syncthreads();
    // scl[i,j] = relu(P[i,:] . F2[j,:]) for both samples (1800 dots)
    for (int idx = t; idx < 2 * S * S; idx += 256) {
        int h = idx / (S * S), r = idx % (S * S);
        int i = r / S, j = r % S;
        const float* Pb = h ? Bu1 : Bu0;
        const float* Fb = h ? A1 : A0;
        float a = 0.f;
        for (int f4 = 0; f4 < 50; f4++) {
            float4 p = *(const float4*)(Pb + i * FD + 4 * f4);
            float4 q = *(const float4*)(Fb + j * FD + 4 * f4);
            a = fmaf(p.x, q.x, a); a = fmaf(p.y, q.y, a);
            a = fmaf(p.z, q.z, a); a = fmaf(p.w, q.w, a);
        }
        float* sc = h ? scl1 : scl0;
        sc[i * 32 + j] = fmaxf(a, 0.f);
    }
    __syncthreads();
    // softmax rows: lanes 0..29 -> sample0, lanes 64..93 -> sample1
    if (t < S) {
        float mx = -1e30f;
        for (int j = 0; j < S; j++) mx = fmaxf(mx, scl0[t * 32 + j]);
        float den = 0.f;
        for (int j = 0; j < S; j++) den += expf(scl0[t * 32 + j] - mx);
        float inv = 1.f / den;
        for (int j = 0; j < S; j++) scl0[t * 32 + j] = expf(scl0[t * 32 + j] - mx) * inv;
    } else if (t >= 64 && t < 64 + S) {
        int s = t - 64;
        float mx = -1e30f;
        for (int j = 0; j < S; j++) mx = fmaxf(mx, scl1[s * 32 + j]);
        float den = 0.f;
        for (int j = 0; j < S; j++) den += expf(scl1[s * 32 + j] - mx);
        float inv = 1.f / den;
        for (int j = 0; j < S; j++) scl1[s * 32 + j] = expf(scl1[s * 32 + j] - mx) * inv;
    }
    __syncthreads();
    for (int idx = t; idx < S * S; idx += 256) {
        int i = idx / S, j = idx % S;
        AF[(size_t)b0 * S * S + idx] = scl0[i * 32 + j];
        AF[(size_t)b1 * S * S + idx] = scl1[i * 32 + j];
    }
    // loc: T = adj@F2 (dual) -> Bu ; Gv[:, :150] = relu(T @ Wl) (dual W stream)
    zacc<6>(acc0); zacc<6>(acc1);
    if (t < 250) gemm_a32_dual<6>(adjl, A0, adjl, A1, FD, ct, rt, acc0, acc1);
    __syncthreads();
    if (t < 250) {
#pragma unroll
        for (int m = 0; m < 6; m++) {
            float4 o0 = {acc0[m][0], acc0[m][1], acc0[m][2], acc0[m][3]};
            float4 o1 = {acc1[m][0], acc1[m][1], acc1[m][2], acc1[m][3]};
            *(float4*)(Bu0 + (rt * 6 + m) * FD + 4 * ct) = o0;
            *(float4*)(Bu1 + (rt * 6 + m) * FD + 4 * ct) = o1;
        }
    }
    __syncthreads();
    const int ct2 = t % 38, rt2 = t / 38;
    const bool full = (4 * ct2 + 2) < 150;
    const int off23 = full ? 2 : -2;
    if (t < 228) {
        float a20[5][4], a21[5][4];
        zacc<5>(a20); zacc<5>(a21);
        gemm_w150_pf_dual(Bu0, Bu1, Wl, ct2, rt2, a20, a21, off23);
#pragma unroll
        for (int m = 0; m < 5; m++) {
            float* o0 = Gv + (size_t)(b0 * S + rt2 * 5 + m) * 300 + 4 * ct2;
            float* o1 = Gv + (size_t)(b1 * S + rt2 * 5 + m) * 300 + 4 * ct2;
            o0[0] = fmaxf(a20[m][0], 0.f); o0[1] = fmaxf(a20[m][1], 0.f);
            o1[0] = fmaxf(a21[m][0], 0.f); o1[1] = fmaxf(a21[m][1], 0.f);
            if (full) {
                o0[2] = fmaxf(a20[m][2], 0.f); o0[3] = fmaxf(a20[m][3], 0.f);
                o1[2] = fmaxf(a21[m][2], 0.f); o1[3] = fmaxf(a21[m][3], 0.f);
            }
        }
    }
    __syncthreads();
    // glb: T = AF@F2 (dual) -> Bu ; Gv[:, 150:] = relu(T @ Wgl) (dual W stream)
    zacc<6>(acc0); zacc<6>(acc1);
    if (t < 250) gemm_a32_dual<6>(scl0, A0, scl1, A1, FD, ct, rt, acc0, acc1);
    __syncthreads();
    if (t < 250) {
#pragma unroll
        for (int m = 0; m < 6; m++) {
            float4 o0 = {acc0[m][0], acc0[m][1], acc0[m][2], acc0[m][3]};
            float4 o1 = {acc1[m][0], acc1[m][1], acc1[m][2], acc1[m][3]};
            *(float4*)(Bu0 + (rt * 6 + m) * FD + 4 * ct) = o0;
            *(float4*)(Bu1 + (rt * 6 + m) * FD + 4 * ct) = o1;
        }
    }
    __syncthreads();
    if (t < 228) {
        float a20[5][4], a21[5][4];
        zacc<5>(a20); zacc<5>(a21);
        gemm_w150_pf_dual(Bu0, Bu1, Wgl, ct2, rt2, a20, a21, off23);
#pragma unroll
        for (int m = 0; m < 5; m++) {
            float* o0 = Gv + (size_t)(b0 * S + rt2 * 5 + m) * 300 + 150 + 4 * ct2;
            float* o1 = Gv + (size_t)(b1 * S + rt2 * 5 + m) * 300 + 150 + 4 * ct2;
            o0[0] = fmaxf(a20[m][0], 0.f); o0[1] = fmaxf(a20[m][1], 0.f);
            o1[0] = fmaxf(a21[m][0], 0.f); o1[1] = fmaxf(a21[m][1], 0.f);
            if (full) {
                o0[2] = fmaxf(a20[m][2], 0.f); o0[3] = fmaxf(a20[m][3], 0.f);
                o1[2] = fmaxf(a21[m][2], 0.f); o1[3] = fmaxf(a21[m][3], 0.f);
            }
        }
    }
}

// ================= K4: k_mgcn4 — 4 samples/block, shared W stream =================
// Quad extension of the thrice-verified W-sharing lever (dual gave −7% here in r4).
// LDS ≈ 126 KB -> 1 block/CU (1 wave/SIMD — proven non-cliff by r8 k_att2).
__global__ __launch_bounds__(256, 1) void k_mgcn4(
    const float* __restrict__ F2g, const float* __restrict__ AFg,
    const float* __restrict__ adj,
    const float* __restrict__ Wg1, const float* __restrict__ Wg2,
    const float* __restrict__ Wm1, const float* __restrict__ Wm2,
    const float* __restrict__ Wm3, const float* __restrict__ wg,
    const float* __restrict__ Wp1, const float* __restrict__ Wp2,
    const float* __restrict__ Wp3,
    float* __restrict__ Rws, float* __restrict__ Gh) {
    const int b0 = blockIdx.x * 4;
    const int t = threadIdx.x;
    __shared__ float A0[32 * FD], A1[32 * FD], A2[32 * FD], A3[32 * FD];
    __shared__ float afl0[1024], afl1[1024], afl2[1024], afl3[1024];
    __shared__ float adjl[1024];
    __shared__ float sk[384];
    __shared__ float gl[384];
    const int ct = t % 50, rt = t / 50;
    const int ct3 = t % 25, rt3 = t / 25;

    for (int idx = t; idx < 1500; idx += 256) {
        *(float4*)(A0 + 4 * idx) = *(const float4*)(F2g + (size_t)(b0 + 0) * S * FD + 4 * idx);
        *(float4*)(A1 + 4 * idx) = *(const float4*)(F2g + (size_t)(b0 + 1) * S * FD + 4 * idx);
        *(float4*)(A2 + 4 * idx) = *(const float4*)(F2g + (size_t)(b0 + 2) * S * FD + 4 * idx);
        *(float4*)(A3 + 4 * idx) = *(const float4*)(F2g + (size_t)(b0 + 3) * S * FD + 4 * idx);
    }
    for (int idx = t; idx < 400; idx += 256) {
        A0[6000 + idx] = 0.f; A1[6000 + idx] = 0.f;
        A2[6000 + idx] = 0.f; A3[6000 + idx] = 0.f;
    }
    for (int idx = t; idx < 1024; idx += 256) {
        int r = idx >> 5, cc = idx & 31;
        bool in = (r < S && cc < S);
        afl0[idx] = in ? AFg[(size_t)(b0 + 0) * S * S + r * S + cc] : 0.f;
        afl1[idx] = in ? AFg[(size_t)(b0 + 1) * S * S + r * S + cc] : 0.f;
        afl2[idx] = in ? AFg[(size_t)(b0 + 2) * S * S + r * S + cc] : 0.f;
        afl3[idx] = in ? AFg[(size_t)(b0 + 3) * S * S + r * S + cc] : 0.f;
        adjl[idx] = in ? adj[r * S + cc] : 0.f;
    }
    for (int idx = t; idx < 384; idx += 256) sk[idx] = 0.f;
    __syncthreads();

    float acc0[6][4], acc1[6][4], acc2[6][4], acc3[6][4];
    float xsr0[6][4], xsr1[6][4], xsr2[6][4], xsr3[6][4];

#define QZ() { zacc<6>(acc0); zacc<6>(acc1); zacc<6>(acc2); zacc<6>(acc3); }
#define QWRITE(RELU)                                                        \
    if (t < 250) {                                                          \
        _Pragma("unroll")                                                   \
        for (int m = 0; m < 6; m++) {                                       \
            float4 o0, o1, o2, o3;                                          \
            o0.x = RELU ? fmaxf(acc0[m][0], 0.f) : acc0[m][0];              \
            o0.y = RELU ? fmaxf(acc0[m][1], 0.f) : acc0[m][1];              \
            o0.z = RELU ? fmaxf(acc0[m][2], 0.f) : acc0[m][2];              \
            o0.w = RELU ? fmaxf(acc0[m][3], 0.f) : acc0[m][3];              \
            o1.x = RELU ? fmaxf(acc1[m][0], 0.f) : acc1[m][0];              \
            o1.y = RELU ? fmaxf(acc1[m][1], 0.f) : acc1[m][1];              \
            o1.z = RELU ? fmaxf(acc1[m][2], 0.f) : acc1[m][2];              \
            o1.w = RELU ? fmaxf(acc1[m][3], 0.f) : acc1[m][3];              \
            o2.x = RELU ? fmaxf(acc2[m][0], 0.f) : acc2[m][0];              \
            o2.y = RELU ? fmaxf(acc2[m][1], 0.f) : acc2[m][1];              \
            o2.z = RELU ? fmaxf(acc2[m][2], 0.f) : acc2[m][2];              \
            o2.w = RELU ? fmaxf(acc2[m][3], 0.f) : acc2[m][3];              \
            o3.x = RELU ? fmaxf(acc3[m][0], 0.f) : acc3[m][0];              \
            o3.y = RELU ? fmaxf(acc3[m][1], 0.f) : acc3[m][1];              \
            o3.z = RELU ? fmaxf(acc3[m][2], 0.f) : acc3[m][2];              \
            o3.w = RELU ? fmaxf(acc3[m][3], 0.f) : acc3[m][3];              \
            *(float4*)(A0 + (rt * 6 + m) * FD + 4 * ct) = o0;               \
            *(float4*)(A1 + (rt * 6 + m) * FD + 4 * ct) = o1;               \
            *(float4*)(A2 + (rt * 6 + m) * FD + 4 * ct) = o2;               \
            *(float4*)(A3 + (rt * 6 + m) * FD + 4 * ct) = o3;               \
        }                                                                   \
    }

    // ---- xs chain, in place (destroys F2 in A0..A3) ----
    QZ();
    if (t < 250) gemm_a32_quad<6>(adjl, A0, adjl, A1, adjl, A2, adjl, A3,
                                  FD, ct, rt, acc0, acc1, acc2, acc3);
    __syncthreads();
    QWRITE(false);
    __syncthreads();
    QZ();
    if (t < 250) gemm_w4_pf_quad<6, FD, FD>(A0, A1, A2, A3, FD, Wg1, ct, rt,
                                            acc0, acc1, acc2, acc3);
    __syncthreads();
    QWRITE(true);
    __syncthreads();
    QZ();
    if (t < 250) gemm_a32_quad<6>(adjl, A0, adjl, A1, adjl, A2, adjl, A3,
                                  FD, ct, rt, acc0, acc1, acc2, acc3);
    __syncthreads();
    QWRITE(false);
    __syncthreads();
    QZ();
    if (t < 250) gemm_w4_pf_quad<6, FD, FD>(A0, A1, A2, A3, FD, Wg2, ct, rt,
                                            acc0, acc1, acc2, acc3);
    __syncthreads();   // all reads of A=T2 done
#pragma unroll
    for (int m = 0; m < 6; m++) {
#pragma unroll
        for (int q = 0; q < 4; q++) {
            xsr0[m][q] = acc0[m][q]; xsr1[m][q] = acc1[m][q];
            xsr2[m][q] = acc2[m][q]; xsr3[m][q] = acc3[m][q];
        }
    }
    for (int idx = t; idx < 1500; idx += 256) {
        *(float4*)(A0 + 4 * idx) = *(const float4*)(F2g + (size_t)(b0 + 0) * S * FD + 4 * idx);
        *(float4*)(A1 + 4 * idx) = *(const float4*)(F2g + (size_t)(b0 + 1) * S * FD + 4 * idx);
        *(float4*)(A2 + 4 * idx) = *(const float4*)(F2g + (size_t)(b0 + 2) * S * FD + 4 * idx);
        *(float4*)(A3 + 4 * idx) = *(const float4*)(F2g + (size_t)(b0 + 3) * S * FD + 4 * idx);
    }
    __syncthreads();

    // ---- MGCN chain: k = 0,1,2 ----
    const float* Wm[3] = {Wm1, Wm2, Wm3};
    const float* Wp[3] = {Wp1, Wp2, Wp3};
#pragma unroll 1
    for (int k = 0; k < 3; k++) {
        // T = AF @ X
        QZ();
        if (t < 250) gemm_a32_quad<6>(afl0, A0, afl1, A1, afl2, A2, afl3, A3,
                                      FD, ct, rt, acc0, acc1, acc2, acc3);
        __syncthreads();
        QWRITE(false);
        __syncthreads();
        // X_k = relu(T @ Wm_k) in regs
        QZ();
        if (t < 250) gemm_w4_pf_quad<6, FD, FD>(A0, A1, A2, A3, FD, Wm[k], ct, rt,
                                                acc0, acc1, acc2, acc3);
        __syncthreads();   // reads of A=T done
        if (t < 250) {
#pragma unroll
            for (int m = 0; m < 6; m++) {
#pragma unroll
                for (int q = 0; q < 4; q++) {
                    acc0[m][q] = fmaxf(acc0[m][q], 0.f);
                    acc1[m][q] = fmaxf(acc1[m][q], 0.f);
                    acc2[m][q] = fmaxf(acc2[m][q], 0.f);
                    acc3[m][q] = fmaxf(acc3[m][q], 0.f);
                }
            }
#pragma unroll
            for (int m = 0; m < 6; m++) {
                int row = rt * 6 + m;
                float wg0 = wg[(4 * ct + 0) * 3 + k], wg1v = wg[(4 * ct + 1) * 3 + k];
                float wg2v = wg[(4 * ct + 2) * 3 + k], wg3 = wg[(4 * ct + 3) * 3 + k];
                float h0, h1, h2, h3;
                h0 = 0.5f * (acc0[m][0] + xsr0[m][0]);
                h1 = 0.5f * (acc0[m][1] + xsr0[m][1]);
                h2 = 0.5f * (acc0[m][2] + xsr0[m][2]);
                h3 = 0.5f * (acc0[m][3] + xsr0[m][3]);
                { float4 o = {h0, h1, h2, h3}; *(float4*)(A0 + row * FD + 4 * ct) = o; }
                atomicAdd(&sk[row * 3 + k], h0 * wg0 + h1 * wg1v + h2 * wg2v + h3 * wg3);
                h0 = 0.5f * (acc1[m][0] + xsr1[m][0]);
                h1 = 0.5f * (acc1[m][1] + xsr1[m][1]);
                h2 = 0.5f * (acc1[m][2] + xsr1[m][2]);
                h3 = 0.5f * (acc1[m][3] + xsr1[m][3]);
                { float4 o = {h0, h1, h2, h3}; *(float4*)(A1 + row * FD + 4 * ct) = o; }
                atomicAdd(&sk[96 + row * 3 + k], h0 * wg0 + h1 * wg1v + h2 * wg2v + h3 * wg3);
                h0 = 0.5f * (acc2[m][0] + xsr2[m][0]);
                h1 = 0.5f * (acc2[m][1] + xsr2[m][1]);
                h2 = 0.5f * (acc2[m][2] + xsr2[m][2]);
                h3 = 0.5f * (acc2[m][3] + xsr2[m][3]);
                { float4 o = {h0, h1, h2, h3}; *(float4*)(A2 + row * FD + 4 * ct) = o; }
                atomicAdd(&sk[192 + row * 3 + k], h0 * wg0 + h1 * wg1v + h2 * wg2v + h3 * wg3);
                h0 = 0.5f * (acc3[m][0] + xsr3[m][0]);
                h1 = 0.5f * (acc3[m][1] + xsr3[m][1]);
                h2 = 0.5f * (acc3[m][2] + xsr3[m][2]);
                h3 = 0.5f * (acc3[m][3] + xsr3[m][3]);
                { float4 o = {h0, h1, h2, h3}; *(float4*)(A3 + row * FD + 4 * ct) = o; }
                atomicAdd(&sk[288 + row * 3 + k], h0 * wg0 + h1 * wg1v + h2 * wg2v + h3 * wg3);
            }
        }
        __syncthreads();
        // R_k = H_k @ Wp_k -> workspace
        if (t < 250) {
            float a30[3][4], a31[3][4], a32[3][4], a33[3][4];
            zacc<3>(a30); zacc<3>(a31); zacc<3>(a32); zacc<3>(a33);
            gemm_w4_pf_quad<3, 100, FD>(A0, A1, A2, A3, FD, Wp[k], ct3, rt3,
                                        a30, a31, a32, a33);
#pragma unroll
            for (int m = 0; m < 3; m++) {
                float4 o0 = {a30[m][0], a30[m][1], a30[m][2], a30[m][3]};
                float4 o1 = {a31[m][0], a31[m][1], a31[m][2], a31[m][3]};
                float4 o2 = {a32[m][0], a32[m][1], a32[m][2], a32[m][3]};
                float4 o3 = {a33[m][0], a33[m][1], a33[m][2], a33[m][3]};
                *(float4*)(Rws + ((size_t)(k * BB + b0 + 0) * S + rt3 * 3 + m) * 100 + 4 * ct3) = o0;
                *(float4*)(Rws + ((size_t)(k * BB + b0 + 1) * S + rt3 * 3 + m) * 100 + 4 * ct3) = o1;
                *(float4*)(Rws + ((size_t)(k * BB + b0 + 2) * S + rt3 * 3 + m) * 100 + 4 * ct3) = o2;
                *(float4*)(Rws + ((size_t)(k * BB + b0 + 3) * S + rt3 * 3 + m) * 100 + 4 * ct3) = o3;
            }
        }
        __syncthreads();   // reads of A=H_k done
        if (k < 2) {
            QWRITE(false);   // acc already relu'd: restore X_k
            __syncthreads();
        }
    }

    // ---- gates: one lane-group of 30 per sample (4 wave groups) ----
    {
        int grp = t >> 6, lane = t & 63;
        if (lane < S) {
            int base = grp * 96;
            float a0 = sk[base + lane * 3 + 0];
            float a1 = sk[base + lane * 3 + 1];
            float a2 = sk[base + lane * 3 + 2];
            float m = fmaxf(a0, fmaxf(a1, a2));
            float e0 = expf(a0 - m), e1 = expf(a1 - m), e2 = expf(a2 - m);
            float inv = 1.f / (e0 + e1 + e2);
            gl[base + lane * 3 + 0] = e0 * inv;
            gl[base + lane * 3 + 1] = e1 * inv;
            gl[base + lane * 3 + 2] = e2 * inv;
        }
    }
    __syncthreads();

    // ---- G_k = adj @ diag(g_k) @ R_k ----
#pragma unroll 1
    for (int k = 0; k < 3; k++) {
        for (int idx = t; idx < 4 * S * 100; idx += 256) {
            int h = idx / 3000, r = idx % 3000;
            int row = r / 100, col = r % 100;
            float* Ah = (h == 0) ? A0 : (h == 1) ? A1 : (h == 2) ? A2 : A3;
            Ah[row * FD + col] = Rws[((size_t)(k * BB + b0 + h) * S) * 100 + r];
        }
        for (int idx = t; idx < 1024; idx += 256) {
            int cc = idx & 31;
            afl0[idx] = (cc < S) ? adjl[idx] * gl[cc * 3 + k] : 0.f;
            afl1[idx] = (cc < S) ? adjl[idx] * gl[96 + cc * 3 + k] : 0.f;
            afl2[idx] = (cc < S) ? adjl[idx] * gl[192 + cc * 3 + k] : 0.f;
            afl3[idx] = (cc < S) ? adjl[idx] * gl[288 + cc * 3 + k] : 0.f;
        }
        __syncthreads();
        if (t < 250) {
            float a30[3][4], a31[3][4], a32[3][4], a33[3][4];
            zacc<3>(a30); zacc<3>(a31); zacc<3>(a32); zacc<3>(a33);
            gemm_a32_quad<3>(afl0, A0, afl1, A1, afl2, A2, afl3, A3,
                             FD, ct3, rt3, a30, a31, a32, a33);
#pragma unroll
            for (int m = 0; m < 3; m++) {
                float4 o0 = {a30[m][0], a30[m][1], a30[m][2], a30[m][3]};
                float4 o1 = {a31[m][0], a31[m][1], a31[m][2], a31[m][3]};
                float4 o2 = {a32[m][0], a32[m][1], a32[m][2], a32[m][3]};
                float4 o3 = {a33[m][0], a33[m][1], a33[m][2], a33[m][3]};
                *(float4*)(Gh + (size_t)((b0 + 0) * S + rt3 * 3 + m) * 300 + k * 100 + 4 * ct3) = o0;
                *(float4*)(Gh + (size_t)((b0 + 1) * S + rt3 * 3 + m) * 300 + k * 100 + 4 * ct3) = o1;
                *(float4*)(Gh + (size_t)((b0 + 2) * S + rt3 * 3 + m) * 300 + k * 100 + 4 * ct3) = o2;
                *(float4*)(Gh + (size_t)((b0 + 3) * S + rt3 * 3 + m) * 300 + k * 100 + 4 * ct3) = o3;
            }
        }
        __syncthreads();
    }
#undef QZ
#undef QWRITE
}

// ================= K5: transpose Wcls -> WclsT[c][i] (once) =================
// NOTE: writes into the C1-overlay region -> must launch AFTER k_f2d.
__global__ __launch_bounds__(256) void k_tw(const float* __restrict__ Wcls,
                                            float* __restrict__ WclsT) {
    int idx = blockIdx.x * 256 + threadIdx.x;
    if (idx < S * 600 * NC) {
        int i = idx / NC, c = idx % NC;
        WclsT[c * (S * 600) + i] = Wcls[idx];
    }
}

// ================= K6: fused SE gates + classifier + log_softmax =================
__global__ __launch_bounds__(256) void k_secls(
    const float* __restrict__ Gh, const float* __restrict__ Gv,
    const float* __restrict__ Ws1, const float* __restrict__ Ws2,
    const float* __restrict__ Wf1, const float* __restrict__ Wf2,
    const float* __restrict__ WclsT, const float* __restrict__ bcls,
    float* __restrict__ out) {
    const int b = blockIdx.x, t = threadIdx.x;
    __shared__ float red[NC][256];
    __shared__ float mrow[S];
    __shared__ float u[15];
    __shared__ float mb[300];
    __shared__ float v[150];
    __shared__ float wftl[300];
    __shared__ float wchl[S];
    if (t < S) {
        float a = 0.f;
        const float* gp = Gv + ((size_t)b * S + t) * 300;
        for (int j = 0; j < 300; j++) a += gp[j];
        mrow[t] = a * (1.f / 300.f);
    }
    for (int j = t; j < 300; j += 256) {
        float a = 0.f;
        for (int s = 0; s < S; s++) a += Gh[(size_t)b * S * 300 + s * 300 + j];
        mb[j] = a * (1.f / S);
    }
    __syncthreads();
    if (t < 15) {
        float a = 0.f;
        for (int i = 0; i < S; i++) a += mrow[i] * Ws1[i * 15 + t];
        u[t] = fmaxf(a, 0.f);
    }
    if (t >= 64 && t < 64 + 150) {
        int h = t - 64;
        float a = 0.f;
        for (int j = 0; j < 300; j++) a += mb[j] * Wf1[j * 150 + h];
        v[h] = fmaxf(a, 0.f);
    }
    __syncthreads();
    if (t < S) {
        float a = 0.f;
        for (int h = 0; h < 15; h++) a += u[h] * Ws2[h * 30 + t];
        wchl[t] = 1.f / (1.f + expf(-a));
    }
    for (int j = t; j < 300; j += 256) {
        float a = 0.f;
        for (int h = 0; h < 150; h++) a += v[h] * Wf2[h * 300 + j];
        wftl[j] = 1.f / (1.f + expf(-a));
    }
    __syncthreads();
    float acc[NC];
#pragma unroll
    for (int c = 0; c < NC; c++) acc[c] = 0.f;
    for (int i = t; i < S * 600; i += 256) {
        int s = i / 600, j = i % 600;
        float gval = (j < 300)
            ? Gh[(size_t)b * S * 300 + s * 300 + j] * wchl[s]
            : Gv[(size_t)b * S * 300 + s * 300 + (j - 300)] * wftl[j - 300];
#pragma unroll
        for (int c = 0; c < NC; c++)
            acc[c] = fmaf(gval, WclsT[c * (S * 600) + i], acc[c]);
    }
#pragma unroll
    for (int c = 0; c < NC; c++) red[c][t] = acc[c];
    __syncthreads();
    for (int off = 128; off > 0; off >>= 1) {
        if (t < off) {
#pragma unroll
            for (int c = 0; c < NC; c++) red[c][t] += red[c][t + off];
        }
        __syncthreads();
    }
    if (t == 0) {
        float lg[NC];
        float mx = -1e30f;
#pragma unroll
        for (int c = 0; c < NC; c++) { lg[c] = red[c][0] + bcls[c]; mx = fmaxf(mx, lg[c]); }
        float den = 0.f;
#pragma unroll
        for (int c = 0; c < NC; c++) den += expf(lg[c] - mx);
        float lden = logf(den) + mx;
#pragma unroll
        for (int c = 0; c < NC; c++) out[b * NC + c] = lg[c] - lden;
    }
}

extern "C" void kernel_launch(void* const* d_in, const int* in_sizes, int n_in,
                              void* d_out, int out_size, void* d_ws, size_t ws_size,
                              hipStream_t stream) {
    const float* x    = (const float*)d_in[0];
    const float* adj  = (const float*)d_in[1];
    const float* Wc1  = (const float*)d_in[2];
    const float* bc1  = (const float*)d_in[3];
    const float* Wc2  = (const float*)d_in[4];
    const float* bc2  = (const float*)d_in[5];
    const float* Wt   = (const float*)d_in[6];
    const float* bt   = (const float*)d_in[7];
    const float* Wa   = (const float*)d_in[8];
    const float* Wm1  = (const float*)d_in[9];
    const float* Wm2  = (const float*)d_in[10];
    const float* Wm3  = (const float*)d_in[11];
    const float* Wg1  = (const float*)d_in[12];
    const float* Wg2  = (const float*)d_in[13];
    const float* wg   = (const float*)d_in[14];
    const float* Wp1  = (const float*)d_in[15];
    const float* Wp2  = (const float*)d_in[16];
    const float* Wp3  = (const float*)d_in[17];
    const float* Wl   = (const float*)d_in[18];
    const float* Wgl  = (const float*)d_in[19];
    const float* Ws1  = (const float*)d_in[20];
    const float* Ws2  = (const float*)d_in[21];
    const float* Wf1  = (const float*)d_in[22];
    const float* Wf2  = (const float*)d_in[23];
    const float* Wcls = (const float*)d_in[24];
    const float* bcls = (const float*)d_in[25];

    float* ws    = (float*)d_ws;
    float* C1    = ws + OFS_C1;
    float* F2    = ws + OFS_F2;
    float* AF    = ws + OFS_AF;
    float* GV    = ws + OFS_GV;
    float* GH    = ws + OFS_GH;
    float* RWS   = ws + OFS_R;
    float* WCLST = ws + OFS_WT;
    float* out   = (float*)d_out;

    k_conv1<<<dim3(4, BB), 256, 0, stream>>>(x, Wc1, bc1, C1);
    k_f2d<<<BB / 2, 256, 0, stream>>>(C1, Wc2, bc2, Wt, bt, F2);
    // k_tw writes into the (now dead) C1 overlay region -> must follow k_f2d.
    k_tw<<<(S * 600 * NC + 255) / 256, 256, 0, stream>>>(Wcls, WCLST);
    k_att2<<<BB / 2, 256, 0, stream>>>(F2, Wa, adj, Wl, Wgl, AF, GV);
    k_mgcn4<<<BB / 4, 256, 0, stream>>>(F2, AF, adj, Wg1, Wg2, Wm1, Wm2, Wm3, wg,
                                        Wp1, Wp2, Wp3, RWS, GH);
    k_secls<<<BB, 256, 0, stream>>>(GH, GV, Ws1, Ws2, Wf1, Wf2, WCLST, bcls, out);
}

// Round 11
// 1146.326 us; speedup vs baseline: 1.0996x; 1.0996x over previous
//
#include <hip/hip_runtime.h>
#include <math.h>

#define S   30
#define FD  200
#define TT  1024
#define BB  1024
#define NC  7

// ---- workspace layout (float offsets), overlaid by live range ----
// C1 occupies [0, 31457280) and is LIVE until k_f2 completes.
// AF/GV/GH/RWS/WclsT overlay the C1 region and may only be written AFTER k_f2.
#define OFS_C1   0ull
#define OFS_F2   31457280ull
#define OFS_AF   0ull
#define OFS_GV   921600ull
#define OFS_GH   10137600ull
#define OFS_R    19691520ull     // 3*1024*30*100 floats
#define OFS_WT   28907520ull     // WclsT: 7*18000 = 126,000 floats

// ================= K1: conv1 + relu -> C1 =================
__global__ __launch_bounds__(256) void k_conv1(
    const float* __restrict__ x,
    const float* __restrict__ Wc1, const float* __restrict__ bc1,
    float* __restrict__ C1) {
    const int c = blockIdx.x, b = blockIdx.y;
    const int t = threadIdx.x;
    const int t0 = c * 256;
    __shared__ float xb[S * 258];
    __shared__ float w1l[90 * 32];
    for (int idx = t; idx < 2700; idx += 256) {
        int so = idx / 90, r = idx % 90;
        w1l[r * 32 + so] = Wc1[idx];
    }
    for (int idx = t; idx < 180; idx += 256) {
        int r = idx >> 1, z = idx & 1;
        w1l[r * 32 + 30 + z] = 0.f;
    }
    for (int idx = t; idx < S * 64; idx += 256) {
        int s = idx >> 6, u = idx & 63;
        float4 v = *(const float4*)(x + (size_t)(b * S + s) * TT + t0 + 4 * u);
        float* d = xb + s * 258 + 1 + 4 * u;
        d[0] = v.x; d[1] = v.y; d[2] = v.z; d[3] = v.w;
    }
    if (t < 60) {
        int s = t % S;
        if (t < S) {
            int gt = t0 - 1;
            xb[s * 258] = (gt >= 0) ? x[(size_t)(b * S + s) * TT + gt] : 0.f;
        } else {
            int gt = t0 + 256;
            xb[s * 258 + 257] = (gt < TT) ? x[(size_t)(b * S + s) * TT + gt] : 0.f;
        }
    }
    __syncthreads();
    float acc[32];
#pragma unroll
    for (int so = 0; so < 32; so++) acc[so] = (so < S) ? bc1[so] : 0.f;
    for (int si = 0; si < S; si++) {
        float v0 = xb[si * 258 + t];
        float v1 = xb[si * 258 + t + 1];
        float v2 = xb[si * 258 + t + 2];
        const float* wr = w1l + si * 96;
#pragma unroll
        for (int u = 0; u < 8; u++) {
            float4 w0 = *(const float4*)(wr + 4 * u);
            float4 w1 = *(const float4*)(wr + 32 + 4 * u);
            float4 w2 = *(const float4*)(wr + 64 + 4 * u);
            acc[4 * u + 0] = fmaf(w0.x, v0, fmaf(w1.x, v1, fmaf(w2.x, v2, acc[4 * u + 0])));
            acc[4 * u + 1] = fmaf(w0.y, v0, fmaf(w1.y, v1, fmaf(w2.y, v2, acc[4 * u + 1])));
            acc[4 * u + 2] = fmaf(w0.z, v0, fmaf(w1.z, v1, fmaf(w2.z, v2, acc[4 * u + 2])));
            acc[4 * u + 3] = fmaf(w0.w, v0, fmaf(w1.w, v1, fmaf(w2.w, v2, acc[4 * u + 3])));
        }
    }
#pragma unroll
    for (int so = 0; so < 32; so++) {
        if (so < S)
            C1[(size_t)(b * S + so) * TT + t0 + t] = fmaxf(acc[so], 0.f);
    }
}

// ---------- FMA tile helpers ----------
#define FMA4(av, wv, accm)                           \
    {                                                \
        accm[0] = fmaf(av, (wv).x, accm[0]);         \
        accm[1] = fmaf(av, (wv).y, accm[1]);         \
        accm[2] = fmaf(av, (wv).z, accm[2]);         \
        accm[3] = fmaf(av, (wv).w, accm[3]);         \
    }

__device__ inline void fma_tile8(const float4 a0, const float4 a1,
                                 const float4 w[8], float accm[4]) {
    FMA4(a0.x, w[0], accm); FMA4(a0.y, w[1], accm);
    FMA4(a0.z, w[2], accm); FMA4(a0.w, w[3], accm);
    FMA4(a1.x, w[4], accm); FMA4(a1.y, w[5], accm);
    FMA4(a1.z, w[6], accm); FMA4(a1.w, w[7], accm);
}

template<int RPT>
__device__ inline void zacc(float acc[][4]) {
#pragma unroll
    for (int m = 0; m < RPT; m++)
#pragma unroll
        for (int q = 0; q < 4; q++) acc[m][q] = 0.f;
}

// ---------- gemm_w4_pf: X(LDS) @ W(global), depth-8 register pipeline ----------
template<int RPT, int N, int K>
__device__ inline void gemm_w4_pf(const float* Xl, int xstr, const float* __restrict__ W,
                                  int ct, int rt, float acc[][4]) {
    const float* wp = W + 4 * ct;
    float4 wreg[8];
#pragma unroll
    for (int u = 0; u < 8; u++) wreg[u] = *(const float4*)(wp + u * N);
#pragma unroll 1
    for (int kt = 0; kt < K / 8 - 1; kt++) {
        float4 wnxt[8];
#pragma unroll
        for (int u = 0; u < 8; u++) wnxt[u] = *(const float4*)(wp + (kt * 8 + 8 + u) * N);
#pragma unroll
        for (int m = 0; m < RPT; m++) {
            const float* xr = Xl + (rt * RPT + m) * xstr + kt * 8;
            float4 a0 = *(const float4*)(xr);
            float4 a1 = *(const float4*)(xr + 4);
            fma_tile8(a0, a1, wreg, acc[m]);
        }
#pragma unroll
        for (int u = 0; u < 8; u++) wreg[u] = wnxt[u];
    }
    {
        const int kb = K - 8;
#pragma unroll
        for (int m = 0; m < RPT; m++) {
            const float* xr = Xl + (rt * RPT + m) * xstr + kb;
            float4 a0 = *(const float4*)(xr);
            float4 a1 = *(const float4*)(xr + 4);
            fma_tile8(a0, a1, wreg, acc[m]);
        }
    }
}

// ---------- gemm_w4_pf_dual: shared W stream, two X buffers / acc sets ----------
template<int RPT, int N, int K>
__device__ inline void gemm_w4_pf_dual(const float* X0, const float* X1, int xstr,
                                       const float* __restrict__ W,
                                       int ct, int rt,
                                       float acc0[][4], float acc1[][4]) {
    const float* wp = W + 4 * ct;
    float4 wreg[8];
#pragma unroll
    for (int u = 0; u < 8; u++) wreg[u] = *(const float4*)(wp + u * N);
#pragma unroll 1
    for (int kt = 0; kt < K / 8 - 1; kt++) {
        float4 wnxt[8];
#pragma unroll
        for (int u = 0; u < 8; u++) wnxt[u] = *(const float4*)(wp + (kt * 8 + 8 + u) * N);
#pragma unroll
        for (int m = 0; m < RPT; m++) {
            const float* xr = X0 + (rt * RPT + m) * xstr + kt * 8;
            float4 a0 = *(const float4*)(xr);
            float4 a1 = *(const float4*)(xr + 4);
            fma_tile8(a0, a1, wreg, acc0[m]);
        }
#pragma unroll
        for (int m = 0; m < RPT; m++) {
            const float* xr = X1 + (rt * RPT + m) * xstr + kt * 8;
            float4 a0 = *(const float4*)(xr);
            float4 a1 = *(const float4*)(xr + 4);
            fma_tile8(a0, a1, wreg, acc1[m]);
        }
#pragma unroll
        for (int u = 0; u < 8; u++) wreg[u] = wnxt[u];
    }
    {
        const int kb = K - 8;
#pragma unroll
        for (int m = 0; m < RPT; m++) {
            const float* xr = X0 + (rt * RPT + m) * xstr + kb;
            float4 a0 = *(const float4*)(xr);
            float4 a1 = *(const float4*)(xr + 4);
            fma_tile8(a0, a1, wreg, acc0[m]);
        }
#pragma unroll
        for (int m = 0; m < RPT; m++) {
            const float* xr = X1 + (rt * RPT + m) * xstr + kb;
            float4 a0 = *(const float4*)(xr);
            float4 a1 = *(const float4*)(xr + 4);
            fma_tile8(a0, a1, wreg, acc1[m]);
        }
    }
}

// ---------- gemm_a32: Al(LDS, stride 32) @ Xl(LDS) ----------
template<int RPT>
__device__ inline void gemm_a32(const float* Al, const float* Xl, int xstr,
                                int ct, int rt, float acc[][4]) {
#pragma unroll
    for (int k4 = 0; k4 < 8; k4++) {
        float4 xv0 = *(const float4*)(Xl + (4 * k4 + 0) * xstr + 4 * ct);
        float4 xv1 = *(const float4*)(Xl + (4 * k4 + 1) * xstr + 4 * ct);
        float4 xv2 = *(const float4*)(Xl + (4 * k4 + 2) * xstr + 4 * ct);
        float4 xv3 = *(const float4*)(Xl + (4 * k4 + 3) * xstr + 4 * ct);
#pragma unroll
        for (int m = 0; m < RPT; m++) {
            float4 av = *(const float4*)(Al + (rt * RPT + m) * 32 + 4 * k4);
            FMA4(av.x, xv0, acc[m]);
            FMA4(av.y, xv1, acc[m]);
            FMA4(av.z, xv2, acc[m]);
            FMA4(av.w, xv3, acc[m]);
        }
    }
}

// ---------- gemm_a32_dual ----------
template<int RPT>
__device__ inline void gemm_a32_dual(const float* Al0, const float* X0,
                                     const float* Al1, const float* X1,
                                     int xstr, int ct, int rt,
                                     float acc0[][4], float acc1[][4]) {
#pragma unroll
    for (int k4 = 0; k4 < 8; k4++) {
        float4 x00 = *(const float4*)(X0 + (4 * k4 + 0) * xstr + 4 * ct);
        float4 x01 = *(const float4*)(X0 + (4 * k4 + 1) * xstr + 4 * ct);
        float4 x02 = *(const float4*)(X0 + (4 * k4 + 2) * xstr + 4 * ct);
        float4 x03 = *(const float4*)(X0 + (4 * k4 + 3) * xstr + 4 * ct);
        float4 x10 = *(const float4*)(X1 + (4 * k4 + 0) * xstr + 4 * ct);
        float4 x11 = *(const float4*)(X1 + (4 * k4 + 1) * xstr + 4 * ct);
        float4 x12 = *(const float4*)(X1 + (4 * k4 + 2) * xstr + 4 * ct);
        float4 x13 = *(const float4*)(X1 + (4 * k4 + 3) * xstr + 4 * ct);
#pragma unroll
        for (int m = 0; m < RPT; m++) {
            float4 av0 = *(const float4*)(Al0 + (rt * RPT + m) * 32 + 4 * k4);
            FMA4(av0.x, x00, acc0[m]);
            FMA4(av0.y, x01, acc0[m]);
            FMA4(av0.z, x02, acc0[m]);
            FMA4(av0.w, x03, acc0[m]);
            float4 av1 = *(const float4*)(Al1 + (rt * RPT + m) * 32 + 4 * k4);
            FMA4(av1.x, x10, acc1[m]);
            FMA4(av1.y, x11, acc1[m]);
            FMA4(av1.z, x12, acc1[m]);
            FMA4(av1.w, x13, acc1[m]);
        }
    }
}

// ---------- gemm_w150_pf: N=150, float2-pair columns ----------
__device__ inline void gemm_w150_pf(const float* Xl, const float* __restrict__ W,
                                    int ct2, int rt2, float acc[5][4], int off23) {
    const float* wp = W + 4 * ct2;
    float2 wa[8], wb[8];
#pragma unroll
    for (int u = 0; u < 8; u++) {
        wa[u] = *(const float2*)(wp + u * 150);
        wb[u] = *(const float2*)(wp + u * 150 + off23);
    }
#pragma unroll 1
    for (int kt = 0; kt < 24; kt++) {
        float2 na[8], nb[8];
#pragma unroll
        for (int u = 0; u < 8; u++) {
            int k = kt * 8 + 8 + u;
            na[u] = *(const float2*)(wp + k * 150);
            nb[u] = *(const float2*)(wp + k * 150 + off23);
        }
#pragma unroll
        for (int m = 0; m < 5; m++) {
            const float* xr = Xl + (rt2 * 5 + m) * FD + kt * 8;
            float4 a0 = *(const float4*)(xr);
            float4 a1 = *(const float4*)(xr + 4);
            float av[8] = {a0.x, a0.y, a0.z, a0.w, a1.x, a1.y, a1.z, a1.w};
#pragma unroll
            for (int u = 0; u < 8; u++) {
                acc[m][0] = fmaf(av[u], wa[u].x, acc[m][0]);
                acc[m][1] = fmaf(av[u], wa[u].y, acc[m][1]);
                acc[m][2] = fmaf(av[u], wb[u].x, acc[m][2]);
                acc[m][3] = fmaf(av[u], wb[u].y, acc[m][3]);
            }
        }
#pragma unroll
        for (int u = 0; u < 8; u++) { wa[u] = na[u]; wb[u] = nb[u]; }
    }
#pragma unroll
    for (int m = 0; m < 5; m++) {
        const float* xr = Xl + (rt2 * 5 + m) * FD + 192;
        float4 a0 = *(const float4*)(xr);
        float4 a1 = *(const float4*)(xr + 4);
        float av[8] = {a0.x, a0.y, a0.z, a0.w, a1.x, a1.y, a1.z, a1.w};
#pragma unroll
        for (int u = 0; u < 8; u++) {
            acc[m][0] = fmaf(av[u], wa[u].x, acc[m][0]);
            acc[m][1] = fmaf(av[u], wa[u].y, acc[m][1]);
            acc[m][2] = fmaf(av[u], wb[u].x, acc[m][2]);
            acc[m][3] = fmaf(av[u], wb[u].y, acc[m][3]);
        }
    }
}

// ---------- gemm_w150_pf_dual: shared W stream, two X buffers / acc sets ----------
__device__ inline void gemm_w150_pf_dual(const float* X0, const float* X1,
                                         const float* __restrict__ W,
                                         int ct2, int rt2,
                                         float acc0[5][4], float acc1[5][4], int off23) {
    const float* wp = W + 4 * ct2;
    float2 wa[8], wb[8];
#pragma unroll
    for (int u = 0; u < 8; u++) {
        wa[u] = *(const float2*)(wp + u * 150);
        wb[u] = *(const float2*)(wp + u * 150 + off23);
    }
#pragma unroll 1
    for (int kt = 0; kt < 24; kt++) {
        float2 na[8], nb[8];
#pragma unroll
        for (int u = 0; u < 8; u++) {
            int k = kt * 8 + 8 + u;
            na[u] = *(const float2*)(wp + k * 150);
            nb[u] = *(const float2*)(wp + k * 150 + off23);
        }
#pragma unroll
        for (int m = 0; m < 5; m++) {
            const float* xr = X0 + (rt2 * 5 + m) * FD + kt * 8;
            float4 a0 = *(const float4*)(xr);
            float4 a1 = *(const float4*)(xr + 4);
            float av[8] = {a0.x, a0.y, a0.z, a0.w, a1.x, a1.y, a1.z, a1.w};
#pragma unroll
            for (int u = 0; u < 8; u++) {
                acc0[m][0] = fmaf(av[u], wa[u].x, acc0[m][0]);
                acc0[m][1] = fmaf(av[u], wa[u].y, acc0[m][1]);
                acc0[m][2] = fmaf(av[u], wb[u].x, acc0[m][2]);
                acc0[m][3] = fmaf(av[u], wb[u].y, acc0[m][3]);
            }
        }
#pragma unroll
        for (int m = 0; m < 5; m++) {
            const float* xr = X1 + (rt2 * 5 + m) * FD + kt * 8;
            float4 a0 = *(const float4*)(xr);
            float4 a1 = *(const float4*)(xr + 4);
            float av[8] = {a0.x, a0.y, a0.z, a0.w, a1.x, a1.y, a1.z, a1.w};
#pragma unroll
            for (int u = 0; u < 8; u++) {
                acc1[m][0] = fmaf(av[u], wa[u].x, acc1[m][0]);
                acc1[m][1] = fmaf(av[u], wa[u].y, acc1[m][1]);
                acc1[m][2] = fmaf(av[u], wb[u].x, acc1[m][2]);
                acc1[m][3] = fmaf(av[u], wb[u].y, acc1[m][3]);
            }
        }
#pragma unroll
        for (int u = 0; u < 8; u++) { wa[u] = na[u]; wb[u] = nb[u]; }
    }
#pragma unroll
    for (int m = 0; m < 5; m++) {
        const float* xr = X0 + (rt2 * 5 + m) * FD + 192;
        float4 a0 = *(const float4*)(xr);
        float4 a1 = *(const float4*)(xr + 4);
        float av[8] = {a0.x, a0.y, a0.z, a0.w, a1.x, a1.y, a1.z, a1.w};
#pragma unroll
        for (int u = 0; u < 8; u++) {
            acc0[m][0] = fmaf(av[u], wa[u].x, acc0[m][0]);
            acc0[m][1] = fmaf(av[u], wa[u].y, acc0[m][1]);
            acc0[m][2] = fmaf(av[u], wb[u].x, acc0[m][2]);
            acc0[m][3] = fmaf(av[u], wb[u].y, acc0[m][3]);
        }
    }
#pragma unroll
    for (int m = 0; m < 5; m++) {
        const float* xr = X1 + (rt2 * 5 + m) * FD + 192;
        float4 a0 = *(const float4*)(xr);
        float4 a1 = *(const float4*)(xr + 4);
        float av[8] = {a0.x, a0.y, a0.z, a0.w, a1.x, a1.y, a1.z, a1.w};
#pragma unroll
        for (int u = 0; u < 8; u++) {
            acc1[m][0] = fmaf(av[u], wa[u].x, acc1[m][0]);
            acc1[m][1] = fmaf(av[u], wa[u].y, acc1[m][1]);
            acc1[m][2] = fmaf(av[u], wb[u].x, acc1[m][2]);
            acc1[m][3] = fmaf(av[u], wb[u].y, acc1[m][3]);
        }
    }
}

// ================= K2: conv2 fused + F2 = relu(h2 @ Wt + bt) =================
__global__ __launch_bounds__(256) void k_f2(
    const float* __restrict__ C1,
    const float* __restrict__ Wc2, const float* __restrict__ bc2,
    const float* __restrict__ Wt, const float* __restrict__ bt,
    float* __restrict__ F2) {
    const int b = blockIdx.x, t = threadIdx.x;
    __shared__ float buf[S * 130];
    __shared__ float w2l[90 * 32];
    const int ct = t % 50, rt = t / 50;
    const int c3p = t & 63, sg = t >> 6;
    const int p0 = 2 * c3p;

    for (int idx = t; idx < 2700; idx += 256) {
        int ch = idx / 90, r = idx % 90;
        w2l[r * 32 + ch] = Wc2[idx];
    }
    for (int idx = t; idx < 180; idx += 256) {
        int r = idx >> 1, z = idx & 1;
        w2l[r * 32 + 30 + z] = 0.f;
    }
    float bias[8];
#pragma unroll
    for (int m = 0; m < 8; m++) {
        int ch = sg * 8 + m;
        bias[m] = bc2[ch < S ? ch : 0];
    }
    float acc[6][4];
    zacc<6>(acc);

    for (int ks = 0; ks < 8; ks++) {
        for (int idx = t; idx < S * 32; idx += 256) {
            int s = idx >> 5, u = idx & 31;
            float4 v = *(const float4*)(C1 + (size_t)(b * S + s) * TT + ks * 128 + 4 * u);
            float* d = buf + s * 130 + 1 + 4 * u;
            d[0] = v.x; d[1] = v.y; d[2] = v.z; d[3] = v.w;
        }
        if (t < 60) {
            int s = t % S;
            if (t < S) {
                int gt = ks * 128 - 1;
                buf[s * 130] = (gt >= 0) ? C1[(size_t)(b * S + s) * TT + gt] : 0.f;
            } else {
                int gt = ks * 128 + 128;
                buf[s * 130 + 129] = (gt < TT) ? C1[(size_t)(b * S + s) * TT + gt] : 0.f;
            }
        }
        __syncthreads();
        float a0[8], a1[8];
#pragma unroll
        for (int m = 0; m < 8; m++) { a0[m] = bias[m]; a1[m] = bias[m]; }
        for (int si = 0; si < S; si++) {
            float2 va = *(const float2*)(buf + si * 130 + p0);
            float2 vb = *(const float2*)(buf + si * 130 + p0 + 2);
            const float* wr = w2l + si * 96 + sg * 8;
            float4 w0a = *(const float4*)(wr);
            float4 w0b = *(const float4*)(wr + 4);
            float4 w1a = *(const float4*)(wr + 32);
            float4 w1b = *(const float4*)(wr + 36);
            float4 w2a = *(const float4*)(wr + 64);
            float4 w2b = *(const float4*)(wr + 68);
            float w0[8] = {w0a.x, w0a.y, w0a.z, w0a.w, w0b.x, w0b.y, w0b.z, w0b.w};
            float w1[8] = {w1a.x, w1a.y, w1a.z, w1a.w, w1b.x, w1b.y, w1b.z, w1b.w};
            float w2[8] = {w2a.x, w2a.y, w2a.z, w2a.w, w2b.x, w2b.y, w2b.z, w2b.w};
#pragma unroll
            for (int m = 0; m < 8; m++) {
                a0[m] = fmaf(w0[m], va.x, fmaf(w1[m], va.y, fmaf(w2[m], vb.x, a0[m])));
                a1[m] = fmaf(w0[m], va.y, fmaf(w1[m], vb.x, fmaf(w2[m], vb.y, a1[m])));
            }
        }
        __syncthreads();
#pragma unroll
        for (int m = 0; m < 8; m++) {
            int ch = sg * 8 + m;
            if (ch < S) {
                float2 o = {fmaxf(a0[m], 0.f), fmaxf(a1[m], 0.f)};
                *(float2*)(buf + ch * 128 + p0) = o;
            }
        }
        __syncthreads();
        if (t < 250)
            gemm_w4_pf<6, FD, 128>(buf, 128, Wt + (size_t)ks * 128 * FD, ct, rt, acc);
        __syncthreads();
    }
    if (t < 250) {
#pragma unroll
        for (int m = 0; m < 6; m++) {
            int row = rt * 6 + m;
            float4 o;
            o.x = fmaxf(acc[m][0] + bt[4 * ct + 0], 0.f);
            o.y = fmaxf(acc[m][1] + bt[4 * ct + 1], 0.f);
            o.z = fmaxf(acc[m][2] + bt[4 * ct + 2], 0.f);
            o.w = fmaxf(acc[m][3] + bt[4 * ct + 3], 0.f);
            *(float4*)(F2 + (size_t)(b * S + row) * FD + 4 * ct) = o;
        }
    }
}

// ================= K3: k_att2 — dual-sample, shared W register streams =================
__global__ __launch_bounds__(256) void k_att2(
    const float* __restrict__ F2, const float* __restrict__ Wa,
    const float* __restrict__ adj, const float* __restrict__ Wl,
    const float* __restrict__ Wgl,
    float* __restrict__ AF, float* __restrict__ Gv) {
    const int b0 = blockIdx.x * 2, b1 = b0 + 1;
    const int t = threadIdx.x;
    __shared__ float A0[32 * FD], A1[32 * FD];    // F2 per sample, rows 30/31 zero
    __shared__ float Bu0[32 * FD], Bu1[32 * FD];  // P / T staging per sample
    __shared__ float scl0[1024], scl1[1024];      // scores -> A_F (stride 32)
    __shared__ float adjl[1024];
    for (int idx = t; idx < 1500; idx += 256) {
        *(float4*)(A0 + 4 * idx) = *(const float4*)(F2 + (size_t)b0 * S * FD + 4 * idx);
        *(float4*)(A1 + 4 * idx) = *(const float4*)(F2 + (size_t)b1 * S * FD + 4 * idx);
    }
    for (int idx = t; idx < 400; idx += 256) {
        A0[6000 + idx] = 0.f; A1[6000 + idx] = 0.f;
        Bu0[6000 + idx] = 0.f; Bu1[6000 + idx] = 0.f;
    }
    for (int idx = t; idx < 1024; idx += 256) {
        int r = idx >> 5, cc = idx & 31;
        adjl[idx] = (r < S && cc < S) ? adj[r * S + cc] : 0.f;
        scl0[idx] = 0.f; scl1[idx] = 0.f;
    }
    __syncthreads();
    const int ct = t % 50, rt = t / 50;
    float acc0[6][4], acc1[6][4];
    // P = F2 @ Wa (dual, shared W stream) -> Bu
    zacc<6>(acc0); zacc<6>(acc1);
    if (t < 250) {
        gemm_w4_pf_dual<6, FD, FD>(A0, A1, FD, Wa, ct, rt, acc0, acc1);
#pragma unroll
        for (int m = 0; m < 6; m++) {
            float4 o0 = {acc0[m][0], acc0[m][1], acc0[m][2], acc0[m][3]};
            float4 o1 = {acc1[m][0], acc1[m][1], acc1[m][2], acc1[m][3]};
            *(float4*)(Bu0 + (rt * 6 + m) * FD + 4 * ct) = o0;
            *(float4*)(Bu1 + (rt * 6 + m) * FD + 4 * ct) = o1;
        }
    }
    __syncthreads();
    // scl[i,j] = relu(P[i,:] . F2[j,:]) for both samples (1800 dots)
    for (int idx = t; idx < 2 * S * S; idx += 256) {
        int h = idx / (S * S), r = idx % (S * S);
        int i = r / S, j = r % S;
        const float* Pb = h ? Bu1 : Bu0;
        const float* Fb = h ? A1 : A0;
        float a = 0.f;
        for (int f4 = 0; f4 < 50; f4++) {
            float4 p = *(const float4*)(Pb + i * FD + 4 * f4);
            float4 q = *(const float4*)(Fb + j * FD + 4 * f4);
            a = fmaf(p.x, q.x, a); a = fmaf(p.y, q.y, a);
            a = fmaf(p.z, q.z, a); a = fmaf(p.w, q.w, a);
        }
        float* sc = h ? scl1 : scl0;
        sc[i * 32 + j] = fmaxf(a, 0.f);
    }
    __syncthreads();
    // softmax rows: lanes 0..29 -> sample0, lanes 64..93 -> sample1
    if (t < S) {
        float mx = -1e30f;
        for (int j = 0; j < S; j++) mx = fmaxf(mx, scl0[t * 32 + j]);
        float den = 0.f;
        for (int j = 0; j < S; j++) den += expf(scl0[t * 32 + j] - mx);
        float inv = 1.f / den;
        for (int j = 0; j < S; j++) scl0[t * 32 + j] = expf(scl0[t * 32 + j] - mx) * inv;
    } else if (t >= 64 && t < 64 + S) {
        int s = t - 64;
        float mx = -1e30f;
        for (int j = 0; j < S; j++) mx = fmaxf(mx, scl1[s * 32 + j]);
        float den = 0.f;
        for (int j = 0; j < S; j++) den += expf(scl1[s * 32 + j] - mx);
        float inv = 1.f / den;
        for (int j = 0; j < S; j++) scl1[s * 32 + j] = expf(scl1[s * 32 + j] - mx) * inv;
    }
    __syncthreads();
    for (int idx = t; idx < S * S; idx += 256) {
        int i = idx / S, j = idx % S;
        AF[(size_t)b0 * S * S + idx] = scl0[i * 32 + j];
        AF[(size_t)b1 * S * S + idx] = scl1[i * 32 + j];
    }
    // loc: T = adj@F2 (dual) -> Bu ; Gv[:, :150] = relu(T @ Wl) (dual W stream)
    zacc<6>(acc0); zacc<6>(acc1);
    if (t < 250) gemm_a32_dual<6>(adjl, A0, adjl, A1, FD, ct, rt, acc0, acc1);
    __syncthreads();
    if (t < 250) {
#pragma unroll
        for (int m = 0; m < 6; m++) {
            float4 o0 = {acc0[m][0], acc0[m][1], acc0[m][2], acc0[m][3]};
            float4 o1 = {acc1[m][0], acc1[m][1], acc1[m][2], acc1[m][3]};
            *(float4*)(Bu0 + (rt * 6 + m) * FD + 4 * ct) = o0;
            *(float4*)(Bu1 + (rt * 6 + m) * FD + 4 * ct) = o1;
        }
    }
    __syncthreads();
    const int ct2 = t % 38, rt2 = t / 38;
    const bool full = (4 * ct2 + 2) < 150;
    const int off23 = full ? 2 : -2;
    if (t < 228) {
        float a20[5][4], a21[5][4];
        zacc<5>(a20); zacc<5>(a21);
        gemm_w150_pf_dual(Bu0, Bu1, Wl, ct2, rt2, a20, a21, off23);
#pragma unroll
        for (int m = 0; m < 5; m++) {
            float* o0 = Gv + (size_t)(b0 * S + rt2 * 5 + m) * 300 + 4 * ct2;
            float* o1 = Gv + (size_t)(b1 * S + rt2 * 5 + m) * 300 + 4 * ct2;
            o0[0] = fmaxf(a20[m][0], 0.f); o0[1] = fmaxf(a20[m][1], 0.f);
            o1[0] = fmaxf(a21[m][0], 0.f); o1[1] = fmaxf(a21[m][1], 0.f);
            if (full) {
                o0[2] = fmaxf(a20[m][2], 0.f); o0[3] = fmaxf(a20[m][3], 0.f);
                o1[2] = fmaxf(a21[m][2], 0.f); o1[3] = fmaxf(a21[m][3], 0.f);
            }
        }
    }
    __syncthreads();
    // glb: T = AF@F2 (dual) -> Bu ; Gv[:, 150:] = relu(T @ Wgl) (dual W stream)
    zacc<6>(acc0); zacc<6>(acc1);
    if (t < 250) gemm_a32_dual<6>(scl0, A0, scl1, A1, FD, ct, rt, acc0, acc1);
    __syncthreads();
    if (t < 250) {
#pragma unroll
        for (int m = 0; m < 6; m++) {
            float4 o0 = {acc0[m][0], acc0[m][1], acc0[m][2], acc0[m][3]};
            float4 o1 = {acc1[m][0], acc1[m][1], acc1[m][2], acc1[m][3]};
            *(float4*)(Bu0 + (rt * 6 + m) * FD + 4 * ct) = o0;
            *(float4*)(Bu1 + (rt * 6 + m) * FD + 4 * ct) = o1;
        }
    }
    __syncthreads();
    if (t < 228) {
        float a20[5][4], a21[5][4];
        zacc<5>(a20); zacc<5>(a21);
        gemm_w150_pf_dual(Bu0, Bu1, Wgl, ct2, rt2, a20, a21, off23);
#pragma unroll
        for (int m = 0; m < 5; m++) {
            float* o0 = Gv + (size_t)(b0 * S + rt2 * 5 + m) * 300 + 150 + 4 * ct2;
            float* o1 = Gv + (size_t)(b1 * S + rt2 * 5 + m) * 300 + 150 + 4 * ct2;
            o0[0] = fmaxf(a20[m][0], 0.f); o0[1] = fmaxf(a20[m][1], 0.f);
            o1[0] = fmaxf(a21[m][0], 0.f); o1[1] = fmaxf(a21[m][1], 0.f);
            if (full) {
                o0[2] = fmaxf(a20[m][2], 0.f); o0[3] = fmaxf(a20[m][3], 0.f);
                o1[2] = fmaxf(a21[m][2], 0.f); o1[3] = fmaxf(a21[m][3], 0.f);
            }
        }
    }
}

// ================= K4: k_mgcn — 2 samples/block, shared W stream =================
// Dual is the verified optimum of the W-sharing lever (r4: −7%; r10 quad: −36% REGRESSION
// at 1 wave/SIMD — do not extend past dual on this kernel).
__global__ __launch_bounds__(256, 2) void k_mgcn(
    const float* __restrict__ F2g, const float* __restrict__ AFg,
    const float* __restrict__ adj,
    const float* __restrict__ Wg1, const float* __restrict__ Wg2,
    const float* __restrict__ Wm1, const float* __restrict__ Wm2,
    const float* __restrict__ Wm3, const float* __restrict__ wg,
    const float* __restrict__ Wp1, const float* __restrict__ Wp2,
    const float* __restrict__ Wp3,
    float* __restrict__ Rws, float* __restrict__ Gh) {
    const int b0 = blockIdx.x * 2, b1 = b0 + 1;
    const int t = threadIdx.x;
    __shared__ float A0[32 * FD], A1[32 * FD];
    __shared__ float afl0[1024], afl1[1024];
    __shared__ float adjl[1024];
    __shared__ float sk[192];
    __shared__ float gl[192];
    const int ct = t % 50, rt = t / 50;
    const int ct3 = t % 25, rt3 = t / 25;

    for (int idx = t; idx < 1500; idx += 256) {
        *(float4*)(A0 + 4 * idx) = *(const float4*)(F2g + (size_t)b0 * S * FD + 4 * idx);
        *(float4*)(A1 + 4 * idx) = *(const float4*)(F2g + (size_t)b1 * S * FD + 4 * idx);
    }
    for (int idx = t; idx < 400; idx += 256) { A0[6000 + idx] = 0.f; A1[6000 + idx] = 0.f; }
    for (int idx = t; idx < 1024; idx += 256) {
        int r = idx >> 5, cc = idx & 31;
        bool in = (r < S && cc < S);
        afl0[idx] = in ? AFg[(size_t)b0 * S * S + r * S + cc] : 0.f;
        afl1[idx] = in ? AFg[(size_t)b1 * S * S + r * S + cc] : 0.f;
        adjl[idx] = in ? adj[r * S + cc] : 0.f;
    }
    if (t < 192) sk[t] = 0.f;
    __syncthreads();

    float acc0[6][4], acc1[6][4], xsr0[6][4], xsr1[6][4];

#define DZ() { zacc<6>(acc0); zacc<6>(acc1); }
#define DWRITE(RELU)                                                        \
    if (t < 250) {                                                          \
        _Pragma("unroll")                                                   \
        for (int m = 0; m < 6; m++) {                                       \
            float4 o0, o1;                                                  \
            o0.x = RELU ? fmaxf(acc0[m][0], 0.f) : acc0[m][0];              \
            o0.y = RELU ? fmaxf(acc0[m][1], 0.f) : acc0[m][1];              \
            o0.z = RELU ? fmaxf(acc0[m][2], 0.f) : acc0[m][2];              \
            o0.w = RELU ? fmaxf(acc0[m][3], 0.f) : acc0[m][3];              \
            o1.x = RELU ? fmaxf(acc1[m][0], 0.f) : acc1[m][0];              \
            o1.y = RELU ? fmaxf(acc1[m][1], 0.f) : acc1[m][1];              \
            o1.z = RELU ? fmaxf(acc1[m][2], 0.f) : acc1[m][2];              \
            o1.w = RELU ? fmaxf(acc1[m][3], 0.f) : acc1[m][3];              \
            *(float4*)(A0 + (rt * 6 + m) * FD + 4 * ct) = o0;               \
            *(float4*)(A1 + (rt * 6 + m) * FD + 4 * ct) = o1;               \
        }                                                                   \
    }

    // ---- xs chain, in place (destroys F2 in A0/A1) ----
    DZ();
    if (t < 250) gemm_a32_dual<6>(adjl, A0, adjl, A1, FD, ct, rt, acc0, acc1);
    __syncthreads();
    DWRITE(false);
    __syncthreads();
    DZ();
    if (t < 250) gemm_w4_pf_dual<6, FD, FD>(A0, A1, FD, Wg1, ct, rt, acc0, acc1);
    __syncthreads();
    DWRITE(true);
    __syncthreads();
    DZ();
    if (t < 250) gemm_a32_dual<6>(adjl, A0, adjl, A1, FD, ct, rt, acc0, acc1);
    __syncthreads();
    DWRITE(false);
    __syncthreads();
    DZ();
    if (t < 250) gemm_w4_pf_dual<6, FD, FD>(A0, A1, FD, Wg2, ct, rt, acc0, acc1);
    __syncthreads();   // all reads of A=T2 done
#pragma unroll
    for (int m = 0; m < 6; m++) {
#pragma unroll
        for (int q = 0; q < 4; q++) { xsr0[m][q] = acc0[m][q]; xsr1[m][q] = acc1[m][q]; }
    }
    for (int idx = t; idx < 1500; idx += 256) {
        *(float4*)(A0 + 4 * idx) = *(const float4*)(F2g + (size_t)b0 * S * FD + 4 * idx);
        *(float4*)(A1 + 4 * idx) = *(const float4*)(F2g + (size_t)b1 * S * FD + 4 * idx);
    }
    __syncthreads();

    // ---- MGCN chain: k = 0,1,2 ----
    const float* Wm[3] = {Wm1, Wm2, Wm3};
    const float* Wp[3] = {Wp1, Wp2, Wp3};
#pragma unroll 1
    for (int k = 0; k < 3; k++) {
        // T = AF @ X
        DZ();
        if (t < 250) gemm_a32_dual<6>(afl0, A0, afl1, A1, FD, ct, rt, acc0, acc1);
        __syncthreads();
        DWRITE(false);
        __syncthreads();
        // X_k = relu(T @ Wm_k) in regs
        DZ();
        if (t < 250) gemm_w4_pf_dual<6, FD, FD>(A0, A1, FD, Wm[k], ct, rt, acc0, acc1);
        __syncthreads();   // reads of A=T done
        if (t < 250) {
#pragma unroll
            for (int m = 0; m < 6; m++) {
#pragma unroll
                for (int q = 0; q < 4; q++) {
                    acc0[m][q] = fmaxf(acc0[m][q], 0.f);
                    acc1[m][q] = fmaxf(acc1[m][q], 0.f);
                }
            }
#pragma unroll
            for (int m = 0; m < 6; m++) {
                int row = rt * 6 + m;
                float wg0 = wg[(4 * ct + 0) * 3 + k], wg1v = wg[(4 * ct + 1) * 3 + k];
                float wg2v = wg[(4 * ct + 2) * 3 + k], wg3 = wg[(4 * ct + 3) * 3 + k];
                float h00 = 0.5f * (acc0[m][0] + xsr0[m][0]);
                float h01 = 0.5f * (acc0[m][1] + xsr0[m][1]);
                float h02 = 0.5f * (acc0[m][2] + xsr0[m][2]);
                float h03 = 0.5f * (acc0[m][3] + xsr0[m][3]);
                float4 o0 = {h00, h01, h02, h03};
                *(float4*)(A0 + row * FD + 4 * ct) = o0;
                atomicAdd(&sk[row * 3 + k],
                          h00 * wg0 + h01 * wg1v + h02 * wg2v + h03 * wg3);
                float h10 = 0.5f * (acc1[m][0] + xsr1[m][0]);
                float h11 = 0.5f * (acc1[m][1] + xsr1[m][1]);
                float h12 = 0.5f * (acc1[m][2] + xsr1[m][2]);
                float h13 = 0.5f * (acc1[m][3] + xsr1[m][3]);
                float4 o1 = {h10, h11, h12, h13};
                *(float4*)(A1 + row * FD + 4 * ct) = o1;
                atomicAdd(&sk[96 + row * 3 + k],
                          h10 * wg0 + h11 * wg1v + h12 * wg2v + h13 * wg3);
            }
        }
        __syncthreads();
        // R_k = H_k @ Wp_k -> workspace
        if (t < 250) {
            float a30[3][4], a31[3][4];
            zacc<3>(a30); zacc<3>(a31);
            gemm_w4_pf_dual<3, 100, FD>(A0, A1, FD, Wp[k], ct3, rt3, a30, a31);
#pragma unroll
            for (int m = 0; m < 3; m++) {
                float4 o0 = {a30[m][0], a30[m][1], a30[m][2], a30[m][3]};
                float4 o1 = {a31[m][0], a31[m][1], a31[m][2], a31[m][3]};
                *(float4*)(Rws + ((size_t)(k * BB + b0) * S + rt3 * 3 + m) * 100 + 4 * ct3) = o0;
                *(float4*)(Rws + ((size_t)(k * BB + b1) * S + rt3 * 3 + m) * 100 + 4 * ct3) = o1;
            }
        }
        __syncthreads();   // reads of A=H_k done
        if (k < 2) {
            DWRITE(false);   // acc already relu'd: restore X_k
            __syncthreads();
        }
    }

    // ---- gates ----
    if (t < S) {
        float a0 = sk[t * 3 + 0], a1 = sk[t * 3 + 1], a2 = sk[t * 3 + 2];
        float m = fmaxf(a0, fmaxf(a1, a2));
        float e0 = expf(a0 - m), e1 = expf(a1 - m), e2 = expf(a2 - m);
        float inv = 1.f / (e0 + e1 + e2);
        gl[t * 3 + 0] = e0 * inv; gl[t * 3 + 1] = e1 * inv; gl[t * 3 + 2] = e2 * inv;
    } else if (t >= 64 && t < 64 + S) {
        int s = t - 64;
        float a0 = sk[96 + s * 3 + 0], a1 = sk[96 + s * 3 + 1], a2 = sk[96 + s * 3 + 2];
        float m = fmaxf(a0, fmaxf(a1, a2));
        float e0 = expf(a0 - m), e1 = expf(a1 - m), e2 = expf(a2 - m);
        float inv = 1.f / (e0 + e1 + e2);
        gl[96 + s * 3 + 0] = e0 * inv; gl[96 + s * 3 + 1] = e1 * inv; gl[96 + s * 3 + 2] = e2 * inv;
    }
    __syncthreads();

    // ---- G_k = adj @ diag(g_k) @ R_k ----
#pragma unroll 1
    for (int k = 0; k < 3; k++) {
        for (int idx = t; idx < S * 100; idx += 256) {
            int row = idx / 100, col = idx % 100;
            A0[row * FD + col] = Rws[((size_t)(k * BB + b0) * S) * 100 + idx];
            A1[row * FD + col] = Rws[((size_t)(k * BB + b1) * S) * 100 + idx];
        }
        for (int idx = t; idx < 1024; idx += 256) {
            int cc = idx & 31;
            afl0[idx] = (cc < S) ? adjl[idx] * gl[cc * 3 + k] : 0.f;
            afl1[idx] = (cc < S) ? adjl[idx] * gl[96 + cc * 3 + k] : 0.f;
        }
        __syncthreads();
        if (t < 250) {
            float a30[3][4], a31[3][4];
            zacc<3>(a30); zacc<3>(a31);
            gemm_a32_dual<3>(afl0, A0, afl1, A1, FD, ct3, rt3, a30, a31);
#pragma unroll
            for (int m = 0; m < 3; m++) {
                float4 o0 = {a30[m][0], a30[m][1], a30[m][2], a30[m][3]};
                float4 o1 = {a31[m][0], a31[m][1], a31[m][2], a31[m][3]};
                *(float4*)(Gh + (size_t)(b0 * S + rt3 * 3 + m) * 300 + k * 100 + 4 * ct3) = o0;
                *(float4*)(Gh + (size_t)(b1 * S + rt3 * 3 + m) * 300 + k * 100 + 4 * ct3) = o1;
            }
        }
        __syncthreads();
    }
#undef DZ
#undef DWRITE
}

// ================= K5: transpose Wcls -> WclsT[c][i] (once) =================
// NOTE: writes into the C1-overlay region -> must launch AFTER k_f2.
__global__ __launch_bounds__(256) void k_tw(const float* __restrict__ Wcls,
                                            float* __restrict__ WclsT) {
    int idx = blockIdx.x * 256 + threadIdx.x;
    if (idx < S * 600 * NC) {
        int i = idx / NC, c = idx % NC;
        WclsT[c * (S * 600) + i] = Wcls[idx];
    }
}

// ================= K6: fused SE gates + classifier + log_softmax =================
__global__ __launch_bounds__(256) void k_secls(
    const float* __restrict__ Gh, const float* __restrict__ Gv,
    const float* __restrict__ Ws1, const float* __restrict__ Ws2,
    const float* __restrict__ Wf1, const float* __restrict__ Wf2,
    const float* __restrict__ WclsT, const float* __restrict__ bcls,
    float* __restrict__ out) {
    const int b = blockIdx.x, t = threadIdx.x;
    __shared__ float red[NC][256];
    __shared__ float mrow[S];
    __shared__ float u[15];
    __shared__ float mb[300];
    __shared__ float v[150];
    __shared__ float wftl[300];
    __shared__ float wchl[S];
    if (t < S) {
        float a = 0.f;
        const float* gp = Gv + ((size_t)b * S + t) * 300;
        for (int j = 0; j < 300; j++) a += gp[j];
        mrow[t] = a * (1.f / 300.f);
    }
    for (int j = t; j < 300; j += 256) {
        float a = 0.f;
        for (int s = 0; s < S; s++) a += Gh[(size_t)b * S * 300 + s * 300 + j];
        mb[j] = a * (1.f / S);
    }
    __syncthreads();
    if (t < 15) {
        float a = 0.f;
        for (int i = 0; i < S; i++) a += mrow[i] * Ws1[i * 15 + t];
        u[t] = fmaxf(a, 0.f);
    }
    if (t >= 64 && t < 64 + 150) {
        int h = t - 64;
        float a = 0.f;
        for (int j = 0; j < 300; j++) a += mb[j] * Wf1[j * 150 + h];
        v[h] = fmaxf(a, 0.f);
    }
    __syncthreads();
    if (t < S) {
        float a = 0.f;
        for (int h = 0; h < 15; h++) a += u[h] * Ws2[h * 30 + t];
        wchl[t] = 1.f / (1.f + expf(-a));
    }
    for (int j = t; j < 300; j += 256) {
        float a = 0.f;
        for (int h = 0; h < 150; h++) a += v[h] * Wf2[h * 300 + j];
        wftl[j] = 1.f / (1.f + expf(-a));
    }
    __syncthreads();
    float acc[NC];
#pragma unroll
    for (int c = 0; c < NC; c++) acc[c] = 0.f;
    for (int i = t; i < S * 600; i += 256) {
        int s = i / 600, j = i % 600;
        float gval = (j < 300)
            ? Gh[(size_t)b * S * 300 + s * 300 + j] * wchl[s]
            : Gv[(size_t)b * S * 300 + s * 300 + (j - 300)] * wftl[j - 300];
#pragma unroll
        for (int c = 0; c < NC; c++)
            acc[c] = fmaf(gval, WclsT[c * (S * 600) + i], acc[c]);
    }
#pragma unroll
    for (int c = 0; c < NC; c++) red[c][t] = acc[c];
    __syncthreads();
    for (int off = 128; off > 0; off >>= 1) {
        if (t < off) {
#pragma unroll
            for (int c = 0; c < NC; c++) red[c][t] += red[c][t + off];
        }
        __syncthreads();
    }
    if (t == 0) {
        float lg[NC];
        float mx = -1e30f;
#pragma unroll
        for (int c = 0; c < NC; c++) { lg[c] = red[c][0] + bcls[c]; mx = fmaxf(mx, lg[c]); }
        float den = 0.f;
#pragma unroll
        for (int c = 0; c < NC; c++) den += expf(lg[c] - mx);
        float lden = logf(den) + mx;
#pragma unroll
        for (int c = 0; c < NC; c++) out[b * NC + c] = lg[c] - lden;
    }
}

extern "C" void kernel_launch(void* const* d_in, const int* in_sizes, int n_in,
                              void* d_out, int out_size, void* d_ws, size_t ws_size,
                              hipStream_t stream) {
    const float* x    = (const float*)d_in[0];
    const float* adj  = (const float*)d_in[1];
    const float* Wc1  = (const float*)d_in[2];
    const float* bc1  = (const float*)d_in[3];
    const float* Wc2  = (const float*)d_in[4];
    const float* bc2  = (const float*)d_in[5];
    const float* Wt   = (const float*)d_in[6];
    const float* bt   = (const float*)d_in[7];
    const float* Wa   = (const float*)d_in[8];
    const float* Wm1  = (const float*)d_in[9];
    const float* Wm2  = (const float*)d_in[10];
    const float* Wm3  = (const float*)d_in[11];
    const float* Wg1  = (const float*)d_in[12];
    const float* Wg2  = (const float*)d_in[13];
    const float* wg   = (const float*)d_in[14];
    const float* Wp1  = (const float*)d_in[15];
    const float* Wp2  = (const float*)d_in[16];
    const float* Wp3  = (const float*)d_in[17];
    const float* Wl   = (const float*)d_in[18];
    const float* Wgl  = (const float*)d_in[19];
    const float* Ws1  = (const float*)d_in[20];
    const float* Ws2  = (const float*)d_in[21];
    const float* Wf1  = (const float*)d_in[22];
    const float* Wf2  = (const float*)d_in[23];
    const float* Wcls = (const float*)d_in[24];
    const float* bcls = (const float*)d_in[25];

    float* ws    = (float*)d_ws;
    float* C1    = ws + OFS_C1;
    float* F2    = ws + OFS_F2;
    float* AF    = ws + OFS_AF;
    float* GV    = ws + OFS_GV;
    float* GH    = ws + OFS_GH;
    float* RWS   = ws + OFS_R;
    float* WCLST = ws + OFS_WT;
    float* out   = (float*)d_out;

    k_conv1<<<dim3(4, BB), 256, 0, stream>>>(x, Wc1, bc1, C1);
    k_f2<<<BB, 256, 0, stream>>>(C1, Wc2, bc2, Wt, bt, F2);
    // k_tw writes into the (now dead) C1 overlay region -> must follow k_f2.
    k_tw<<<(S * 600 * NC + 255) / 256, 256, 0, stream>>>(Wcls, WCLST);
    k_att2<<<BB / 2, 256, 0, stream>>>(F2, Wa, adj, Wl, Wgl, AF, GV);
    k_mgcn<<<BB / 2, 256, 0, stream>>>(F2, AF, adj, Wg1, Wg2, Wm1, Wm2, Wm3, wg,
                                       Wp1, Wp2, Wp3, RWS, GH);
    k_secls<<<BB, 256, 0, stream>>>(GH, GV, Ws1, Ws2, Wf1, Wf2, WCLST, bcls, out);
}

// Round 12
// 1109.901 us; speedup vs baseline: 1.1357x; 1.0328x over previous
//
#include <hip/hip_runtime.h>
#include <math.h>

#define S   30
#define FD  200
#define TT  1024
#define BB  1024
#define NC  7

// ---- workspace layout (float offsets), overlaid by live range ----
// C1 occupies [0, 31457280) and is LIVE until k_f2 completes.
// AF/GV/GH/RWS/WclsT overlay the C1 region and may only be written AFTER k_f2.
#define OFS_C1   0ull
#define OFS_F2   31457280ull
#define OFS_AF   0ull
#define OFS_GV   921600ull
#define OFS_GH   10137600ull
#define OFS_R    19691520ull     // 3*1024*30*100 floats
#define OFS_WT   28907520ull     // WclsT: 7*18000 = 126,000 floats

// ================= K1: conv1 + relu -> C1 =================
__global__ __launch_bounds__(256) void k_conv1(
    const float* __restrict__ x,
    const float* __restrict__ Wc1, const float* __restrict__ bc1,
    float* __restrict__ C1) {
    const int c = blockIdx.x, b = blockIdx.y;
    const int t = threadIdx.x;
    const int t0 = c * 256;
    __shared__ float xb[S * 258];
    __shared__ float w1l[90 * 32];
    for (int idx = t; idx < 2700; idx += 256) {
        int so = idx / 90, r = idx % 90;
        w1l[r * 32 + so] = Wc1[idx];
    }
    for (int idx = t; idx < 180; idx += 256) {
        int r = idx >> 1, z = idx & 1;
        w1l[r * 32 + 30 + z] = 0.f;
    }
    for (int idx = t; idx < S * 64; idx += 256) {
        int s = idx >> 6, u = idx & 63;
        float4 v = *(const float4*)(x + (size_t)(b * S + s) * TT + t0 + 4 * u);
        float* d = xb + s * 258 + 1 + 4 * u;
        d[0] = v.x; d[1] = v.y; d[2] = v.z; d[3] = v.w;
    }
    if (t < 60) {
        int s = t % S;
        if (t < S) {
            int gt = t0 - 1;
            xb[s * 258] = (gt >= 0) ? x[(size_t)(b * S + s) * TT + gt] : 0.f;
        } else {
            int gt = t0 + 256;
            xb[s * 258 + 257] = (gt < TT) ? x[(size_t)(b * S + s) * TT + gt] : 0.f;
        }
    }
    __syncthreads();
    float acc[32];
#pragma unroll
    for (int so = 0; so < 32; so++) acc[so] = (so < S) ? bc1[so] : 0.f;
    for (int si = 0; si < S; si++) {
        float v0 = xb[si * 258 + t];
        float v1 = xb[si * 258 + t + 1];
        float v2 = xb[si * 258 + t + 2];
        const float* wr = w1l + si * 96;
#pragma unroll
        for (int u = 0; u < 8; u++) {
            float4 w0 = *(const float4*)(wr + 4 * u);
            float4 w1 = *(const float4*)(wr + 32 + 4 * u);
            float4 w2 = *(const float4*)(wr + 64 + 4 * u);
            acc[4 * u + 0] = fmaf(w0.x, v0, fmaf(w1.x, v1, fmaf(w2.x, v2, acc[4 * u + 0])));
            acc[4 * u + 1] = fmaf(w0.y, v0, fmaf(w1.y, v1, fmaf(w2.y, v2, acc[4 * u + 1])));
            acc[4 * u + 2] = fmaf(w0.z, v0, fmaf(w1.z, v1, fmaf(w2.z, v2, acc[4 * u + 2])));
            acc[4 * u + 3] = fmaf(w0.w, v0, fmaf(w1.w, v1, fmaf(w2.w, v2, acc[4 * u + 3])));
        }
    }
#pragma unroll
    for (int so = 0; so < 32; so++) {
        if (so < S)
            C1[(size_t)(b * S + so) * TT + t0 + t] = fmaxf(acc[so], 0.f);
    }
}

// ---------- FMA tile helpers ----------
#define FMA4(av, wv, accm)                           \
    {                                                \
        accm[0] = fmaf(av, (wv).x, accm[0]);         \
        accm[1] = fmaf(av, (wv).y, accm[1]);         \
        accm[2] = fmaf(av, (wv).z, accm[2]);         \
        accm[3] = fmaf(av, (wv).w, accm[3]);         \
    }

__device__ inline void fma_tile8(const float4 a0, const float4 a1,
                                 const float4 w[8], float accm[4]) {
    FMA4(a0.x, w[0], accm); FMA4(a0.y, w[1], accm);
    FMA4(a0.z, w[2], accm); FMA4(a0.w, w[3], accm);
    FMA4(a1.x, w[4], accm); FMA4(a1.y, w[5], accm);
    FMA4(a1.z, w[6], accm); FMA4(a1.w, w[7], accm);
}

template<int RPT>
__device__ inline void zacc(float acc[][4]) {
#pragma unroll
    for (int m = 0; m < RPT; m++)
#pragma unroll
        for (int q = 0; q < 4; q++) acc[m][q] = 0.f;
}

// ---------- gemm_w4_pf: X(LDS) @ W(global), depth-8 register pipeline ----------
template<int RPT, int N, int K>
__device__ inline void gemm_w4_pf(const float* Xl, int xstr, const float* __restrict__ W,
                                  int ct, int rt, float acc[][4]) {
    const float* wp = W + 4 * ct;
    float4 wreg[8];
#pragma unroll
    for (int u = 0; u < 8; u++) wreg[u] = *(const float4*)(wp + u * N);
#pragma unroll 1
    for (int kt = 0; kt < K / 8 - 1; kt++) {
        float4 wnxt[8];
#pragma unroll
        for (int u = 0; u < 8; u++) wnxt[u] = *(const float4*)(wp + (kt * 8 + 8 + u) * N);
#pragma unroll
        for (int m = 0; m < RPT; m++) {
            const float* xr = Xl + (rt * RPT + m) * xstr + kt * 8;
            float4 a0 = *(const float4*)(xr);
            float4 a1 = *(const float4*)(xr + 4);
            fma_tile8(a0, a1, wreg, acc[m]);
        }
#pragma unroll
        for (int u = 0; u < 8; u++) wreg[u] = wnxt[u];
    }
    {
        const int kb = K - 8;
#pragma unroll
        for (int m = 0; m < RPT; m++) {
            const float* xr = Xl + (rt * RPT + m) * xstr + kb;
            float4 a0 = *(const float4*)(xr);
            float4 a1 = *(const float4*)(xr + 4);
            fma_tile8(a0, a1, wreg, acc[m]);
        }
    }
}

// ---------- gemm_w4_pf_dual: shared W stream, two X buffers / acc sets ----------
template<int RPT, int N, int K>
__device__ inline void gemm_w4_pf_dual(const float* X0, const float* X1, int xstr,
                                       const float* __restrict__ W,
                                       int ct, int rt,
                                       float acc0[][4], float acc1[][4]) {
    const float* wp = W + 4 * ct;
    float4 wreg[8];
#pragma unroll
    for (int u = 0; u < 8; u++) wreg[u] = *(const float4*)(wp + u * N);
#pragma unroll 1
    for (int kt = 0; kt < K / 8 - 1; kt++) {
        float4 wnxt[8];
#pragma unroll
        for (int u = 0; u < 8; u++) wnxt[u] = *(const float4*)(wp + (kt * 8 + 8 + u) * N);
#pragma unroll
        for (int m = 0; m < RPT; m++) {
            const float* xr = X0 + (rt * RPT + m) * xstr + kt * 8;
            float4 a0 = *(const float4*)(xr);
            float4 a1 = *(const float4*)(xr + 4);
            fma_tile8(a0, a1, wreg, acc0[m]);
        }
#pragma unroll
        for (int m = 0; m < RPT; m++) {
            const float* xr = X1 + (rt * RPT + m) * xstr + kt * 8;
            float4 a0 = *(const float4*)(xr);
            float4 a1 = *(const float4*)(xr + 4);
            fma_tile8(a0, a1, wreg, acc1[m]);
        }
#pragma unroll
        for (int u = 0; u < 8; u++) wreg[u] = wnxt[u];
    }
    {
        const int kb = K - 8;
#pragma unroll
        for (int m = 0; m < RPT; m++) {
            const float* xr = X0 + (rt * RPT + m) * xstr + kb;
            float4 a0 = *(const float4*)(xr);
            float4 a1 = *(const float4*)(xr + 4);
            fma_tile8(a0, a1, wreg, acc0[m]);
        }
#pragma unroll
        for (int m = 0; m < RPT; m++) {
            const float* xr = X1 + (rt * RPT + m) * xstr + kb;
            float4 a0 = *(const float4*)(xr);
            float4 a1 = *(const float4*)(xr + 4);
            fma_tile8(a0, a1, wreg, acc1[m]);
        }
    }
}

// ---------- gemm_a32: Al(LDS, stride 32) @ Xl(LDS) ----------
template<int RPT>
__device__ inline void gemm_a32(const float* Al, const float* Xl, int xstr,
                                int ct, int rt, float acc[][4]) {
#pragma unroll
    for (int k4 = 0; k4 < 8; k4++) {
        float4 xv0 = *(const float4*)(Xl + (4 * k4 + 0) * xstr + 4 * ct);
        float4 xv1 = *(const float4*)(Xl + (4 * k4 + 1) * xstr + 4 * ct);
        float4 xv2 = *(const float4*)(Xl + (4 * k4 + 2) * xstr + 4 * ct);
        float4 xv3 = *(const float4*)(Xl + (4 * k4 + 3) * xstr + 4 * ct);
#pragma unroll
        for (int m = 0; m < RPT; m++) {
            float4 av = *(const float4*)(Al + (rt * RPT + m) * 32 + 4 * k4);
            FMA4(av.x, xv0, acc[m]);
            FMA4(av.y, xv1, acc[m]);
            FMA4(av.z, xv2, acc[m]);
            FMA4(av.w, xv3, acc[m]);
        }
    }
}

// ---------- gemm_a32_dual ----------
template<int RPT>
__device__ inline void gemm_a32_dual(const float* Al0, const float* X0,
                                     const float* Al1, const float* X1,
                                     int xstr, int ct, int rt,
                                     float acc0[][4], float acc1[][4]) {
#pragma unroll
    for (int k4 = 0; k4 < 8; k4++) {
        float4 x00 = *(const float4*)(X0 + (4 * k4 + 0) * xstr + 4 * ct);
        float4 x01 = *(const float4*)(X0 + (4 * k4 + 1) * xstr + 4 * ct);
        float4 x02 = *(const float4*)(X0 + (4 * k4 + 2) * xstr + 4 * ct);
        float4 x03 = *(const float4*)(X0 + (4 * k4 + 3) * xstr + 4 * ct);
        float4 x10 = *(const float4*)(X1 + (4 * k4 + 0) * xstr + 4 * ct);
        float4 x11 = *(const float4*)(X1 + (4 * k4 + 1) * xstr + 4 * ct);
        float4 x12 = *(const float4*)(X1 + (4 * k4 + 2) * xstr + 4 * ct);
        float4 x13 = *(const float4*)(X1 + (4 * k4 + 3) * xstr + 4 * ct);
#pragma unroll
        for (int m = 0; m < RPT; m++) {
            float4 av0 = *(const float4*)(Al0 + (rt * RPT + m) * 32 + 4 * k4);
            FMA4(av0.x, x00, acc0[m]);
            FMA4(av0.y, x01, acc0[m]);
            FMA4(av0.z, x02, acc0[m]);
            FMA4(av0.w, x03, acc0[m]);
            float4 av1 = *(const float4*)(Al1 + (rt * RPT + m) * 32 + 4 * k4);
            FMA4(av1.x, x10, acc1[m]);
            FMA4(av1.y, x11, acc1[m]);
            FMA4(av1.z, x12, acc1[m]);
            FMA4(av1.w, x13, acc1[m]);
        }
    }
}

// ---------- gemm_w150_pf: N=150, float2-pair columns ----------
__device__ inline void gemm_w150_pf(const float* Xl, const float* __restrict__ W,
                                    int ct2, int rt2, float acc[5][4], int off23) {
    const float* wp = W + 4 * ct2;
    float2 wa[8], wb[8];
#pragma unroll
    for (int u = 0; u < 8; u++) {
        wa[u] = *(const float2*)(wp + u * 150);
        wb[u] = *(const float2*)(wp + u * 150 + off23);
    }
#pragma unroll 1
    for (int kt = 0; kt < 24; kt++) {
        float2 na[8], nb[8];
#pragma unroll
        for (int u = 0; u < 8; u++) {
            int k = kt * 8 + 8 + u;
            na[u] = *(const float2*)(wp + k * 150);
            nb[u] = *(const float2*)(wp + k * 150 + off23);
        }
#pragma unroll
        for (int m = 0; m < 5; m++) {
            const float* xr = Xl + (rt2 * 5 + m) * FD + kt * 8;
            float4 a0 = *(const float4*)(xr);
            float4 a1 = *(const float4*)(xr + 4);
            float av[8] = {a0.x, a0.y, a0.z, a0.w, a1.x, a1.y, a1.z, a1.w};
#pragma unroll
            for (int u = 0; u < 8; u++) {
                acc[m][0] = fmaf(av[u], wa[u].x, acc[m][0]);
                acc[m][1] = fmaf(av[u], wa[u].y, acc[m][1]);
                acc[m][2] = fmaf(av[u], wb[u].x, acc[m][2]);
                acc[m][3] = fmaf(av[u], wb[u].y, acc[m][3]);
            }
        }
#pragma unroll
        for (int u = 0; u < 8; u++) { wa[u] = na[u]; wb[u] = nb[u]; }
    }
#pragma unroll
    for (int m = 0; m < 5; m++) {
        const float* xr = Xl + (rt2 * 5 + m) * FD + 192;
        float4 a0 = *(const float4*)(xr);
        float4 a1 = *(const float4*)(xr + 4);
        float av[8] = {a0.x, a0.y, a0.z, a0.w, a1.x, a1.y, a1.z, a1.w};
#pragma unroll
        for (int u = 0; u < 8; u++) {
            acc[m][0] = fmaf(av[u], wa[u].x, acc[m][0]);
            acc[m][1] = fmaf(av[u], wa[u].y, acc[m][1]);
            acc[m][2] = fmaf(av[u], wb[u].x, acc[m][2]);
            acc[m][3] = fmaf(av[u], wb[u].y, acc[m][3]);
        }
    }
}

// ---------- gemm_w150_pf_dual: shared W stream, two X buffers / acc sets ----------
__device__ inline void gemm_w150_pf_dual(const float* X0, const float* X1,
                                         const float* __restrict__ W,
                                         int ct2, int rt2,
                                         float acc0[5][4], float acc1[5][4], int off23) {
    const float* wp = W + 4 * ct2;
    float2 wa[8], wb[8];
#pragma unroll
    for (int u = 0; u < 8; u++) {
        wa[u] = *(const float2*)(wp + u * 150);
        wb[u] = *(const float2*)(wp + u * 150 + off23);
    }
#pragma unroll 1
    for (int kt = 0; kt < 24; kt++) {
        float2 na[8], nb[8];
#pragma unroll
        for (int u = 0; u < 8; u++) {
            int k = kt * 8 + 8 + u;
            na[u] = *(const float2*)(wp + k * 150);
            nb[u] = *(const float2*)(wp + k * 150 + off23);
        }
#pragma unroll
        for (int m = 0; m < 5; m++) {
            const float* xr = X0 + (rt2 * 5 + m) * FD + kt * 8;
            float4 a0 = *(const float4*)(xr);
            float4 a1 = *(const float4*)(xr + 4);
            float av[8] = {a0.x, a0.y, a0.z, a0.w, a1.x, a1.y, a1.z, a1.w};
#pragma unroll
            for (int u = 0; u < 8; u++) {
                acc0[m][0] = fmaf(av[u], wa[u].x, acc0[m][0]);
                acc0[m][1] = fmaf(av[u], wa[u].y, acc0[m][1]);
                acc0[m][2] = fmaf(av[u], wb[u].x, acc0[m][2]);
                acc0[m][3] = fmaf(av[u], wb[u].y, acc0[m][3]);
            }
        }
#pragma unroll
        for (int m = 0; m < 5; m++) {
            const float* xr = X1 + (rt2 * 5 + m) * FD + kt * 8;
            float4 a0 = *(const float4*)(xr);
            float4 a1 = *(const float4*)(xr + 4);
            float av[8] = {a0.x, a0.y, a0.z, a0.w, a1.x, a1.y, a1.z, a1.w};
#pragma unroll
            for (int u = 0; u < 8; u++) {
                acc1[m][0] = fmaf(av[u], wa[u].x, acc1[m][0]);
                acc1[m][1] = fmaf(av[u], wa[u].y, acc1[m][1]);
                acc1[m][2] = fmaf(av[u], wb[u].x, acc1[m][2]);
                acc1[m][3] = fmaf(av[u], wb[u].y, acc1[m][3]);
            }
        }
#pragma unroll
        for (int u = 0; u < 8; u++) { wa[u] = na[u]; wb[u] = nb[u]; }
    }
#pragma unroll
    for (int m = 0; m < 5; m++) {
        const float* xr = X0 + (rt2 * 5 + m) * FD + 192;
        float4 a0 = *(const float4*)(xr);
        float4 a1 = *(const float4*)(xr + 4);
        float av[8] = {a0.x, a0.y, a0.z, a0.w, a1.x, a1.y, a1.z, a1.w};
#pragma unroll
        for (int u = 0; u < 8; u++) {
            acc0[m][0] = fmaf(av[u], wa[u].x, acc0[m][0]);
            acc0[m][1] = fmaf(av[u], wa[u].y, acc0[m][1]);
            acc0[m][2] = fmaf(av[u], wb[u].x, acc0[m][2]);
            acc0[m][3] = fmaf(av[u], wb[u].y, acc0[m][3]);
        }
    }
#pragma unroll
    for (int m = 0; m < 5; m++) {
        const float* xr = X1 + (rt2 * 5 + m) * FD + 192;
        float4 a0 = *(const float4*)(xr);
        float4 a1 = *(const float4*)(xr + 4);
        float av[8] = {a0.x, a0.y, a0.z, a0.w, a1.x, a1.y, a1.z, a1.w};
#pragma unroll
        for (int u = 0; u < 8; u++) {
            acc1[m][0] = fmaf(av[u], wa[u].x, acc1[m][0]);
            acc1[m][1] = fmaf(av[u], wa[u].y, acc1[m][1]);
            acc1[m][2] = fmaf(av[u], wb[u].x, acc1[m][2]);
            acc1[m][3] = fmaf(av[u], wb[u].y, acc1[m][3]);
        }
    }
}

// ================= K2: conv2 fused + F2 = relu(h2 @ Wt + bt) =================
__global__ __launch_bounds__(256) void k_f2(
    const float* __restrict__ C1,
    const float* __restrict__ Wc2, const float* __restrict__ bc2,
    const float* __restrict__ Wt, const float* __restrict__ bt,
    float* __restrict__ F2) {
    const int b = blockIdx.x, t = threadIdx.x;
    __shared__ float buf[S * 130];
    __shared__ float w2l[90 * 32];
    const int ct = t % 50, rt = t / 50;
    const int c3p = t & 63, sg = t >> 6;
    const int p0 = 2 * c3p;

    for (int idx = t; idx < 2700; idx += 256) {
        int ch = idx / 90, r = idx % 90;
        w2l[r * 32 + ch] = Wc2[idx];
    }
    for (int idx = t; idx < 180; idx += 256) {
        int r = idx >> 1, z = idx & 1;
        w2l[r * 32 + 30 + z] = 0.f;
    }
    float bias[8];
#pragma unroll
    for (int m = 0; m < 8; m++) {
        int ch = sg * 8 + m;
        bias[m] = bc2[ch < S ? ch : 0];
    }
    float acc[6][4];
    zacc<6>(acc);

    for (int ks = 0; ks < 8; ks++) {
        for (int idx = t; idx < S * 32; idx += 256) {
            int s = idx >> 5, u = idx & 31;
            float4 v = *(const float4*)(C1 + (size_t)(b * S + s) * TT + ks * 128 + 4 * u);
            float* d = buf + s * 130 + 1 + 4 * u;
            d[0] = v.x; d[1] = v.y; d[2] = v.z; d[3] = v.w;
        }
        if (t < 60) {
            int s = t % S;
            if (t < S) {
                int gt = ks * 128 - 1;
                buf[s * 130] = (gt >= 0) ? C1[(size_t)(b * S + s) * TT + gt] : 0.f;
            } else {
                int gt = ks * 128 + 128;
                buf[s * 130 + 129] = (gt < TT) ? C1[(size_t)(b * S + s) * TT + gt] : 0.f;
            }
        }
        __syncthreads();
        float a0[8], a1[8];
#pragma unroll
        for (int m = 0; m < 8; m++) { a0[m] = bias[m]; a1[m] = bias[m]; }
        for (int si = 0; si < S; si++) {
            float2 va = *(const float2*)(buf + si * 130 + p0);
            float2 vb = *(const float2*)(buf + si * 130 + p0 + 2);
            const float* wr = w2l + si * 96 + sg * 8;
            float4 w0a = *(const float4*)(wr);
            float4 w0b = *(const float4*)(wr + 4);
            float4 w1a = *(const float4*)(wr + 32);
            float4 w1b = *(const float4*)(wr + 36);
            float4 w2a = *(const float4*)(wr + 64);
            float4 w2b = *(const float4*)(wr + 68);
            float w0[8] = {w0a.x, w0a.y, w0a.z, w0a.w, w0b.x, w0b.y, w0b.z, w0b.w};
            float w1[8] = {w1a.x, w1a.y, w1a.z, w1a.w, w1b.x, w1b.y, w1b.z, w1b.w};
            float w2[8] = {w2a.x, w2a.y, w2a.z, w2a.w, w2b.x, w2b.y, w2b.z, w2b.w};
#pragma unroll
            for (int m = 0; m < 8; m++) {
                a0[m] = fmaf(w0[m], va.x, fmaf(w1[m], va.y, fmaf(w2[m], vb.x, a0[m])));
                a1[m] = fmaf(w0[m], va.y, fmaf(w1[m], vb.x, fmaf(w2[m], vb.y, a1[m])));
            }
        }
        __syncthreads();
#pragma unroll
        for (int m = 0; m < 8; m++) {
            int ch = sg * 8 + m;
            if (ch < S) {
                float2 o = {fmaxf(a0[m], 0.f), fmaxf(a1[m], 0.f)};
                *(float2*)(buf + ch * 128 + p0) = o;
            }
        }
        __syncthreads();
        if (t < 250)
            gemm_w4_pf<6, FD, 128>(buf, 128, Wt + (size_t)ks * 128 * FD, ct, rt, acc);
        __syncthreads();
    }
    if (t < 250) {
#pragma unroll
        for (int m = 0; m < 6; m++) {
            int row = rt * 6 + m;
            float4 o;
            o.x = fmaxf(acc[m][0] + bt[4 * ct + 0], 0.f);
            o.y = fmaxf(acc[m][1] + bt[4 * ct + 1], 0.f);
            o.z = fmaxf(acc[m][2] + bt[4 * ct + 2], 0.f);
            o.w = fmaxf(acc[m][3] + bt[4 * ct + 3], 0.f);
            *(float4*)(F2 + (size_t)(b * S + row) * FD + 4 * ct) = o;
        }
    }
}

// ================= K3: k_att2 — dual-sample, shared W register streams =================
__global__ __launch_bounds__(256) void k_att2(
    const float* __restrict__ F2, const float* __restrict__ Wa,
    const float* __restrict__ adj, const float* __restrict__ Wl,
    const float* __restrict__ Wgl,
    float* __restrict__ AF, float* __restrict__ Gv) {
    const int b0 = blockIdx.x * 2, b1 = b0 + 1;
    const int t = threadIdx.x;
    __shared__ float A0[32 * FD], A1[32 * FD];    // F2 per sample, rows 30/31 zero
    __shared__ float Bu0[32 * FD], Bu1[32 * FD];  // P / T staging per sample
    __shared__ float scl0[1024], scl1[1024];      // scores -> A_F (stride 32)
    __shared__ float adjl[1024];
    for (int idx = t; idx < 1500; idx += 256) {
        *(float4*)(A0 + 4 * idx) = *(const float4*)(F2 + (size_t)b0 * S * FD + 4 * idx);
        *(float4*)(A1 + 4 * idx) = *(const float4*)(F2 + (size_t)b1 * S * FD + 4 * idx);
    }
    for (int idx = t; idx < 400; idx += 256) {
        A0[6000 + idx] = 0.f; A1[6000 + idx] = 0.f;
        Bu0[6000 + idx] = 0.f; Bu1[6000 + idx] = 0.f;
    }
    for (int idx = t; idx < 1024; idx += 256) {
        int r = idx >> 5, cc = idx & 31;
        adjl[idx] = (r < S && cc < S) ? adj[r * S + cc] : 0.f;
        scl0[idx] = 0.f; scl1[idx] = 0.f;
    }
    __syncthreads();
    const int ct = t % 50, rt = t / 50;
    float acc0[6][4], acc1[6][4];
    // P = F2 @ Wa (dual, shared W stream) -> Bu
    zacc<6>(acc0); zacc<6>(acc1);
    if (t < 250) {
        gemm_w4_pf_dual<6, FD, FD>(A0, A1, FD, Wa, ct, rt, acc0, acc1);
#pragma unroll
        for (int m = 0; m < 6; m++) {
            float4 o0 = {acc0[m][0], acc0[m][1], acc0[m][2], acc0[m][3]};
            float4 o1 = {acc1[m][0], acc1[m][1], acc1[m][2], acc1[m][3]};
            *(float4*)(Bu0 + (rt * 6 + m) * FD + 4 * ct) = o0;
            *(float4*)(Bu1 + (rt * 6 + m) * FD + 4 * ct) = o1;
        }
    }
    __syncthreads();
    // scl[i,j] = relu(P[i,:] . F2[j,:]) for both samples (1800 dots)
    for (int idx = t; idx < 2 * S * S; idx += 256) {
        int h = idx / (S * S), r = idx % (S * S);
        int i = r / S, j = r % S;
        const float* Pb = h ? Bu1 : Bu0;
        const float* Fb = h ? A1 : A0;
        float a = 0.f;
        for (int f4 = 0; f4 < 50; f4++) {
            float4 p = *(const float4*)(Pb + i * FD + 4 * f4);
            float4 q = *(const float4*)(Fb + j * FD + 4 * f4);
            a = fmaf(p.x, q.x, a); a = fmaf(p.y, q.y, a);
            a = fmaf(p.z, q.z, a); a = fmaf(p.w, q.w, a);
        }
        float* sc = h ? scl1 : scl0;
        sc[i * 32 + j] = fmaxf(a, 0.f);
    }
    __syncthreads();
    // softmax rows: lanes 0..29 -> sample0, lanes 64..93 -> sample1
    if (t < S) {
        float mx = -1e30f;
        for (int j = 0; j < S; j++) mx = fmaxf(mx, scl0[t * 32 + j]);
        float den = 0.f;
        for (int j = 0; j < S; j++) den += expf(scl0[t * 32 + j] - mx);
        float inv = 1.f / den;
        for (int j = 0; j < S; j++) scl0[t * 32 + j] = expf(scl0[t * 32 + j] - mx) * inv;
    } else if (t >= 64 && t < 64 + S) {
        int s = t - 64;
        float mx = -1e30f;
        for (int j = 0; j < S; j++) mx = fmaxf(mx, scl1[s * 32 + j]);
        float den = 0.f;
        for (int j = 0; j < S; j++) den += expf(scl1[s * 32 + j] - mx);
        float inv = 1.f / den;
        for (int j = 0; j < S; j++) scl1[s * 32 + j] = expf(scl1[s * 32 + j] - mx) * inv;
    }
    __syncthreads();
    for (int idx = t; idx < S * S; idx += 256) {
        int i = idx / S, j = idx % S;
        AF[(size_t)b0 * S * S + idx] = scl0[i * 32 + j];
        AF[(size_t)b1 * S * S + idx] = scl1[i * 32 + j];
    }
    // loc: T = adj@F2 (dual) -> Bu ; Gv[:, :150] = relu(T @ Wl) (dual W stream)
    zacc<6>(acc0); zacc<6>(acc1);
    if (t < 250) gemm_a32_dual<6>(adjl, A0, adjl, A1, FD, ct, rt, acc0, acc1);
    __syncthreads();
    if (t < 250) {
#pragma unroll
        for (int m = 0; m < 6; m++) {
            float4 o0 = {acc0[m][0], acc0[m][1], acc0[m][2], acc0[m][3]};
            float4 o1 = {acc1[m][0], acc1[m][1], acc1[m][2], acc1[m][3]};
            *(float4*)(Bu0 + (rt * 6 + m) * FD + 4 * ct) = o0;
            *(float4*)(Bu1 + (rt * 6 + m) * FD + 4 * ct) = o1;
        }
    }
    __syncthreads();
    const int ct2 = t % 38, rt2 = t / 38;
    const bool full = (4 * ct2 + 2) < 150;
    const int off23 = full ? 2 : -2;
    if (t < 228) {
        float a20[5][4], a21[5][4];
        zacc<5>(a20); zacc<5>(a21);
        gemm_w150_pf_dual(Bu0, Bu1, Wl, ct2, rt2, a20, a21, off23);
#pragma unroll
        for (int m = 0; m < 5; m++) {
            float* o0 = Gv + (size_t)(b0 * S + rt2 * 5 + m) * 300 + 4 * ct2;
            float* o1 = Gv + (size_t)(b1 * S + rt2 * 5 + m) * 300 + 4 * ct2;
            o0[0] = fmaxf(a20[m][0], 0.f); o0[1] = fmaxf(a20[m][1], 0.f);
            o1[0] = fmaxf(a21[m][0], 0.f); o1[1] = fmaxf(a21[m][1], 0.f);
            if (full) {
                o0[2] = fmaxf(a20[m][2], 0.f); o0[3] = fmaxf(a20[m][3], 0.f);
                o1[2] = fmaxf(a21[m][2], 0.f); o1[3] = fmaxf(a21[m][3], 0.f);
            }
        }
    }
    __syncthreads();
    // glb: T = AF@F2 (dual) -> Bu ; Gv[:, 150:] = relu(T @ Wgl) (dual W stream)
    zacc<6>(acc0); zacc<6>(acc1);
    if (t < 250) gemm_a32_dual<6>(scl0, A0, scl1, A1, FD, ct, rt, acc0, acc1);
    __syncthreads();
    if (t < 250) {
#pragma unroll
        for (int m = 0; m < 6; m++) {
            float4 o0 = {acc0[m][0], acc0[m][1], acc0[m][2], acc0[m][3]};
            float4 o1 = {acc1[m][0], acc1[m][1], acc1[m][2], acc1[m][3]};
            *(float4*)(Bu0 + (rt * 6 + m) * FD + 4 * ct) = o0;
            *(float4*)(Bu1 + (rt * 6 + m) * FD + 4 * ct) = o1;
        }
    }
    __syncthreads();
    if (t < 228) {
        float a20[5][4], a21[5][4];
        zacc<5>(a20); zacc<5>(a21);
        gemm_w150_pf_dual(Bu0, Bu1, Wgl, ct2, rt2, a20, a21, off23);
#pragma unroll
        for (int m = 0; m < 5; m++) {
            float* o0 = Gv + (size_t)(b0 * S + rt2 * 5 + m) * 300 + 150 + 4 * ct2;
            float* o1 = Gv + (size_t)(b1 * S + rt2 * 5 + m) * 300 + 150 + 4 * ct2;
            o0[0] = fmaxf(a20[m][0], 0.f); o0[1] = fmaxf(a20[m][1], 0.f);
            o1[0] = fmaxf(a21[m][0], 0.f); o1[1] = fmaxf(a21[m][1], 0.f);
            if (full) {
                o0[2] = fmaxf(a20[m][2], 0.f); o0[3] = fmaxf(a20[m][3], 0.f);
                o1[2] = fmaxf(a21[m][2], 0.f); o1[3] = fmaxf(a21[m][3], 0.f);
            }
        }
    }
}

// ================= K4: k_mgcn — 2 samples/block, shared W stream =================
// Dual is the verified optimum of the W-sharing lever (r4: −7%; r10 quad: −36% REGRESSION
// at 1 wave/SIMD — do not extend past dual on this kernel).
__global__ __launch_bounds__(256, 2) void k_mgcn(
    const float* __restrict__ F2g, const float* __restrict__ AFg,
    const float* __restrict__ adj,
    const float* __restrict__ Wg1, const float* __restrict__ Wg2,
    const float* __restrict__ Wm1, const float* __restrict__ Wm2,
    const float* __restrict__ Wm3, const float* __restrict__ wg,
    const float* __restrict__ Wp1, const float* __restrict__ Wp2,
    const float* __restrict__ Wp3,
    float* __restrict__ Rws, float* __restrict__ Gh) {
    const int b0 = blockIdx.x * 2, b1 = b0 + 1;
    const int t = threadIdx.x;
    __shared__ float A0[32 * FD], A1[32 * FD];
    __shared__ float afl0[1024], afl1[1024];
    __shared__ float adjl[1024];
    __shared__ float sk[192];
    __shared__ float gl[192];
    const int ct = t % 50, rt = t / 50;
    const int ct3 = t % 25, rt3 = t / 25;

    for (int idx = t; idx < 1500; idx += 256) {
        *(float4*)(A0 + 4 * idx) = *(const float4*)(F2g + (size_t)b0 * S * FD + 4 * idx);
        *(float4*)(A1 + 4 * idx) = *(const float4*)(F2g + (size_t)b1 * S * FD + 4 * idx);
    }
    for (int idx = t; idx < 400; idx += 256) { A0[6000 + idx] = 0.f; A1[6000 + idx] = 0.f; }
    for (int idx = t; idx < 1024; idx += 256) {
        int r = idx >> 5, cc = idx & 31;
        bool in = (r < S && cc < S);
        afl0[idx] = in ? AFg[(size_t)b0 * S * S + r * S + cc] : 0.f;
        afl1[idx] = in ? AFg[(size_t)b1 * S * S + r * S + cc] : 0.f;
        adjl[idx] = in ? adj[r * S + cc] : 0.f;
    }
    if (t < 192) sk[t] = 0.f;
    __syncthreads();

    float acc0[6][4], acc1[6][4], xsr0[6][4], xsr1[6][4];

#define DZ() { zacc<6>(acc0); zacc<6>(acc1); }
#define DWRITE(RELU)                                                        \
    if (t < 250) {                                                          \
        _Pragma("unroll")                                                   \
        for (int m = 0; m < 6; m++) {                                       \
            float4 o0, o1;                                                  \
            o0.x = RELU ? fmaxf(acc0[m][0], 0.f) : acc0[m][0];              \
            o0.y = RELU ? fmaxf(acc0[m][1], 0.f) : acc0[m][1];              \
            o0.z = RELU ? fmaxf(acc0[m][2], 0.f) : acc0[m][2];              \
            o0.w = RELU ? fmaxf(acc0[m][3], 0.f) : acc0[m][3];              \
            o1.x = RELU ? fmaxf(acc1[m][0], 0.f) : acc1[m][0];              \
            o1.y = RELU ? fmaxf(acc1[m][1], 0.f) : acc1[m][1];              \
            o1.z = RELU ? fmaxf(acc1[m][2], 0.f) : acc1[m][2];              \
            o1.w = RELU ? fmaxf(acc1[m][3], 0.f) : acc1[m][3];              \
            *(float4*)(A0 + (rt * 6 + m) * FD + 4 * ct) = o0;               \
            *(float4*)(A1 + (rt * 6 + m) * FD + 4 * ct) = o1;               \
        }                                                                   \
    }

    // ---- xs chain, in place (destroys F2 in A0/A1) ----
    DZ();
    if (t < 250) gemm_a32_dual<6>(adjl, A0, adjl, A1, FD, ct, rt, acc0, acc1);
    __syncthreads();
    DWRITE(false);
    __syncthreads();
    DZ();
    if (t < 250) gemm_w4_pf_dual<6, FD, FD>(A0, A1, FD, Wg1, ct, rt, acc0, acc1);
    __syncthreads();
    DWRITE(true);
    __syncthreads();
    DZ();
    if (t < 250) gemm_a32_dual<6>(adjl, A0, adjl, A1, FD, ct, rt, acc0, acc1);
    __syncthreads();
    DWRITE(false);
    __syncthreads();
    DZ();
    if (t < 250) gemm_w4_pf_dual<6, FD, FD>(A0, A1, FD, Wg2, ct, rt, acc0, acc1);
    __syncthreads();   // all reads of A=T2 done
#pragma unroll
    for (int m = 0; m < 6; m++) {
#pragma unroll
        for (int q = 0; q < 4; q++) { xsr0[m][q] = acc0[m][q]; xsr1[m][q] = acc1[m][q]; }
    }
    for (int idx = t; idx < 1500; idx += 256) {
        *(float4*)(A0 + 4 * idx) = *(const float4*)(F2g + (size_t)b0 * S * FD + 4 * idx);
        *(float4*)(A1 + 4 * idx) = *(const float4*)(F2g + (size_t)b1 * S * FD + 4 * idx);
    }
    __syncthreads();

    // ---- MGCN chain: k = 0,1,2 ----
    const float* Wm[3] = {Wm1, Wm2, Wm3};
    const float* Wp[3] = {Wp1, Wp2, Wp3};
#pragma unroll 1
    for (int k = 0; k < 3; k++) {
        // T = AF @ X
        DZ();
        if (t < 250) gemm_a32_dual<6>(afl0, A0, afl1, A1, FD, ct, rt, acc0, acc1);
        __syncthreads();
        DWRITE(false);
        __syncthreads();
        // X_k = relu(T @ Wm_k) in regs
        DZ();
        if (t < 250) gemm_w4_pf_dual<6, FD, FD>(A0, A1, FD, Wm[k], ct, rt, acc0, acc1);
        __syncthreads();   // reads of A=T done
        if (t < 250) {
#pragma unroll
            for (int m = 0; m < 6; m++) {
#pragma unroll
                for (int q = 0; q < 4; q++) {
                    acc0[m][q] = fmaxf(acc0[m][q], 0.f);
                    acc1[m][q] = fmaxf(acc1[m][q], 0.f);
                }
            }
#pragma unroll
            for (int m = 0; m < 6; m++) {
                int row = rt * 6 + m;
                float wg0 = wg[(4 * ct + 0) * 3 + k], wg1v = wg[(4 * ct + 1) * 3 + k];
                float wg2v = wg[(4 * ct + 2) * 3 + k], wg3 = wg[(4 * ct + 3) * 3 + k];
                float h00 = 0.5f * (acc0[m][0] + xsr0[m][0]);
                float h01 = 0.5f * (acc0[m][1] + xsr0[m][1]);
                float h02 = 0.5f * (acc0[m][2] + xsr0[m][2]);
                float h03 = 0.5f * (acc0[m][3] + xsr0[m][3]);
                float4 o0 = {h00, h01, h02, h03};
                *(float4*)(A0 + row * FD + 4 * ct) = o0;
                atomicAdd(&sk[row * 3 + k],
                          h00 * wg0 + h01 * wg1v + h02 * wg2v + h03 * wg3);
                float h10 = 0.5f * (acc1[m][0] + xsr1[m][0]);
                float h11 = 0.5f * (acc1[m][1] + xsr1[m][1]);
                float h12 = 0.5f * (acc1[m][2] + xsr1[m][2]);
                float h13 = 0.5f * (acc1[m][3] + xsr1[m][3]);
                float4 o1 = {h10, h11, h12, h13};
                *(float4*)(A1 + row * FD + 4 * ct) = o1;
                atomicAdd(&sk[96 + row * 3 + k],
                          h10 * wg0 + h11 * wg1v + h12 * wg2v + h13 * wg3);
            }
        }
        __syncthreads();
        // R_k = H_k @ Wp_k -> workspace
        if (t < 250) {
            float a30[3][4], a31[3][4];
            zacc<3>(a30); zacc<3>(a31);
            gemm_w4_pf_dual<3, 100, FD>(A0, A1, FD, Wp[k], ct3, rt3, a30, a31);
#pragma unroll
            for (int m = 0; m < 3; m++) {
                float4 o0 = {a30[m][0], a30[m][1], a30[m][2], a30[m][3]};
                float4 o1 = {a31[m][0], a31[m][1], a31[m][2], a31[m][3]};
                *(float4*)(Rws + ((size_t)(k * BB + b0) * S + rt3 * 3 + m) * 100 + 4 * ct3) = o0;
                *(float4*)(Rws + ((size_t)(k * BB + b1) * S + rt3 * 3 + m) * 100 + 4 * ct3) = o1;
            }
        }
        __syncthreads();   // reads of A=H_k done
        if (k < 2) {
            DWRITE(false);   // acc already relu'd: restore X_k
            __syncthreads();
        }
    }

    // ---- gates ----
    if (t < S) {
        float a0 = sk[t * 3 + 0], a1 = sk[t * 3 + 1], a2 = sk[t * 3 + 2];
        float m = fmaxf(a0, fmaxf(a1, a2));
        float e0 = expf(a0 - m), e1 = expf(a1 - m), e2 = expf(a2 - m);
        float inv = 1.f / (e0 + e1 + e2);
        gl[t * 3 + 0] = e0 * inv; gl[t * 3 + 1] = e1 * inv; gl[t * 3 + 2] = e2 * inv;
    } else if (t >= 64 && t < 64 + S) {
        int s = t - 64;
        float a0 = sk[96 + s * 3 + 0], a1 = sk[96 + s * 3 + 1], a2 = sk[96 + s * 3 + 2];
        float m = fmaxf(a0, fmaxf(a1, a2));
        float e0 = expf(a0 - m), e1 = expf(a1 - m), e2 = expf(a2 - m);
        float inv = 1.f / (e0 + e1 + e2);
        gl[96 + s * 3 + 0] = e0 * inv; gl[96 + s * 3 + 1] = e1 * inv; gl[96 + s * 3 + 2] = e2 * inv;
    }
    __syncthreads();

    // ---- G_k = adj @ diag(g_k) @ R_k ----
#pragma unroll 1
    for (int k = 0; k < 3; k++) {
        for (int idx = t; idx < S * 100; idx += 256) {
            int row = idx / 100, col = idx % 100;
            A0[row * FD + col] = Rws[((size_t)(k * BB + b0) * S) * 100 + idx];
            A1[row * FD + col] = Rws[((size_t)(k * BB + b1) * S) * 100 + idx];
        }
        for (int idx = t; idx < 1024; idx += 256) {
            int cc = idx & 31;
            afl0[idx] = (cc < S) ? adjl[idx] * gl[cc * 3 + k] : 0.f;
            afl1[idx] = (cc < S) ? adjl[idx] * gl[96 + cc * 3 + k] : 0.f;
        }
        __syncthreads();
        if (t < 250) {
            float a30[3][4], a31[3][4];
            zacc<3>(a30); zacc<3>(a31);
            gemm_a32_dual<3>(afl0, A0, afl1, A1, FD, ct3, rt3, a30, a31);
#pragma unroll
            for (int m = 0; m < 3; m++) {
                float4 o0 = {a30[m][0], a30[m][1], a30[m][2], a30[m][3]};
                float4 o1 = {a31[m][0], a31[m][1], a31[m][2], a31[m][3]};
                *(float4*)(Gh + (size_t)(b0 * S + rt3 * 3 + m) * 300 + k * 100 + 4 * ct3) = o0;
                *(float4*)(Gh + (size_t)(b1 * S + rt3 * 3 + m) * 300 + k * 100 + 4 * ct3) = o1;
            }
        }
        __syncthreads();
    }
#undef DZ
#undef DWRITE
}

// ================= K5: transpose Wcls -> WclsT[c][i] (once) =================
// NOTE: writes into the C1-overlay region -> must launch AFTER k_f2.
__global__ __launch_bounds__(256) void k_tw(const float* __restrict__ Wcls,
                                            float* __restrict__ WclsT) {
    int idx = blockIdx.x * 256 + threadIdx.x;
    if (idx < S * 600 * NC) {
        int i = idx / NC, c = idx % NC;
        WclsT[c * (S * 600) + i] = Wcls[idx];
    }
}

// ================= K6: fused SE gates + classifier + log_softmax =================
// r12: instruction-count reduction (the one verified mechanism class):
//  - mrow row-sums vectorized to float4 (rows are 1200 B = 16 B aligned).
//  - classifier loop processes 2 consecutive i per iteration: even pairs never
//    straddle the Gh/Gv boundary (300 even) or a row boundary (600 even), so
//    data and WclsT load as float2; loads and div/mod halved.
__global__ __launch_bounds__(256) void k_secls(
    const float* __restrict__ Gh, const float* __restrict__ Gv,
    const float* __restrict__ Ws1, const float* __restrict__ Ws2,
    const float* __restrict__ Wf1, const float* __restrict__ Wf2,
    const float* __restrict__ WclsT, const float* __restrict__ bcls,
    float* __restrict__ out) {
    const int b = blockIdx.x, t = threadIdx.x;
    __shared__ float red[NC][256];
    __shared__ float mrow[S];
    __shared__ float u[15];
    __shared__ float mb[300];
    __shared__ float v[150];
    __shared__ float wftl[300];
    __shared__ float wchl[S];
    if (t < S) {
        float a = 0.f;
        const float* gp = Gv + ((size_t)b * S + t) * 300;
        for (int j4 = 0; j4 < 75; j4++) {
            float4 w = *(const float4*)(gp + 4 * j4);
            a += (w.x + w.y) + (w.z + w.w);
        }
        mrow[t] = a * (1.f / 300.f);
    }
    for (int j = t; j < 300; j += 256) {
        float a = 0.f;
        for (int s = 0; s < S; s++) a += Gh[(size_t)b * S * 300 + s * 300 + j];
        mb[j] = a * (1.f / S);
    }
    __syncthreads();
    if (t < 15) {
        float a = 0.f;
        for (int i = 0; i < S; i++) a += mrow[i] * Ws1[i * 15 + t];
        u[t] = fmaxf(a, 0.f);
    }
    if (t >= 64 && t < 64 + 150) {
        int h = t - 64;
        float a = 0.f;
        for (int j = 0; j < 300; j++) a += mb[j] * Wf1[j * 150 + h];
        v[h] = fmaxf(a, 0.f);
    }
    __syncthreads();
    if (t < S) {
        float a = 0.f;
        for (int h = 0; h < 15; h++) a += u[h] * Ws2[h * 30 + t];
        wchl[t] = 1.f / (1.f + expf(-a));
    }
    for (int j = t; j < 300; j += 256) {
        float a = 0.f;
        for (int h = 0; h < 150; h++) a += v[h] * Wf2[h * 300 + j];
        wftl[j] = 1.f / (1.f + expf(-a));
    }
    __syncthreads();
    float acc[NC];
#pragma unroll
    for (int c = 0; c < NC; c++) acc[c] = 0.f;
    // paired classifier loop: i = 2*i2, i2 in [0, 9000)
    for (int i2 = t; i2 < S * 300; i2 += 256) {
        int s = i2 / 300, jj = i2 % 300;
        int i = 2 * i2;                       // = s*600 + 2*jj
        float2 d2;
        float sc0, sc1;
        if (jj < 150) {
            d2 = *(const float2*)(Gh + (size_t)b * S * 300 + s * 300 + 2 * jj);
            sc0 = wchl[s]; sc1 = sc0;
        } else {
            int j2 = 2 * jj - 300;
            d2 = *(const float2*)(Gv + (size_t)b * S * 300 + s * 300 + j2);
            sc0 = wftl[j2]; sc1 = wftl[j2 + 1];
        }
        float g0 = d2.x * sc0, g1 = d2.y * sc1;
#pragma unroll
        for (int c = 0; c < NC; c++) {
            float2 w2 = *(const float2*)(WclsT + c * (S * 600) + i);
            acc[c] = fmaf(g1, w2.y, fmaf(g0, w2.x, acc[c]));
        }
    }
#pragma unroll
    for (int c = 0; c < NC; c++) red[c][t] = acc[c];
    __syncthreads();
    for (int off = 128; off > 0; off >>= 1) {
        if (t < off) {
#pragma unroll
            for (int c = 0; c < NC; c++) red[c][t] += red[c][t + off];
        }
        __syncthreads();
    }
    if (t == 0) {
        float lg[NC];
        float mx = -1e30f;
#pragma unroll
        for (int c = 0; c < NC; c++) { lg[c] = red[c][0] + bcls[c]; mx = fmaxf(mx, lg[c]); }
        float den = 0.f;
#pragma unroll
        for (int c = 0; c < NC; c++) den += expf(lg[c] - mx);
        float lden = logf(den) + mx;
#pragma unroll
        for (int c = 0; c < NC; c++) out[b * NC + c] = lg[c] - lden;
    }
}

extern "C" void kernel_launch(void* const* d_in, const int* in_sizes, int n_in,
                              void* d_out, int out_size, void* d_ws, size_t ws_size,
                              hipStream_t stream) {
    const float* x    = (const float*)d_in[0];
    const float* adj  = (const float*)d_in[1];
    const float* Wc1  = (const float*)d_in[2];
    const float* bc1  = (const float*)d_in[3];
    const float* Wc2  = (const float*)d_in[4];
    const float* bc2  = (const float*)d_in[5];
    const float* Wt   = (const float*)d_in[6];
    const float* bt   = (const float*)d_in[7];
    const float* Wa   = (const float*)d_in[8];
    const float* Wm1  = (const float*)d_in[9];
    const float* Wm2  = (const float*)d_in[10];
    const float* Wm3  = (const float*)d_in[11];
    const float* Wg1  = (const float*)d_in[12];
    const float* Wg2  = (const float*)d_in[13];
    const float* wg   = (const float*)d_in[14];
    const float* Wp1  = (const float*)d_in[15];
    const float* Wp2  = (const float*)d_in[16];
    const float* Wp3  = (const float*)d_in[17];
    const float* Wl   = (const float*)d_in[18];
    const float* Wgl  = (const float*)d_in[19];
    const float* Ws1  = (const float*)d_in[20];
    const float* Ws2  = (const float*)d_in[21];
    const float* Wf1  = (const float*)d_in[22];
    const float* Wf2  = (const float*)d_in[23];
    const float* Wcls = (const float*)d_in[24];
    const float* bcls = (const float*)d_in[25];

    float* ws    = (float*)d_ws;
    float* C1    = ws + OFS_C1;
    float* F2    = ws + OFS_F2;
    float* AF    = ws + OFS_AF;
    float* GV    = ws + OFS_GV;
    float* GH    = ws + OFS_GH;
    float* RWS   = ws + OFS_R;
    float* WCLST = ws + OFS_WT;
    float* out   = (float*)d_out;

    k_conv1<<<dim3(4, BB), 256, 0, stream>>>(x, Wc1, bc1, C1);
    k_f2<<<BB, 256, 0, stream>>>(C1, Wc2, bc2, Wt, bt, F2);
    // k_tw writes into the (now dead) C1 overlay region -> must follow k_f2.
    k_tw<<<(S * 600 * NC + 255) / 256, 256, 0, stream>>>(Wcls, WCLST);
    k_att2<<<BB / 2, 256, 0, stream>>>(F2, Wa, adj, Wl, Wgl, AF, GV);
    k_mgcn<<<BB / 2, 256, 0, stream>>>(F2, AF, adj, Wg1, Wg2, Wm1, Wm2, Wm3, wg,
                                       Wp1, Wp2, Wp3, RWS, GH);
    k_secls<<<BB, 256, 0, stream>>>(GH, GV, Ws1, Ws2, Wf1, Wf2, WCLST, bcls, out);
}

// Round 13
// 1097.746 us; speedup vs baseline: 1.1483x; 1.0111x over previous
//
#include <hip/hip_runtime.h>
#include <math.h>

#define S   30
#define FD  200
#define TT  1024
#define BB  1024
#define NC  7

// ---- workspace layout (float offsets), overlaid by live range ----
// C1 occupies [0, 31457280) and is LIVE until k_f2 completes.
// AF/GV/GH/RWS/WclsT overlay the C1 region and may only be written AFTER k_f2.
#define OFS_C1   0ull
#define OFS_F2   31457280ull
#define OFS_AF   0ull
#define OFS_GV   921600ull
#define OFS_GH   10137600ull
#define OFS_R    19691520ull     // 3*1024*30*100 floats
#define OFS_WT   28907520ull     // WclsT: 7*18000 = 126,000 floats

// ================= K1: conv1 + relu -> C1 =================
__global__ __launch_bounds__(256) void k_conv1(
    const float* __restrict__ x,
    const float* __restrict__ Wc1, const float* __restrict__ bc1,
    float* __restrict__ C1) {
    const int c = blockIdx.x, b = blockIdx.y;
    const int t = threadIdx.x;
    const int t0 = c * 256;
    __shared__ float xb[S * 258];
    __shared__ float w1l[90 * 32];
    for (int idx = t; idx < 2700; idx += 256) {
        int so = idx / 90, r = idx % 90;
        w1l[r * 32 + so] = Wc1[idx];
    }
    for (int idx = t; idx < 180; idx += 256) {
        int r = idx >> 1, z = idx & 1;
        w1l[r * 32 + 30 + z] = 0.f;
    }
    for (int idx = t; idx < S * 64; idx += 256) {
        int s = idx >> 6, u = idx & 63;
        float4 v = *(const float4*)(x + (size_t)(b * S + s) * TT + t0 + 4 * u);
        float* d = xb + s * 258 + 1 + 4 * u;
        d[0] = v.x; d[1] = v.y; d[2] = v.z; d[3] = v.w;
    }
    if (t < 60) {
        int s = t % S;
        if (t < S) {
            int gt = t0 - 1;
            xb[s * 258] = (gt >= 0) ? x[(size_t)(b * S + s) * TT + gt] : 0.f;
        } else {
            int gt = t0 + 256;
            xb[s * 258 + 257] = (gt < TT) ? x[(size_t)(b * S + s) * TT + gt] : 0.f;
        }
    }
    __syncthreads();
    float acc[32];
#pragma unroll
    for (int so = 0; so < 32; so++) acc[so] = (so < S) ? bc1[so] : 0.f;
    for (int si = 0; si < S; si++) {
        float v0 = xb[si * 258 + t];
        float v1 = xb[si * 258 + t + 1];
        float v2 = xb[si * 258 + t + 2];
        const float* wr = w1l + si * 96;
#pragma unroll
        for (int u = 0; u < 8; u++) {
            float4 w0 = *(const float4*)(wr + 4 * u);
            float4 w1 = *(const float4*)(wr + 32 + 4 * u);
            float4 w2 = *(const float4*)(wr + 64 + 4 * u);
            acc[4 * u + 0] = fmaf(w0.x, v0, fmaf(w1.x, v1, fmaf(w2.x, v2, acc[4 * u + 0])));
            acc[4 * u + 1] = fmaf(w0.y, v0, fmaf(w1.y, v1, fmaf(w2.y, v2, acc[4 * u + 1])));
            acc[4 * u + 2] = fmaf(w0.z, v0, fmaf(w1.z, v1, fmaf(w2.z, v2, acc[4 * u + 2])));
            acc[4 * u + 3] = fmaf(w0.w, v0, fmaf(w1.w, v1, fmaf(w2.w, v2, acc[4 * u + 3])));
        }
    }
#pragma unroll
    for (int so = 0; so < 32; so++) {
        if (so < S)
            C1[(size_t)(b * S + so) * TT + t0 + t] = fmaxf(acc[so], 0.f);
    }
}

// ---------- FMA tile helpers ----------
#define FMA4(av, wv, accm)                           \
    {                                                \
        accm[0] = fmaf(av, (wv).x, accm[0]);         \
        accm[1] = fmaf(av, (wv).y, accm[1]);         \
        accm[2] = fmaf(av, (wv).z, accm[2]);         \
        accm[3] = fmaf(av, (wv).w, accm[3]);         \
    }

__device__ inline void fma_tile8(const float4 a0, const float4 a1,
                                 const float4 w[8], float accm[4]) {
    FMA4(a0.x, w[0], accm); FMA4(a0.y, w[1], accm);
    FMA4(a0.z, w[2], accm); FMA4(a0.w, w[3], accm);
    FMA4(a1.x, w[4], accm); FMA4(a1.y, w[5], accm);
    FMA4(a1.z, w[6], accm); FMA4(a1.w, w[7], accm);
}

template<int RPT>
__device__ inline void zacc(float acc[][4]) {
#pragma unroll
    for (int m = 0; m < RPT; m++)
#pragma unroll
        for (int q = 0; q < 4; q++) acc[m][q] = 0.f;
}

// ---------- gemm_w4_pf: X(LDS) @ W(global), depth-8 register pipeline ----------
template<int RPT, int N, int K>
__device__ inline void gemm_w4_pf(const float* Xl, int xstr, const float* __restrict__ W,
                                  int ct, int rt, float acc[][4]) {
    const float* wp = W + 4 * ct;
    float4 wreg[8];
#pragma unroll
    for (int u = 0; u < 8; u++) wreg[u] = *(const float4*)(wp + u * N);
#pragma unroll 1
    for (int kt = 0; kt < K / 8 - 1; kt++) {
        float4 wnxt[8];
#pragma unroll
        for (int u = 0; u < 8; u++) wnxt[u] = *(const float4*)(wp + (kt * 8 + 8 + u) * N);
#pragma unroll
        for (int m = 0; m < RPT; m++) {
            const float* xr = Xl + (rt * RPT + m) * xstr + kt * 8;
            float4 a0 = *(const float4*)(xr);
            float4 a1 = *(const float4*)(xr + 4);
            fma_tile8(a0, a1, wreg, acc[m]);
        }
#pragma unroll
        for (int u = 0; u < 8; u++) wreg[u] = wnxt[u];
    }
    {
        const int kb = K - 8;
#pragma unroll
        for (int m = 0; m < RPT; m++) {
            const float* xr = Xl + (rt * RPT + m) * xstr + kb;
            float4 a0 = *(const float4*)(xr);
            float4 a1 = *(const float4*)(xr + 4);
            fma_tile8(a0, a1, wreg, acc[m]);
        }
    }
}

// ---------- gemm_w4_pf_dual: shared W stream, two X buffers / acc sets ----------
template<int RPT, int N, int K>
__device__ inline void gemm_w4_pf_dual(const float* X0, const float* X1, int xstr,
                                       const float* __restrict__ W,
                                       int ct, int rt,
                                       float acc0[][4], float acc1[][4]) {
    const float* wp = W + 4 * ct;
    float4 wreg[8];
#pragma unroll
    for (int u = 0; u < 8; u++) wreg[u] = *(const float4*)(wp + u * N);
#pragma unroll 1
    for (int kt = 0; kt < K / 8 - 1; kt++) {
        float4 wnxt[8];
#pragma unroll
        for (int u = 0; u < 8; u++) wnxt[u] = *(const float4*)(wp + (kt * 8 + 8 + u) * N);
#pragma unroll
        for (int m = 0; m < RPT; m++) {
            const float* xr = X0 + (rt * RPT + m) * xstr + kt * 8;
            float4 a0 = *(const float4*)(xr);
            float4 a1 = *(const float4*)(xr + 4);
            fma_tile8(a0, a1, wreg, acc0[m]);
        }
#pragma unroll
        for (int m = 0; m < RPT; m++) {
            const float* xr = X1 + (rt * RPT + m) * xstr + kt * 8;
            float4 a0 = *(const float4*)(xr);
            float4 a1 = *(const float4*)(xr + 4);
            fma_tile8(a0, a1, wreg, acc1[m]);
        }
#pragma unroll
        for (int u = 0; u < 8; u++) wreg[u] = wnxt[u];
    }
    {
        const int kb = K - 8;
#pragma unroll
        for (int m = 0; m < RPT; m++) {
            const float* xr = X0 + (rt * RPT + m) * xstr + kb;
            float4 a0 = *(const float4*)(xr);
            float4 a1 = *(const float4*)(xr + 4);
            fma_tile8(a0, a1, wreg, acc0[m]);
        }
#pragma unroll
        for (int m = 0; m < RPT; m++) {
            const float* xr = X1 + (rt * RPT + m) * xstr + kb;
            float4 a0 = *(const float4*)(xr);
            float4 a1 = *(const float4*)(xr + 4);
            fma_tile8(a0, a1, wreg, acc1[m]);
        }
    }
}

// ---------- gemm_a32: Al(LDS, stride 32) @ Xl(LDS) ----------
template<int RPT>
__device__ inline void gemm_a32(const float* Al, const float* Xl, int xstr,
                                int ct, int rt, float acc[][4]) {
#pragma unroll
    for (int k4 = 0; k4 < 8; k4++) {
        float4 xv0 = *(const float4*)(Xl + (4 * k4 + 0) * xstr + 4 * ct);
        float4 xv1 = *(const float4*)(Xl + (4 * k4 + 1) * xstr + 4 * ct);
        float4 xv2 = *(const float4*)(Xl + (4 * k4 + 2) * xstr + 4 * ct);
        float4 xv3 = *(const float4*)(Xl + (4 * k4 + 3) * xstr + 4 * ct);
#pragma unroll
        for (int m = 0; m < RPT; m++) {
            float4 av = *(const float4*)(Al + (rt * RPT + m) * 32 + 4 * k4);
            FMA4(av.x, xv0, acc[m]);
            FMA4(av.y, xv1, acc[m]);
            FMA4(av.z, xv2, acc[m]);
            FMA4(av.w, xv3, acc[m]);
        }
    }
}

// ---------- gemm_a32_dual ----------
template<int RPT>
__device__ inline void gemm_a32_dual(const float* Al0, const float* X0,
                                     const float* Al1, const float* X1,
                                     int xstr, int ct, int rt,
                                     float acc0[][4], float acc1[][4]) {
#pragma unroll
    for (int k4 = 0; k4 < 8; k4++) {
        float4 x00 = *(const float4*)(X0 + (4 * k4 + 0) * xstr + 4 * ct);
        float4 x01 = *(const float4*)(X0 + (4 * k4 + 1) * xstr + 4 * ct);
        float4 x02 = *(const float4*)(X0 + (4 * k4 + 2) * xstr + 4 * ct);
        float4 x03 = *(const float4*)(X0 + (4 * k4 + 3) * xstr + 4 * ct);
        float4 x10 = *(const float4*)(X1 + (4 * k4 + 0) * xstr + 4 * ct);
        float4 x11 = *(const float4*)(X1 + (4 * k4 + 1) * xstr + 4 * ct);
        float4 x12 = *(const float4*)(X1 + (4 * k4 + 2) * xstr + 4 * ct);
        float4 x13 = *(const float4*)(X1 + (4 * k4 + 3) * xstr + 4 * ct);
#pragma unroll
        for (int m = 0; m < RPT; m++) {
            float4 av0 = *(const float4*)(Al0 + (rt * RPT + m) * 32 + 4 * k4);
            FMA4(av0.x, x00, acc0[m]);
            FMA4(av0.y, x01, acc0[m]);
            FMA4(av0.z, x02, acc0[m]);
            FMA4(av0.w, x03, acc0[m]);
            float4 av1 = *(const float4*)(Al1 + (rt * RPT + m) * 32 + 4 * k4);
            FMA4(av1.x, x10, acc1[m]);
            FMA4(av1.y, x11, acc1[m]);
            FMA4(av1.z, x12, acc1[m]);
            FMA4(av1.w, x13, acc1[m]);
        }
    }
}

// ---------- gemm_w150_pf: N=150, float2-pair columns ----------
__device__ inline void gemm_w150_pf(const float* Xl, const float* __restrict__ W,
                                    int ct2, int rt2, float acc[5][4], int off23) {
    const float* wp = W + 4 * ct2;
    float2 wa[8], wb[8];
#pragma unroll
    for (int u = 0; u < 8; u++) {
        wa[u] = *(const float2*)(wp + u * 150);
        wb[u] = *(const float2*)(wp + u * 150 + off23);
    }
#pragma unroll 1
    for (int kt = 0; kt < 24; kt++) {
        float2 na[8], nb[8];
#pragma unroll
        for (int u = 0; u < 8; u++) {
            int k = kt * 8 + 8 + u;
            na[u] = *(const float2*)(wp + k * 150);
            nb[u] = *(const float2*)(wp + k * 150 + off23);
        }
#pragma unroll
        for (int m = 0; m < 5; m++) {
            const float* xr = Xl + (rt2 * 5 + m) * FD + kt * 8;
            float4 a0 = *(const float4*)(xr);
            float4 a1 = *(const float4*)(xr + 4);
            float av[8] = {a0.x, a0.y, a0.z, a0.w, a1.x, a1.y, a1.z, a1.w};
#pragma unroll
            for (int u = 0; u < 8; u++) {
                acc[m][0] = fmaf(av[u], wa[u].x, acc[m][0]);
                acc[m][1] = fmaf(av[u], wa[u].y, acc[m][1]);
                acc[m][2] = fmaf(av[u], wb[u].x, acc[m][2]);
                acc[m][3] = fmaf(av[u], wb[u].y, acc[m][3]);
            }
        }
#pragma unroll
        for (int u = 0; u < 8; u++) { wa[u] = na[u]; wb[u] = nb[u]; }
    }
#pragma unroll
    for (int m = 0; m < 5; m++) {
        const float* xr = Xl + (rt2 * 5 + m) * FD + 192;
        float4 a0 = *(const float4*)(xr);
        float4 a1 = *(const float4*)(xr + 4);
        float av[8] = {a0.x, a0.y, a0.z, a0.w, a1.x, a1.y, a1.z, a1.w};
#pragma unroll
        for (int u = 0; u < 8; u++) {
            acc[m][0] = fmaf(av[u], wa[u].x, acc[m][0]);
            acc[m][1] = fmaf(av[u], wa[u].y, acc[m][1]);
            acc[m][2] = fmaf(av[u], wb[u].x, acc[m][2]);
            acc[m][3] = fmaf(av[u], wb[u].y, acc[m][3]);
        }
    }
}

// ---------- gemm_w150_pf_dual: shared W stream, two X buffers / acc sets ----------
__device__ inline void gemm_w150_pf_dual(const float* X0, const float* X1,
                                         const float* __restrict__ W,
                                         int ct2, int rt2,
                                         float acc0[5][4], float acc1[5][4], int off23) {
    const float* wp = W + 4 * ct2;
    float2 wa[8], wb[8];
#pragma unroll
    for (int u = 0; u < 8; u++) {
        wa[u] = *(const float2*)(wp + u * 150);
        wb[u] = *(const float2*)(wp + u * 150 + off23);
    }
#pragma unroll 1
    for (int kt = 0; kt < 24; kt++) {
        float2 na[8], nb[8];
#pragma unroll
        for (int u = 0; u < 8; u++) {
            int k = kt * 8 + 8 + u;
            na[u] = *(const float2*)(wp + k * 150);
            nb[u] = *(const float2*)(wp + k * 150 + off23);
        }
#pragma unroll
        for (int m = 0; m < 5; m++) {
            const float* xr = X0 + (rt2 * 5 + m) * FD + kt * 8;
            float4 a0 = *(const float4*)(xr);
            float4 a1 = *(const float4*)(xr + 4);
            float av[8] = {a0.x, a0.y, a0.z, a0.w, a1.x, a1.y, a1.z, a1.w};
#pragma unroll
            for (int u = 0; u < 8; u++) {
                acc0[m][0] = fmaf(av[u], wa[u].x, acc0[m][0]);
                acc0[m][1] = fmaf(av[u], wa[u].y, acc0[m][1]);
                acc0[m][2] = fmaf(av[u], wb[u].x, acc0[m][2]);
                acc0[m][3] = fmaf(av[u], wb[u].y, acc0[m][3]);
            }
        }
#pragma unroll
        for (int m = 0; m < 5; m++) {
            const float* xr = X1 + (rt2 * 5 + m) * FD + kt * 8;
            float4 a0 = *(const float4*)(xr);
            float4 a1 = *(const float4*)(xr + 4);
            float av[8] = {a0.x, a0.y, a0.z, a0.w, a1.x, a1.y, a1.z, a1.w};
#pragma unroll
            for (int u = 0; u < 8; u++) {
                acc1[m][0] = fmaf(av[u], wa[u].x, acc1[m][0]);
                acc1[m][1] = fmaf(av[u], wa[u].y, acc1[m][1]);
                acc1[m][2] = fmaf(av[u], wb[u].x, acc1[m][2]);
                acc1[m][3] = fmaf(av[u], wb[u].y, acc1[m][3]);
            }
        }
#pragma unroll
        for (int u = 0; u < 8; u++) { wa[u] = na[u]; wb[u] = nb[u]; }
    }
#pragma unroll
    for (int m = 0; m < 5; m++) {
        const float* xr = X0 + (rt2 * 5 + m) * FD + 192;
        float4 a0 = *(const float4*)(xr);
        float4 a1 = *(const float4*)(xr + 4);
        float av[8] = {a0.x, a0.y, a0.z, a0.w, a1.x, a1.y, a1.z, a1.w};
#pragma unroll
        for (int u = 0; u < 8; u++) {
            acc0[m][0] = fmaf(av[u], wa[u].x, acc0[m][0]);
            acc0[m][1] = fmaf(av[u], wa[u].y, acc0[m][1]);
            acc0[m][2] = fmaf(av[u], wb[u].x, acc0[m][2]);
            acc0[m][3] = fmaf(av[u], wb[u].y, acc0[m][3]);
        }
    }
#pragma unroll
    for (int m = 0; m < 5; m++) {
        const float* xr = X1 + (rt2 * 5 + m) * FD + 192;
        float4 a0 = *(const float4*)(xr);
        float4 a1 = *(const float4*)(xr + 4);
        float av[8] = {a0.x, a0.y, a0.z, a0.w, a1.x, a1.y, a1.z, a1.w};
#pragma unroll
        for (int u = 0; u < 8; u++) {
            acc1[m][0] = fmaf(av[u], wa[u].x, acc1[m][0]);
            acc1[m][1] = fmaf(av[u], wa[u].y, acc1[m][1]);
            acc1[m][2] = fmaf(av[u], wb[u].x, acc1[m][2]);
            acc1[m][3] = fmaf(av[u], wb[u].y, acc1[m][3]);
        }
    }
}

// ================= K2: conv2 fused + F2 = relu(h2 @ Wt + bt) =================
__global__ __launch_bounds__(256) void k_f2(
    const float* __restrict__ C1,
    const float* __restrict__ Wc2, const float* __restrict__ bc2,
    const float* __restrict__ Wt, const float* __restrict__ bt,
    float* __restrict__ F2) {
    const int b = blockIdx.x, t = threadIdx.x;
    __shared__ float buf[S * 130];
    __shared__ float w2l[90 * 32];
    const int ct = t % 50, rt = t / 50;
    const int c3p = t & 63, sg = t >> 6;
    const int p0 = 2 * c3p;

    for (int idx = t; idx < 2700; idx += 256) {
        int ch = idx / 90, r = idx % 90;
        w2l[r * 32 + ch] = Wc2[idx];
    }
    for (int idx = t; idx < 180; idx += 256) {
        int r = idx >> 1, z = idx & 1;
        w2l[r * 32 + 30 + z] = 0.f;
    }
    float bias[8];
#pragma unroll
    for (int m = 0; m < 8; m++) {
        int ch = sg * 8 + m;
        bias[m] = bc2[ch < S ? ch : 0];
    }
    float acc[6][4];
    zacc<6>(acc);

    for (int ks = 0; ks < 8; ks++) {
        for (int idx = t; idx < S * 32; idx += 256) {
            int s = idx >> 5, u = idx & 31;
            float4 v = *(const float4*)(C1 + (size_t)(b * S + s) * TT + ks * 128 + 4 * u);
            float* d = buf + s * 130 + 1 + 4 * u;
            d[0] = v.x; d[1] = v.y; d[2] = v.z; d[3] = v.w;
        }
        if (t < 60) {
            int s = t % S;
            if (t < S) {
                int gt = ks * 128 - 1;
                buf[s * 130] = (gt >= 0) ? C1[(size_t)(b * S + s) * TT + gt] : 0.f;
            } else {
                int gt = ks * 128 + 128;
                buf[s * 130 + 129] = (gt < TT) ? C1[(size_t)(b * S + s) * TT + gt] : 0.f;
            }
        }
        __syncthreads();
        float a0[8], a1[8];
#pragma unroll
        for (int m = 0; m < 8; m++) { a0[m] = bias[m]; a1[m] = bias[m]; }
        for (int si = 0; si < S; si++) {
            float2 va = *(const float2*)(buf + si * 130 + p0);
            float2 vb = *(const float2*)(buf + si * 130 + p0 + 2);
            const float* wr = w2l + si * 96 + sg * 8;
            float4 w0a = *(const float4*)(wr);
            float4 w0b = *(const float4*)(wr + 4);
            float4 w1a = *(const float4*)(wr + 32);
            float4 w1b = *(const float4*)(wr + 36);
            float4 w2a = *(const float4*)(wr + 64);
            float4 w2b = *(const float4*)(wr + 68);
            float w0[8] = {w0a.x, w0a.y, w0a.z, w0a.w, w0b.x, w0b.y, w0b.z, w0b.w};
            float w1[8] = {w1a.x, w1a.y, w1a.z, w1a.w, w1b.x, w1b.y, w1b.z, w1b.w};
            float w2[8] = {w2a.x, w2a.y, w2a.z, w2a.w, w2b.x, w2b.y, w2b.z, w2b.w};
#pragma unroll
            for (int m = 0; m < 8; m++) {
                a0[m] = fmaf(w0[m], va.x, fmaf(w1[m], va.y, fmaf(w2[m], vb.x, a0[m])));
                a1[m] = fmaf(w0[m], va.y, fmaf(w1[m], vb.x, fmaf(w2[m], vb.y, a1[m])));
            }
        }
        __syncthreads();
#pragma unroll
        for (int m = 0; m < 8; m++) {
            int ch = sg * 8 + m;
            if (ch < S) {
                float2 o = {fmaxf(a0[m], 0.f), fmaxf(a1[m], 0.f)};
                *(float2*)(buf + ch * 128 + p0) = o;
            }
        }
        __syncthreads();
        if (t < 250)
            gemm_w4_pf<6, FD, 128>(buf, 128, Wt + (size_t)ks * 128 * FD, ct, rt, acc);
        __syncthreads();
    }
    if (t < 250) {
#pragma unroll
        for (int m = 0; m < 6; m++) {
            int row = rt * 6 + m;
            float4 o;
            o.x = fmaxf(acc[m][0] + bt[4 * ct + 0], 0.f);
            o.y = fmaxf(acc[m][1] + bt[4 * ct + 1], 0.f);
            o.z = fmaxf(acc[m][2] + bt[4 * ct + 2], 0.f);
            o.w = fmaxf(acc[m][3] + bt[4 * ct + 3], 0.f);
            *(float4*)(F2 + (size_t)(b * S + row) * FD + 4 * ct) = o;
        }
    }
}

// ================= K3: k_att2 — dual-sample, shared W register streams =================
__global__ __launch_bounds__(256) void k_att2(
    const float* __restrict__ F2, const float* __restrict__ Wa,
    const float* __restrict__ adj, const float* __restrict__ Wl,
    const float* __restrict__ Wgl,
    float* __restrict__ AF, float* __restrict__ Gv) {
    const int b0 = blockIdx.x * 2, b1 = b0 + 1;
    const int t = threadIdx.x;
    __shared__ float A0[32 * FD], A1[32 * FD];    // F2 per sample, rows 30/31 zero
    __shared__ float Bu0[32 * FD], Bu1[32 * FD];  // P / T staging per sample
    __shared__ float scl0[1024], scl1[1024];      // scores -> A_F (stride 32)
    __shared__ float adjl[1024];
    for (int idx = t; idx < 1500; idx += 256) {
        *(float4*)(A0 + 4 * idx) = *(const float4*)(F2 + (size_t)b0 * S * FD + 4 * idx);
        *(float4*)(A1 + 4 * idx) = *(const float4*)(F2 + (size_t)b1 * S * FD + 4 * idx);
    }
    for (int idx = t; idx < 400; idx += 256) {
        A0[6000 + idx] = 0.f; A1[6000 + idx] = 0.f;
        Bu0[6000 + idx] = 0.f; Bu1[6000 + idx] = 0.f;
    }
    for (int idx = t; idx < 1024; idx += 256) {
        int r = idx >> 5, cc = idx & 31;
        adjl[idx] = (r < S && cc < S) ? adj[r * S + cc] : 0.f;
        scl0[idx] = 0.f; scl1[idx] = 0.f;
    }
    __syncthreads();
    const int ct = t % 50, rt = t / 50;
    float acc0[6][4], acc1[6][4];
    // P = F2 @ Wa (dual, shared W stream) -> Bu
    zacc<6>(acc0); zacc<6>(acc1);
    if (t < 250) {
        gemm_w4_pf_dual<6, FD, FD>(A0, A1, FD, Wa, ct, rt, acc0, acc1);
#pragma unroll
        for (int m = 0; m < 6; m++) {
            float4 o0 = {acc0[m][0], acc0[m][1], acc0[m][2], acc0[m][3]};
            float4 o1 = {acc1[m][0], acc1[m][1], acc1[m][2], acc1[m][3]};
            *(float4*)(Bu0 + (rt * 6 + m) * FD + 4 * ct) = o0;
            *(float4*)(Bu1 + (rt * 6 + m) * FD + 4 * ct) = o1;
        }
    }
    __syncthreads();
    // scl[i,j] = relu(P[i,:] . F2[j,:]) for both samples (1800 dots)
    for (int idx = t; idx < 2 * S * S; idx += 256) {
        int h = idx / (S * S), r = idx % (S * S);
        int i = r / S, j = r % S;
        const float* Pb = h ? Bu1 : Bu0;
        const float* Fb = h ? A1 : A0;
        float a = 0.f;
        for (int f4 = 0; f4 < 50; f4++) {
            float4 p = *(const float4*)(Pb + i * FD + 4 * f4);
            float4 q = *(const float4*)(Fb + j * FD + 4 * f4);
            a = fmaf(p.x, q.x, a); a = fmaf(p.y, q.y, a);
            a = fmaf(p.z, q.z, a); a = fmaf(p.w, q.w, a);
        }
        float* sc = h ? scl1 : scl0;
        sc[i * 32 + j] = fmaxf(a, 0.f);
    }
    __syncthreads();
    // softmax rows: lanes 0..29 -> sample0, lanes 64..93 -> sample1
    if (t < S) {
        float mx = -1e30f;
        for (int j = 0; j < S; j++) mx = fmaxf(mx, scl0[t * 32 + j]);
        float den = 0.f;
        for (int j = 0; j < S; j++) den += expf(scl0[t * 32 + j] - mx);
        float inv = 1.f / den;
        for (int j = 0; j < S; j++) scl0[t * 32 + j] = expf(scl0[t * 32 + j] - mx) * inv;
    } else if (t >= 64 && t < 64 + S) {
        int s = t - 64;
        float mx = -1e30f;
        for (int j = 0; j < S; j++) mx = fmaxf(mx, scl1[s * 32 + j]);
        float den = 0.f;
        for (int j = 0; j < S; j++) den += expf(scl1[s * 32 + j] - mx);
        float inv = 1.f / den;
        for (int j = 0; j < S; j++) scl1[s * 32 + j] = expf(scl1[s * 32 + j] - mx) * inv;
    }
    __syncthreads();
    for (int idx = t; idx < S * S; idx += 256) {
        int i = idx / S, j = idx % S;
        AF[(size_t)b0 * S * S + idx] = scl0[i * 32 + j];
        AF[(size_t)b1 * S * S + idx] = scl1[i * 32 + j];
    }
    // loc: T = adj@F2 (dual) -> Bu ; Gv[:, :150] = relu(T @ Wl) (dual W stream)
    zacc<6>(acc0); zacc<6>(acc1);
    if (t < 250) gemm_a32_dual<6>(adjl, A0, adjl, A1, FD, ct, rt, acc0, acc1);
    __syncthreads();
    if (t < 250) {
#pragma unroll
        for (int m = 0; m < 6; m++) {
            float4 o0 = {acc0[m][0], acc0[m][1], acc0[m][2], acc0[m][3]};
            float4 o1 = {acc1[m][0], acc1[m][1], acc1[m][2], acc1[m][3]};
            *(float4*)(Bu0 + (rt * 6 + m) * FD + 4 * ct) = o0;
            *(float4*)(Bu1 + (rt * 6 + m) * FD + 4 * ct) = o1;
        }
    }
    __syncthreads();
    const int ct2 = t % 38, rt2 = t / 38;
    const bool full = (4 * ct2 + 2) < 150;
    const int off23 = full ? 2 : -2;
    if (t < 228) {
        float a20[5][4], a21[5][4];
        zacc<5>(a20); zacc<5>(a21);
        gemm_w150_pf_dual(Bu0, Bu1, Wl, ct2, rt2, a20, a21, off23);
#pragma unroll
        for (int m = 0; m < 5; m++) {
            float* o0 = Gv + (size_t)(b0 * S + rt2 * 5 + m) * 300 + 4 * ct2;
            float* o1 = Gv + (size_t)(b1 * S + rt2 * 5 + m) * 300 + 4 * ct2;
            o0[0] = fmaxf(a20[m][0], 0.f); o0[1] = fmaxf(a20[m][1], 0.f);
            o1[0] = fmaxf(a21[m][0], 0.f); o1[1] = fmaxf(a21[m][1], 0.f);
            if (full) {
                o0[2] = fmaxf(a20[m][2], 0.f); o0[3] = fmaxf(a20[m][3], 0.f);
                o1[2] = fmaxf(a21[m][2], 0.f); o1[3] = fmaxf(a21[m][3], 0.f);
            }
        }
    }
    __syncthreads();
    // glb: T = AF@F2 (dual) -> Bu ; Gv[:, 150:] = relu(T @ Wgl) (dual W stream)
    zacc<6>(acc0); zacc<6>(acc1);
    if (t < 250) gemm_a32_dual<6>(scl0, A0, scl1, A1, FD, ct, rt, acc0, acc1);
    __syncthreads();
    if (t < 250) {
#pragma unroll
        for (int m = 0; m < 6; m++) {
            float4 o0 = {acc0[m][0], acc0[m][1], acc0[m][2], acc0[m][3]};
            float4 o1 = {acc1[m][0], acc1[m][1], acc1[m][2], acc1[m][3]};
            *(float4*)(Bu0 + (rt * 6 + m) * FD + 4 * ct) = o0;
            *(float4*)(Bu1 + (rt * 6 + m) * FD + 4 * ct) = o1;
        }
    }
    __syncthreads();
    if (t < 228) {
        float a20[5][4], a21[5][4];
        zacc<5>(a20); zacc<5>(a21);
        gemm_w150_pf_dual(Bu0, Bu1, Wgl, ct2, rt2, a20, a21, off23);
#pragma unroll
        for (int m = 0; m < 5; m++) {
            float* o0 = Gv + (size_t)(b0 * S + rt2 * 5 + m) * 300 + 150 + 4 * ct2;
            float* o1 = Gv + (size_t)(b1 * S + rt2 * 5 + m) * 300 + 150 + 4 * ct2;
            o0[0] = fmaxf(a20[m][0], 0.f); o0[1] = fmaxf(a20[m][1], 0.f);
            o1[0] = fmaxf(a21[m][0], 0.f); o1[1] = fmaxf(a21[m][1], 0.f);
            if (full) {
                o0[2] = fmaxf(a20[m][2], 0.f); o0[3] = fmaxf(a20[m][3], 0.f);
                o1[2] = fmaxf(a21[m][2], 0.f); o1[3] = fmaxf(a21[m][3], 0.f);
            }
        }
    }
}

// ================= K4: k_mgcn — 2 samples/block, shared W stream =================
// Dual is the verified optimum of the W-sharing lever (r4: −7%; r10 quad: −36% REGRESSION
// at 1 wave/SIMD — do not extend past dual on this kernel).
__global__ __launch_bounds__(256, 2) void k_mgcn(
    const float* __restrict__ F2g, const float* __restrict__ AFg,
    const float* __restrict__ adj,
    const float* __restrict__ Wg1, const float* __restrict__ Wg2,
    const float* __restrict__ Wm1, const float* __restrict__ Wm2,
    const float* __restrict__ Wm3, const float* __restrict__ wg,
    const float* __restrict__ Wp1, const float* __restrict__ Wp2,
    const float* __restrict__ Wp3,
    float* __restrict__ Rws, float* __restrict__ Gh) {
    const int b0 = blockIdx.x * 2, b1 = b0 + 1;
    const int t = threadIdx.x;
    __shared__ float A0[32 * FD], A1[32 * FD];
    __shared__ float afl0[1024], afl1[1024];
    __shared__ float adjl[1024];
    __shared__ float sk[192];
    __shared__ float gl[192];
    const int ct = t % 50, rt = t / 50;
    const int ct3 = t % 25, rt3 = t / 25;

    for (int idx = t; idx < 1500; idx += 256) {
        *(float4*)(A0 + 4 * idx) = *(const float4*)(F2g + (size_t)b0 * S * FD + 4 * idx);
        *(float4*)(A1 + 4 * idx) = *(const float4*)(F2g + (size_t)b1 * S * FD + 4 * idx);
    }
    for (int idx = t; idx < 400; idx += 256) { A0[6000 + idx] = 0.f; A1[6000 + idx] = 0.f; }
    for (int idx = t; idx < 1024; idx += 256) {
        int r = idx >> 5, cc = idx & 31;
        bool in = (r < S && cc < S);
        afl0[idx] = in ? AFg[(size_t)b0 * S * S + r * S + cc] : 0.f;
        afl1[idx] = in ? AFg[(size_t)b1 * S * S + r * S + cc] : 0.f;
        adjl[idx] = in ? adj[r * S + cc] : 0.f;
    }
    if (t < 192) sk[t] = 0.f;
    __syncthreads();

    float acc0[6][4], acc1[6][4], xsr0[6][4], xsr1[6][4];

#define DZ() { zacc<6>(acc0); zacc<6>(acc1); }
#define DWRITE(RELU)                                                        \
    if (t < 250) {                                                          \
        _Pragma("unroll")                                                   \
        for (int m = 0; m < 6; m++) {                                       \
            float4 o0, o1;                                                  \
            o0.x = RELU ? fmaxf(acc0[m][0], 0.f) : acc0[m][0];              \
            o0.y = RELU ? fmaxf(acc0[m][1], 0.f) : acc0[m][1];              \
            o0.z = RELU ? fmaxf(acc0[m][2], 0.f) : acc0[m][2];              \
            o0.w = RELU ? fmaxf(acc0[m][3], 0.f) : acc0[m][3];              \
            o1.x = RELU ? fmaxf(acc1[m][0], 0.f) : acc1[m][0];              \
            o1.y = RELU ? fmaxf(acc1[m][1], 0.f) : acc1[m][1];              \
            o1.z = RELU ? fmaxf(acc1[m][2], 0.f) : acc1[m][2];              \
            o1.w = RELU ? fmaxf(acc1[m][3], 0.f) : acc1[m][3];              \
            *(float4*)(A0 + (rt * 6 + m) * FD + 4 * ct) = o0;               \
            *(float4*)(A1 + (rt * 6 + m) * FD + 4 * ct) = o1;               \
        }                                                                   \
    }

    // ---- xs chain, in place (destroys F2 in A0/A1) ----
    DZ();
    if (t < 250) gemm_a32_dual<6>(adjl, A0, adjl, A1, FD, ct, rt, acc0, acc1);
    __syncthreads();
    DWRITE(false);
    __syncthreads();
    DZ();
    if (t < 250) gemm_w4_pf_dual<6, FD, FD>(A0, A1, FD, Wg1, ct, rt, acc0, acc1);
    __syncthreads();
    DWRITE(true);
    __syncthreads();
    DZ();
    if (t < 250) gemm_a32_dual<6>(adjl, A0, adjl, A1, FD, ct, rt, acc0, acc1);
    __syncthreads();
    DWRITE(false);
    __syncthreads();
    DZ();
    if (t < 250) gemm_w4_pf_dual<6, FD, FD>(A0, A1, FD, Wg2, ct, rt, acc0, acc1);
    __syncthreads();   // all reads of A=T2 done
#pragma unroll
    for (int m = 0; m < 6; m++) {
#pragma unroll
        for (int q = 0; q < 4; q++) { xsr0[m][q] = acc0[m][q]; xsr1[m][q] = acc1[m][q]; }
    }
    for (int idx = t; idx < 1500; idx += 256) {
        *(float4*)(A0 + 4 * idx) = *(const float4*)(F2g + (size_t)b0 * S * FD + 4 * idx);
        *(float4*)(A1 + 4 * idx) = *(const float4*)(F2g + (size_t)b1 * S * FD + 4 * idx);
    }
    __syncthreads();

    // ---- MGCN chain: k = 0,1,2 ----
    const float* Wm[3] = {Wm1, Wm2, Wm3};
    const float* Wp[3] = {Wp1, Wp2, Wp3};
#pragma unroll 1
    for (int k = 0; k < 3; k++) {
        // T = AF @ X
        DZ();
        if (t < 250) gemm_a32_dual<6>(afl0, A0, afl1, A1, FD, ct, rt, acc0, acc1);
        __syncthreads();
        DWRITE(false);
        __syncthreads();
        // X_k = relu(T @ Wm_k) in regs
        DZ();
        if (t < 250) gemm_w4_pf_dual<6, FD, FD>(A0, A1, FD, Wm[k], ct, rt, acc0, acc1);
        __syncthreads();   // reads of A=T done
        if (t < 250) {
#pragma unroll
            for (int m = 0; m < 6; m++) {
#pragma unroll
                for (int q = 0; q < 4; q++) {
                    acc0[m][q] = fmaxf(acc0[m][q], 0.f);
                    acc1[m][q] = fmaxf(acc1[m][q], 0.f);
                }
            }
#pragma unroll
            for (int m = 0; m < 6; m++) {
                int row = rt * 6 + m;
                float wg0 = wg[(4 * ct + 0) * 3 + k], wg1v = wg[(4 * ct + 1) * 3 + k];
                float wg2v = wg[(4 * ct + 2) * 3 + k], wg3 = wg[(4 * ct + 3) * 3 + k];
                float h00 = 0.5f * (acc0[m][0] + xsr0[m][0]);
                float h01 = 0.5f * (acc0[m][1] + xsr0[m][1]);
                float h02 = 0.5f * (acc0[m][2] + xsr0[m][2]);
                float h03 = 0.5f * (acc0[m][3] + xsr0[m][3]);
                float4 o0 = {h00, h01, h02, h03};
                *(float4*)(A0 + row * FD + 4 * ct) = o0;
                atomicAdd(&sk[row * 3 + k],
                          h00 * wg0 + h01 * wg1v + h02 * wg2v + h03 * wg3);
                float h10 = 0.5f * (acc1[m][0] + xsr1[m][0]);
                float h11 = 0.5f * (acc1[m][1] + xsr1[m][1]);
                float h12 = 0.5f * (acc1[m][2] + xsr1[m][2]);
                float h13 = 0.5f * (acc1[m][3] + xsr1[m][3]);
                float4 o1 = {h10, h11, h12, h13};
                *(float4*)(A1 + row * FD + 4 * ct) = o1;
                atomicAdd(&sk[96 + row * 3 + k],
                          h10 * wg0 + h11 * wg1v + h12 * wg2v + h13 * wg3);
            }
        }
        __syncthreads();
        // R_k = H_k @ Wp_k -> workspace
        if (t < 250) {
            float a30[3][4], a31[3][4];
            zacc<3>(a30); zacc<3>(a31);
            gemm_w4_pf_dual<3, 100, FD>(A0, A1, FD, Wp[k], ct3, rt3, a30, a31);
#pragma unroll
            for (int m = 0; m < 3; m++) {
                float4 o0 = {a30[m][0], a30[m][1], a30[m][2], a30[m][3]};
                float4 o1 = {a31[m][0], a31[m][1], a31[m][2], a31[m][3]};
                *(float4*)(Rws + ((size_t)(k * BB + b0) * S + rt3 * 3 + m) * 100 + 4 * ct3) = o0;
                *(float4*)(Rws + ((size_t)(k * BB + b1) * S + rt3 * 3 + m) * 100 + 4 * ct3) = o1;
            }
        }
        __syncthreads();   // reads of A=H_k done
        if (k < 2) {
            DWRITE(false);   // acc already relu'd: restore X_k
            __syncthreads();
        }
    }

    // ---- gates ----
    if (t < S) {
        float a0 = sk[t * 3 + 0], a1 = sk[t * 3 + 1], a2 = sk[t * 3 + 2];
        float m = fmaxf(a0, fmaxf(a1, a2));
        float e0 = expf(a0 - m), e1 = expf(a1 - m), e2 = expf(a2 - m);
        float inv = 1.f / (e0 + e1 + e2);
        gl[t * 3 + 0] = e0 * inv; gl[t * 3 + 1] = e1 * inv; gl[t * 3 + 2] = e2 * inv;
    } else if (t >= 64 && t < 64 + S) {
        int s = t - 64;
        float a0 = sk[96 + s * 3 + 0], a1 = sk[96 + s * 3 + 1], a2 = sk[96 + s * 3 + 2];
        float m = fmaxf(a0, fmaxf(a1, a2));
        float e0 = expf(a0 - m), e1 = expf(a1 - m), e2 = expf(a2 - m);
        float inv = 1.f / (e0 + e1 + e2);
        gl[96 + s * 3 + 0] = e0 * inv; gl[96 + s * 3 + 1] = e1 * inv; gl[96 + s * 3 + 2] = e2 * inv;
    }
    __syncthreads();

    // ---- G_k = adj @ diag(g_k) @ R_k ----
#pragma unroll 1
    for (int k = 0; k < 3; k++) {
        for (int idx = t; idx < S * 100; idx += 256) {
            int row = idx / 100, col = idx % 100;
            A0[row * FD + col] = Rws[((size_t)(k * BB + b0) * S) * 100 + idx];
            A1[row * FD + col] = Rws[((size_t)(k * BB + b1) * S) * 100 + idx];
        }
        for (int idx = t; idx < 1024; idx += 256) {
            int cc = idx & 31;
            afl0[idx] = (cc < S) ? adjl[idx] * gl[cc * 3 + k] : 0.f;
            afl1[idx] = (cc < S) ? adjl[idx] * gl[96 + cc * 3 + k] : 0.f;
        }
        __syncthreads();
        if (t < 250) {
            float a30[3][4], a31[3][4];
            zacc<3>(a30); zacc<3>(a31);
            gemm_a32_dual<3>(afl0, A0, afl1, A1, FD, ct3, rt3, a30, a31);
#pragma unroll
            for (int m = 0; m < 3; m++) {
                float4 o0 = {a30[m][0], a30[m][1], a30[m][2], a30[m][3]};
                float4 o1 = {a31[m][0], a31[m][1], a31[m][2], a31[m][3]};
                *(float4*)(Gh + (size_t)(b0 * S + rt3 * 3 + m) * 300 + k * 100 + 4 * ct3) = o0;
                *(float4*)(Gh + (size_t)(b1 * S + rt3 * 3 + m) * 300 + k * 100 + 4 * ct3) = o1;
            }
        }
        __syncthreads();
    }
#undef DZ
#undef DWRITE
}

// ================= K5: transpose Wcls -> WclsT[c][i] (once) =================
// NOTE: writes into the C1-overlay region -> must launch AFTER k_f2.
__global__ __launch_bounds__(256) void k_tw(const float* __restrict__ Wcls,
                                            float* __restrict__ WclsT) {
    int idx = blockIdx.x * 256 + threadIdx.x;
    if (idx < S * 600 * NC) {
        int i = idx / NC, c = idx % NC;
        WclsT[c * (S * 600) + i] = Wcls[idx];
    }
}

// ================= K6: fused SE gates + classifier + log_softmax =================
// r13: quad-vectorized classifier (i = 4*i4; 18000 % 4 == 0; all bases 16B-aligned)
// and float4 mb column sums — continuation of the verified instruction-count vein.
__global__ __launch_bounds__(256) void k_secls(
    const float* __restrict__ Gh, const float* __restrict__ Gv,
    const float* __restrict__ Ws1, const float* __restrict__ Ws2,
    const float* __restrict__ Wf1, const float* __restrict__ Wf2,
    const float* __restrict__ WclsT, const float* __restrict__ bcls,
    float* __restrict__ out) {
    const int b = blockIdx.x, t = threadIdx.x;
    __shared__ float red[NC][256];
    __shared__ float mrow[S];
    __shared__ float u[15];
    __shared__ float mb[300];
    __shared__ float v[150];
    __shared__ float wftl[300];
    __shared__ float wchl[S];
    if (t < S) {
        float a = 0.f;
        const float* gp = Gv + ((size_t)b * S + t) * 300;
        for (int j4 = 0; j4 < 75; j4++) {
            float4 w = *(const float4*)(gp + 4 * j4);
            a += (w.x + w.y) + (w.z + w.w);
        }
        mrow[t] = a * (1.f / 300.f);
    }
    // mb column sums: 75 threads x float4 across rows (Gh rows 16B-aligned)
    if (t >= 128 && t < 128 + 75) {
        int j4 = t - 128;
        float4 a = {0.f, 0.f, 0.f, 0.f};
        const float* gp = Gh + (size_t)b * S * 300 + 4 * j4;
        for (int s = 0; s < S; s++) {
            float4 w = *(const float4*)(gp + s * 300);
            a.x += w.x; a.y += w.y; a.z += w.z; a.w += w.w;
        }
        mb[4 * j4 + 0] = a.x * (1.f / S);
        mb[4 * j4 + 1] = a.y * (1.f / S);
        mb[4 * j4 + 2] = a.z * (1.f / S);
        mb[4 * j4 + 3] = a.w * (1.f / S);
    }
    __syncthreads();
    if (t < 15) {
        float a = 0.f;
        for (int i = 0; i < S; i++) a += mrow[i] * Ws1[i * 15 + t];
        u[t] = fmaxf(a, 0.f);
    }
    if (t >= 64 && t < 64 + 150) {
        int h = t - 64;
        float a = 0.f;
        for (int j = 0; j < 300; j++) a += mb[j] * Wf1[j * 150 + h];
        v[h] = fmaxf(a, 0.f);
    }
    __syncthreads();
    if (t < S) {
        float a = 0.f;
        for (int h = 0; h < 15; h++) a += u[h] * Ws2[h * 30 + t];
        wchl[t] = 1.f / (1.f + expf(-a));
    }
    for (int j = t; j < 300; j += 256) {
        float a = 0.f;
        for (int h = 0; h < 150; h++) a += v[h] * Wf2[h * 300 + j];
        wftl[j] = 1.f / (1.f + expf(-a));
    }
    __syncthreads();
    float acc[NC];
#pragma unroll
    for (int c = 0; c < NC; c++) acc[c] = 0.f;
    // quad classifier loop: i = 4*i4, i4 in [0, 4500)
    for (int i4 = t; i4 < S * 150; i4 += 256) {
        int s = i4 / 150, jj = i4 % 150;      // 4*jj in [0,600)
        int i = 4 * i4;                        // = s*600 + 4*jj
        float4 d4;
        float sc0, sc1, sc2, sc3;
        if (jj < 75) {
            d4 = *(const float4*)(Gh + (size_t)b * S * 300 + s * 300 + 4 * jj);
            sc0 = wchl[s]; sc1 = sc0; sc2 = sc0; sc3 = sc0;
        } else {
            int j4 = 4 * jj - 300;            // [0,300), multiple of 4
            d4 = *(const float4*)(Gv + (size_t)b * S * 300 + s * 300 + j4);
            sc0 = wftl[j4]; sc1 = wftl[j4 + 1]; sc2 = wftl[j4 + 2]; sc3 = wftl[j4 + 3];
        }
        float g0 = d4.x * sc0, g1 = d4.y * sc1, g2 = d4.z * sc2, g3 = d4.w * sc3;
#pragma unroll
        for (int c = 0; c < NC; c++) {
            float4 w4 = *(const float4*)(WclsT + c * (S * 600) + i);
            acc[c] = fmaf(g3, w4.w, fmaf(g2, w4.z, fmaf(g1, w4.y, fmaf(g0, w4.x, acc[c]))));
        }
    }
#pragma unroll
    for (int c = 0; c < NC; c++) red[c][t] = acc[c];
    __syncthreads();
    for (int off = 128; off > 0; off >>= 1) {
        if (t < off) {
#pragma unroll
            for (int c = 0; c < NC; c++) red[c][t] += red[c][t + off];
        }
        __syncthreads();
    }
    if (t == 0) {
        float lg[NC];
        float mx = -1e30f;
#pragma unroll
        for (int c = 0; c < NC; c++) { lg[c] = red[c][0] + bcls[c]; mx = fmaxf(mx, lg[c]); }
        float den = 0.f;
#pragma unroll
        for (int c = 0; c < NC; c++) den += expf(lg[c] - mx);
        float lden = logf(den) + mx;
#pragma unroll
        for (int c = 0; c < NC; c++) out[b * NC + c] = lg[c] - lden;
    }
}

extern "C" void kernel_launch(void* const* d_in, const int* in_sizes, int n_in,
                              void* d_out, int out_size, void* d_ws, size_t ws_size,
                              hipStream_t stream) {
    const float* x    = (const float*)d_in[0];
    const float* adj  = (const float*)d_in[1];
    const float* Wc1  = (const float*)d_in[2];
    const float* bc1  = (const float*)d_in[3];
    const float* Wc2  = (const float*)d_in[4];
    const float* bc2  = (const float*)d_in[5];
    const float* Wt   = (const float*)d_in[6];
    const float* bt   = (const float*)d_in[7];
    const float* Wa   = (const float*)d_in[8];
    const float* Wm1  = (const float*)d_in[9];
    const float* Wm2  = (const float*)d_in[10];
    const float* Wm3  = (const float*)d_in[11];
    const float* Wg1  = (const float*)d_in[12];
    const float* Wg2  = (const float*)d_in[13];
    const float* wg   = (const float*)d_in[14];
    const float* Wp1  = (const float*)d_in[15];
    const float* Wp2  = (const float*)d_in[16];
    const float* Wp3  = (const float*)d_in[17];
    const float* Wl   = (const float*)d_in[18];
    const float* Wgl  = (const float*)d_in[19];
    const float* Ws1  = (const float*)d_in[20];
    const float* Ws2  = (const float*)d_in[21];
    const float* Wf1  = (const float*)d_in[22];
    const float* Wf2  = (const float*)d_in[23];
    const float* Wcls = (const float*)d_in[24];
    const float* bcls = (const float*)d_in[25];

    float* ws    = (float*)d_ws;
    float* C1    = ws + OFS_C1;
    float* F2    = ws + OFS_F2;
    float* AF    = ws + OFS_AF;
    float* GV    = ws + OFS_GV;
    float* GH    = ws + OFS_GH;
    float* RWS   = ws + OFS_R;
    float* WCLST = ws + OFS_WT;
    float* out   = (float*)d_out;

    k_conv1<<<dim3(4, BB), 256, 0, stream>>>(x, Wc1, bc1, C1);
    k_f2<<<BB, 256, 0, stream>>>(C1, Wc2, bc2, Wt, bt, F2);
    // k_tw writes into the (now dead) C1 overlay region -> must follow k_f2.
    k_tw<<<(S * 600 * NC + 255) / 256, 256, 0, stream>>>(Wcls, WCLST);
    k_att2<<<BB / 2, 256, 0, stream>>>(F2, Wa, adj, Wl, Wgl, AF, GV);
    k_mgcn<<<BB / 2, 256, 0, stream>>>(F2, AF, adj, Wg1, Wg2, Wm1, Wm2, Wm3, wg,
                                       Wp1, Wp2, Wp3, RWS, GH);
    k_secls<<<BB, 256, 0, stream>>>(GH, GV, Ws1, Ws2, Wf1, Wf2, WCLST, bcls, out);
}